// Round 3
// baseline (627.170 us; speedup 1.0000x reference)
//
#include <hip/hip_runtime.h>
#include <hip/hip_bf16.h>
#include <stdint.h>

#define N_NODES 50000
#define N_EDGES 800000
#define K_KEEP  40000
#define BKT     196        // ceil(N_NODES/256) dst-range buckets
#define BCAP    6144       // per-bucket capacity (mean 4081, +32 sigma)

typedef unsigned long long u64;
typedef unsigned int u32;
typedef unsigned short u16;
typedef __hip_bfloat16 bf16;
typedef __hip_bfloat162 bf16x2;
typedef __attribute__((ext_vector_type(8))) short short8;
typedef __attribute__((ext_vector_type(4))) float f32x4;

#define SCOPE_AGENT __HIP_MEMORY_SCOPE_AGENT

struct Ctl {
  u64 prefix;
  u32 kremain;
  u32 cnt;
  float inv_norm;
  u32 isfp32;
  u32 done;         // radix pass arrival counter (cumulative, never reset)
  u32 pad;          // csr2 edge cursor
  u32 gen;          // radix generation (published pass count)
  u32 done2;        // final-gather arrival counter
  u32 hist[256];    // radix histogram (LDS-aggregated flushes only)
};

__device__ __forceinline__ float bf2f(bf16 v) { return __bfloat162float(v); }
__device__ __forceinline__ float loadF(const void* p, size_t i, bool f32) {
  return f32 ? ((const float*)p)[i] : bf2f(((const bf16*)p)[i]);
}
__device__ __forceinline__ short f2bf_bits(float f) {
  bf16 t = __float2bfloat16(f);
  return *(const short*)&t;
}

// ---------------- init (+parallel dtype detect, proven R5-R8) ----------------

__global__ void init_kernel(const unsigned short* __restrict__ x16,
                            int* __restrict__ bucket_cur, int* __restrict__ detcnt, Ctl* ctl) {
  __shared__ u32 dsh[256];
  int i = blockIdx.x * 256 + threadIdx.x;
  if (i < BKT) bucket_cur[i] = i * BCAP;
  if (blockIdx.x == 0) {
    ctl->hist[threadIdx.x] = 0u;
    if (threadIdx.x == 0) {
      ctl->prefix = 0ull; ctl->kremain = K_KEEP; ctl->cnt = 0u;
      ctl->done = 0u; ctl->pad = 0u; ctl->gen = 0u; ctl->done2 = 0u;
    }
  }
  if (blockIdx.x < 64) {
    int base = blockIdx.x * 2048;
    u32 c = 0;
    for (int j = threadIdx.x; j < 2048; j += 256) {
      u32 h = x16[base + j];
      if ((h & 0x7F80u) == 0x7F80u) c++;
    }
    dsh[threadIdx.x] = c;
    __syncthreads();
    for (int s = 128; s > 0; s >>= 1) {
      if (threadIdx.x < s) dsh[threadIdx.x] += dsh[threadIdx.x + s];
      __syncthreads();
    }
    if (threadIdx.x == 0) detcnt[blockIdx.x] = (int)dsh[0];
  }
}

// ------- CSR1 bucket scatter (proven R8) + fused dtype/norm + fp32->bf16 convert -------

__global__ void bucket_scatter_kernel(const int* __restrict__ src, const int* __restrict__ dst,
                                      int* __restrict__ bucket_cur, u32* __restrict__ bucketbuf,
                                      const void* __restrict__ x, u32* __restrict__ xbf,
                                      const int* __restrict__ detcnt, const void* __restrict__ pw,
                                      Ctl* ctl)
{
  __shared__ u32 hist[BKT];
  __shared__ u32 base[BKT];
  __shared__ int f32sh;
  __shared__ float ns[128];
  const int tid = threadIdx.x;
  const int e0 = blockIdx.x * 2048;

  // dtype detect from detcnt (written by init, prior dispatch)
  if (tid < 64) {
    int dc = detcnt[tid];
    for (int off = 32; off; off >>= 1) dc += __shfl_down(dc, off);
    if (tid == 0) f32sh = (dc >= 16) ? 1 : 0;
  }
  for (int t = tid; t < BKT; t += 256) hist[t] = 0;
  __syncthreads();
  const bool f32in = f32sh != 0;

  #pragma unroll
  for (int j = 0; j < 8; ++j) {
    int e = e0 + j * 256 + tid;
    if (e < N_EDGES) atomicAdd(&hist[dst[e] >> 8], 1u);
  }
  __syncthreads();
  for (int t = tid; t < BKT; t += 256) {
    u32 c = hist[t];
    base[t] = c ? (u32)atomicAdd(&bucket_cur[t], (int)c) : 0u;
    hist[t] = 0;
  }
  __syncthreads();
  #pragma unroll
  for (int j = 0; j < 8; ++j) {
    int e = e0 + j * 256 + tid;
    if (e < N_EDGES) {
      int d = dst[e];
      int b = d >> 8;
      u32 pos = base[b] + atomicAdd(&hist[b], 1u);
      bucketbuf[pos] = ((u32)src[e] << 8) | (u32)(d & 255);
    }
  }
  // fused x -> bf16 (pair) conversion; only when input is fp32
  if (f32in) {
    const int p0 = blockIdx.x * 4096;
    const float2* xf = (const float2*)x;
    for (int j = tid; j < 4096; j += 256) {
      int p = p0 + j;
      if (p < N_NODES * 32) {
        float2 v = xf[p];
        u32 w = ((u32)(u16)f2bf_bits(v.y) << 16) | (u32)(u16)f2bf_bits(v.x);
        xbf[p] = w;
      }
    }
  }
  // fused norm: block 0 computes inv_norm + publishes isfp32
  if (blockIdx.x == 0) {
    if (tid < 128) { float v = loadF(pw, tid, f32in); ns[tid] = v * v; }
    __syncthreads();
    for (int s = 64; s > 0; s >>= 1) {
      if (tid < s) ns[tid] += ns[tid + s];
      __syncthreads();
    }
    if (tid == 0) {
      ctl->inv_norm = 1.0f / sqrtf(ns[0]);
      ctl->isfp32 = f32in ? 1u : 0u;
    }
  }
}

// ------- CSR1 from buckets (inline bucket scan; no separate scan kernel) -------

__global__ void csr_from_buckets_kernel(const u32* __restrict__ bucketbuf, const int* __restrict__ bucket_cur,
                                        int* __restrict__ rowstart, float* __restrict__ dis,
                                        int* __restrict__ csr)
{
  __shared__ u32 cnt[256];
  __shared__ u32 loc[256];
  __shared__ u32 cur[256];
  const int b = blockIdx.x;
  const int tid = threadIdx.x;

  // inline scan of all bucket sizes -> off0 for this bucket
  int v = (tid < BKT) ? (bucket_cur[tid] - tid * BCAP) : 0;
  loc[tid] = (u32)v;
  __syncthreads();
  for (int off = 1; off < 256; off <<= 1) {
    u32 t = (tid >= off) ? loc[tid - off] : 0;
    __syncthreads();
    loc[tid] += t;
    __syncthreads();
  }
  const int bc = bucket_cur[b] - b * BCAP;
  const int off0 = (int)loc[b] - bc;
  if (b == BKT - 1 && tid == 0) rowstart[N_NODES] = (int)loc[BKT - 1];
  __syncthreads();

  const u32* buf = bucketbuf + (size_t)b * BCAP;
  cnt[tid] = 0;
  __syncthreads();
  for (int i = tid; i < bc; i += 256) atomicAdd(&cnt[buf[i] & 255u], 1u);
  __syncthreads();
  u32 c = cnt[tid];
  loc[tid] = c;
  __syncthreads();
  for (int off = 1; off < 256; off <<= 1) {
    u32 t = (tid >= off) ? loc[tid - off] : 0;
    __syncthreads();
    loc[tid] += t;
    __syncthreads();
  }
  int node = b * 256 + tid;
  u32 excl = loc[tid] - c;
  if (node < N_NODES) {
    rowstart[node] = off0 + (int)excl;
    dis[node] = rsqrtf(1.0f + (float)c);
  }
  cur[tid] = off0 + excl;
  __syncthreads();
  for (int i = tid; i < bc; i += 256) {
    u32 p = buf[i];
    u32 pos = atomicAdd(&cur[p & 255u], 1u);
    csr[pos] = (int)(p >> 8);
  }
}

// ------------- unified gather: 32 lanes/node, bf16x2 loads; ILP-4 -------------

__global__ void agg_gather64_kernel(const bf16* __restrict__ hW, const bf16* __restrict__ hWalt,
                                    const int* __restrict__ rowstart,
                                    const int* __restrict__ len, const int* __restrict__ csr,
                                    const float* __restrict__ dis,
                                    const void* __restrict__ b, const Ctl* __restrict__ ctl,
                                    bf16* __restrict__ agg, int M, int relusrc, int addbias)
{
  const bool f32 = ctl->isfp32 != 0;
  int gid = blockIdx.x * 256 + threadIdx.x;
  int d = gid >> 5;
  int lane = gid & 31;
  if (d >= M) return;
  const bf16x2* H = (const bf16x2*)(f32 ? hWalt : hW);
  float dd = dis[d];
  bf16x2 v = H[(size_t)d * 32 + lane];
  float ax = bf2f(v.x), ay = bf2f(v.y);
  if (relusrc) { ax = fmaxf(ax, 0.f); ay = fmaxf(ay, 0.f); }
  float sw = dd * dd;
  ax *= sw; ay *= sw;
  if (addbias) { ax += loadF(b, 2 * lane, f32); ay += loadF(b, 2 * lane + 1, f32); }
  int i = rowstart[d];
  int i1 = len ? (i + len[d]) : rowstart[d + 1];
  for (; i + 4 <= i1; i += 4) {
    int s0 = csr[i], s1 = csr[i + 1], s2 = csr[i + 2], s3 = csr[i + 3];
    float w0 = dd * dis[s0], w1 = dd * dis[s1], w2 = dd * dis[s2], w3 = dd * dis[s3];
    bf16x2 v0 = H[(size_t)s0 * 32 + lane];
    bf16x2 v1 = H[(size_t)s1 * 32 + lane];
    bf16x2 v2 = H[(size_t)s2 * 32 + lane];
    bf16x2 v3 = H[(size_t)s3 * 32 + lane];
    float x0 = bf2f(v0.x), y0 = bf2f(v0.y), x1 = bf2f(v1.x), y1 = bf2f(v1.y);
    float x2 = bf2f(v2.x), y2 = bf2f(v2.y), x3 = bf2f(v3.x), y3 = bf2f(v3.y);
    if (relusrc) {
      x0 = fmaxf(x0, 0.f); y0 = fmaxf(y0, 0.f); x1 = fmaxf(x1, 0.f); y1 = fmaxf(y1, 0.f);
      x2 = fmaxf(x2, 0.f); y2 = fmaxf(y2, 0.f); x3 = fmaxf(x3, 0.f); y3 = fmaxf(y3, 0.f);
    }
    ax += w0 * x0 + w1 * x1 + w2 * x2 + w3 * x3;
    ay += w0 * y0 + w1 * y1 + w2 * y2 + w3 * y3;
  }
  for (; i < i1; ++i) {
    int s = csr[i];
    float w = dd * dis[s];
    bf16x2 vv = H[(size_t)s * 32 + lane];
    float xx = bf2f(vv.x), yy = bf2f(vv.y);
    if (relusrc) { xx = fmaxf(xx, 0.f); yy = fmaxf(yy, 0.f); }
    ax += w * xx; ay += w * yy;
  }
  bf16x2 w2;
  w2.x = __float2bfloat16(ax);
  w2.y = __float2bfloat16(ay);
  ((bf16x2*)agg)[(size_t)d * 32 + lane] = w2;
}

// ---------------- MFMA GEMMs (16x16x32 bf16, fp32 acc) ----------------

// conv1: Y[N,128] = G[N,64] @ W1 + b1, fused pooling score/keys
__global__ void gemm_in_kernel(const bf16* __restrict__ G, const void* __restrict__ W,
                               const void* __restrict__ b, const void* __restrict__ pw,
                               bf16* __restrict__ Y, const Ctl* __restrict__ ctl,
                               float* __restrict__ score, u64* __restrict__ keys)
{
  __shared__ short Xs[64 * 72];
  __shared__ short Wt[128 * 72];
  __shared__ float bs[128];
  __shared__ float ps[128];
  const bool f32 = ctl->isfp32 != 0;
  const int tid = threadIdx.x;
  const int row0 = blockIdx.x * 64;

  for (int i = tid; i < 64 * 128; i += 256) {
    int k = i >> 7, n = i & 127;
    Wt[n * 72 + k] = f32 ? f2bf_bits(((const float*)W)[i]) : ((const short*)W)[i];
  }
  const u32* G2 = (const u32*)G;
  for (int p = tid; p < 64 * 32; p += 256) {
    int r = p >> 5, kp = p & 31;
    int gr = row0 + r;
    u32 v = (gr < N_NODES) ? G2[(size_t)gr * 32 + kp] : 0u;
    *(u32*)&Xs[r * 72 + 2 * kp] = v;
  }
  for (int i = tid; i < 128; i += 256) { bs[i] = loadF(b, i, f32); ps[i] = loadF(pw, i, f32); }
  __syncthreads();

  const int lane = tid & 63;
  const int w = tid >> 6;
  const int l16 = lane & 15;
  const int quad = lane >> 4;
  f32x4 acc[8];
  #pragma unroll
  for (int ct = 0; ct < 8; ++ct) acc[ct] = (f32x4){0.f, 0.f, 0.f, 0.f};
  const int arow = w * 16 + l16;
  #pragma unroll
  for (int kc = 0; kc < 2; ++kc) {
    short8 a = *(short8*)&Xs[arow * 72 + kc * 32 + quad * 8];
    #pragma unroll
    for (int ct = 0; ct < 8; ++ct) {
      short8 bb = *(short8*)&Wt[(ct * 16 + l16) * 72 + kc * 32 + quad * 8];
      acc[ct] = __builtin_amdgcn_mfma_f32_16x16x32_bf16(a, bb, acc[ct], 0, 0, 0);
    }
  }
  float inv_norm = ctl->inv_norm;
  #pragma unroll
  for (int r = 0; r < 4; ++r) {
    int gr = row0 + w * 16 + quad * 4 + r;
    float p = 0.f;
    #pragma unroll
    for (int ct = 0; ct < 8; ++ct) {
      int col = ct * 16 + l16;
      float h = acc[ct][r] + bs[col];
      if (gr < N_NODES) Y[(size_t)gr * 128 + col] = __float2bfloat16(h);
      p += fmaxf(h, 0.f) * ps[col];
    }
    p += __shfl_down(p, 8, 16);
    p += __shfl_down(p, 4, 16);
    p += __shfl_down(p, 2, 16);
    p += __shfl_down(p, 1, 16);
    if (l16 == 0 && gr < N_NODES) {
      float sc = tanhf(p * inv_norm);
      score[gr] = sc;
      u32 u = __float_as_uint(sc);
      u = (u & 0x80000000u) ? ~u : (u | 0x80000000u);
      keys[gr] = (((u64)u) << 16) | (u64)(0xFFFFu - (u32)gr);
    }
  }
}

// Y[M,64] = (relu?)X[M,128] @ W[128,64]; M multiple of 64
// kept!=null: X row = kept[row], apply relu*score[kept[row]] (fused TopK hp)
__global__ void gemm_128_64_kernel(const bf16* __restrict__ X, const void* __restrict__ W,
                                   bf16* __restrict__ Y, const Ctl* __restrict__ ctl,
                                   int M, int relu_x,
                                   const int* __restrict__ kept, const float* __restrict__ score)
{
  __shared__ short Xs[64 * 136];
  __shared__ short Wt[64 * 136];
  __shared__ int keptS[64];
  __shared__ float scS[64];
  const bool f32 = ctl->isfp32 != 0;
  const int tid = threadIdx.x;
  const int row0 = blockIdx.x * 64;

  if (kept) {
    for (int i = tid; i < 64; i += 256) {
      int o = kept[row0 + i];
      keptS[i] = o;
      scS[i] = score[o];
    }
  }
  __syncthreads();

  for (int i = tid; i < 128 * 64; i += 256) {
    int k = i >> 6, n = i & 63;
    Wt[n * 136 + k] = f32 ? f2bf_bits(((const float*)W)[i]) : ((const short*)W)[i];
  }
  const u32* X2 = (const u32*)X;
  for (int p = tid; p < 64 * 64; p += 256) {
    int r = p >> 6, kp = p & 63;
    int srow = kept ? keptS[r] : (row0 + r);
    u32 v = X2[(size_t)srow * 64 + kp];
    if (relu_x) {
      if (v & 0x8000u) v &= 0xFFFF0000u;
      if (v & 0x80000000u) v &= 0x0000FFFFu;
    }
    if (kept) {
      bf16x2 h = *(bf16x2*)&v;
      float s = scS[r];
      bf16x2 o;
      o.x = __float2bfloat16(fmaxf(bf2f(h.x), 0.f) * s);
      o.y = __float2bfloat16(fmaxf(bf2f(h.y), 0.f) * s);
      v = *(u32*)&o;
    }
    *(u32*)&Xs[r * 136 + 2 * kp] = v;
  }
  __syncthreads();

  const int lane = tid & 63;
  const int w = tid >> 6;
  const int l16 = lane & 15;
  const int quad = lane >> 4;
  f32x4 acc[4];
  #pragma unroll
  for (int ct = 0; ct < 4; ++ct) acc[ct] = (f32x4){0.f, 0.f, 0.f, 0.f};
  const int arow = w * 16 + l16;
  #pragma unroll
  for (int kc = 0; kc < 4; ++kc) {
    short8 a = *(short8*)&Xs[arow * 136 + kc * 32 + quad * 8];
    #pragma unroll
    for (int ct = 0; ct < 4; ++ct) {
      short8 bb = *(short8*)&Wt[(ct * 16 + l16) * 136 + kc * 32 + quad * 8];
      acc[ct] = __builtin_amdgcn_mfma_f32_16x16x32_bf16(a, bb, acc[ct], 0, 0, 0);
    }
  }
  #pragma unroll
  for (int ct = 0; ct < 4; ++ct)
    #pragma unroll
    for (int r = 0; r < 4; ++r) {
      int gr = row0 + w * 16 + quad * 4 + r;
      Y[(size_t)gr * 64 + ct * 16 + l16] = __float2bfloat16(acc[ct][r]);
    }
}

// conv3: Y[M,128] = X[M,64] @ W[64,128] + b; M multiple of 64
__global__ void gemm_64_128_kernel(const bf16* __restrict__ X, const void* __restrict__ W,
                                   const void* __restrict__ b, bf16* __restrict__ Y,
                                   const Ctl* __restrict__ ctl, int M)
{
  __shared__ short Xs[64 * 72];
  __shared__ short Wt[128 * 72];
  __shared__ float bs[128];
  const bool f32 = ctl->isfp32 != 0;
  const int tid = threadIdx.x;
  const int row0 = blockIdx.x * 64;

  for (int i = tid; i < 64 * 128; i += 256) {
    int k = i >> 7, n = i & 127;
    Wt[n * 72 + k] = f32 ? f2bf_bits(((const float*)W)[i]) : ((const short*)W)[i];
  }
  const u32* X2 = (const u32*)X;
  for (int p = tid; p < 64 * 32; p += 256) {
    int r = p >> 5, kp = p & 31;
    *(u32*)&Xs[r * 72 + 2 * kp] = X2[(size_t)(row0 + r) * 32 + kp];
  }
  for (int i = tid; i < 128; i += 256) bs[i] = loadF(b, i, f32);
  __syncthreads();

  const int lane = tid & 63;
  const int w = tid >> 6;
  const int l16 = lane & 15;
  const int quad = lane >> 4;
  f32x4 acc[8];
  #pragma unroll
  for (int ct = 0; ct < 8; ++ct) acc[ct] = (f32x4){0.f, 0.f, 0.f, 0.f};
  const int arow = w * 16 + l16;
  #pragma unroll
  for (int kc = 0; kc < 2; ++kc) {
    short8 a = *(short8*)&Xs[arow * 72 + kc * 32 + quad * 8];
    #pragma unroll
    for (int ct = 0; ct < 8; ++ct) {
      short8 bb = *(short8*)&Wt[(ct * 16 + l16) * 72 + kc * 32 + quad * 8];
      acc[ct] = __builtin_amdgcn_mfma_f32_16x16x32_bf16(a, bb, acc[ct], 0, 0, 0);
    }
  }
  #pragma unroll
  for (int ct = 0; ct < 8; ++ct)
    #pragma unroll
    for (int r = 0; r < 4; ++r) {
      int gr = row0 + w * 16 + quad * 4 + r;
      int col = ct * 16 + l16;
      Y[(size_t)gr * 128 + col] = __float2bfloat16(acc[ct][r] + bs[col]);
    }
}

// conv4: gather + per-block mean-pool partial + fused final reduce (last block)
__global__ void agg_gather64_final_kernel(const bf16* __restrict__ hW, const int* __restrict__ rowstart,
                                          const int* __restrict__ len, const int* __restrict__ csr,
                                          const float* __restrict__ dis,
                                          float* __restrict__ partial, int M, int nblk,
                                          const void* __restrict__ b, Ctl* ctl,
                                          void* __restrict__ out)
{
  __shared__ float cs[64];
  __shared__ int lastflag;
  const int tid = threadIdx.x;
  if (tid < 64) cs[tid] = 0.f;
  __syncthreads();
  const int lane = tid & 31;
  const bf16x2* H = (const bf16x2*)hW;
  for (int d = (blockIdx.x * 256 + tid) >> 5; d < M; d += nblk * 8) {
    float dd = dis[d];
    bf16x2 v = H[(size_t)d * 32 + lane];
    float sw = dd * dd;
    float ax = bf2f(v.x) * sw, ay = bf2f(v.y) * sw;
    int i = rowstart[d];
    int i1 = i + len[d];
    for (; i + 4 <= i1; i += 4) {
      int s0 = csr[i], s1 = csr[i + 1], s2 = csr[i + 2], s3 = csr[i + 3];
      float w0 = dd * dis[s0], w1 = dd * dis[s1], w2 = dd * dis[s2], w3 = dd * dis[s3];
      bf16x2 v0 = H[(size_t)s0 * 32 + lane];
      bf16x2 v1 = H[(size_t)s1 * 32 + lane];
      bf16x2 v2 = H[(size_t)s2 * 32 + lane];
      bf16x2 v3 = H[(size_t)s3 * 32 + lane];
      ax += w0 * bf2f(v0.x) + w1 * bf2f(v1.x) + w2 * bf2f(v2.x) + w3 * bf2f(v3.x);
      ay += w0 * bf2f(v0.y) + w1 * bf2f(v1.y) + w2 * bf2f(v2.y) + w3 * bf2f(v3.y);
    }
    for (; i < i1; ++i) {
      int s = csr[i];
      float w = dd * dis[s];
      bf16x2 vv = H[(size_t)s * 32 + lane];
      ax += w * bf2f(vv.x);
      ay += w * bf2f(vv.y);
    }
    atomicAdd(&cs[2 * lane], ax);
    atomicAdd(&cs[2 * lane + 1], ay);
  }
  __syncthreads();
  if (tid < 64) partial[(size_t)tid * nblk + blockIdx.x] = cs[tid];
  // fused reduce: last-arriving block sums partials and writes output
  __threadfence();
  __syncthreads();
  if (tid == 0) {
    u32 old = atomicAdd(&ctl->done2, 1u);
    lastflag = (old == (u32)(nblk - 1));
  }
  __syncthreads();
  if (!lastflag) return;
  __threadfence();
  const int c = tid & 63;
  const int part = tid >> 6;           // 0..3
  float s = 0.f;
  for (int j = part; j < nblk; j += 4) s += partial[(size_t)c * nblk + j];
  __shared__ float rs[256];
  rs[tid] = s;
  __syncthreads();
  if (tid < 64) {
    const bool f32 = ctl->isfp32 != 0;
    float val = rs[tid] + rs[tid + 64] + rs[tid + 128] + rs[tid + 192];
    val = val / (float)K_KEEP + loadF(b, tid, f32);
    if (f32) ((float*)out)[tid] = val;
    else     ((bf16*)out)[tid] = __float2bfloat16(val);
  }
}

// ---- persistent TopK: six 8-bit radix passes + mark, ONE kernel (spin-barrier) ----
// 196 blocks x 256 threads (784 waves, tiny LDS/VGPR) -> trivially co-resident.

__global__ void radix_topk_kernel(const u64* __restrict__ keys, Ctl* ctl,
                                  int* __restrict__ new_idx, int* __restrict__ kept, int nblocks)
{
  __shared__ u32 lh[256];
  __shared__ int lastflag;
  const int tid = threadIdx.x;
  const int i = blockIdx.x * 256 + tid;
  const bool valid = (i < N_NODES);
  const u64 key = valid ? keys[i] : 0ull;

  for (int p = 0; p < 6; ++p) {
    const int shift = 40 - 8 * p;
    if (tid == 0) {
      while (__hip_atomic_load(&ctl->gen, __ATOMIC_ACQUIRE, SCOPE_AGENT) < (u32)p)
        __builtin_amdgcn_s_sleep(1);
    }
    __syncthreads();
    const u64 prefix = __hip_atomic_load(&ctl->prefix, __ATOMIC_RELAXED, SCOPE_AGENT);
    lh[tid] = 0;
    __syncthreads();
    if (valid && (key >> (shift + 8)) == (prefix >> (shift + 8)))
      atomicAdd(&lh[(u32)((key >> shift) & 0xFF)], 1u);
    __syncthreads();
    u32 c = lh[tid];
    if (c) atomicAdd(&ctl->hist[tid], c);
    __threadfence();
    __syncthreads();
    if (tid == 0) {
      u32 old = atomicAdd(&ctl->done, 1u);
      lastflag = (old == (u32)((p + 1) * nblocks - 1));
    }
    __syncthreads();
    if (lastflag) {
      u32 cc = atomicExch(&ctl->hist[tid], 0u);   // coherent read + zero for next pass
      lh[tid] = cc;
      __syncthreads();
      if (tid == 0) {
        u32 kr = __hip_atomic_load(&ctl->kremain, __ATOMIC_RELAXED, SCOPE_AGENT);
        u32 cum = 0;
        int sel = 0;
        for (int v = 255; v >= 0; --v) {
          u32 c2 = lh[v];
          if (cum + c2 >= kr) { sel = v; break; }
          cum += c2;
        }
        __hip_atomic_store(&ctl->kremain, kr - cum, __ATOMIC_RELAXED, SCOPE_AGENT);
        __hip_atomic_store(&ctl->prefix, prefix | (((u64)(u32)sel) << shift),
                           __ATOMIC_RELAXED, SCOPE_AGENT);
        __hip_atomic_store(&ctl->gen, (u32)(p + 1), __ATOMIC_RELEASE, SCOPE_AGENT);
      }
    }
  }

  // fused mark (after final pick)
  if (tid == 0) {
    while (__hip_atomic_load(&ctl->gen, __ATOMIC_ACQUIRE, SCOPE_AGENT) < 6u)
      __builtin_amdgcn_s_sleep(1);
  }
  __syncthreads();
  const u64 fp = __hip_atomic_load(&ctl->prefix, __ATOMIC_RELAXED, SCOPE_AGENT);
  if (valid) {
    if (key >= fp) {
      int pos = (int)atomicAdd(&ctl->cnt, 1u);
      new_idx[i] = pos;
      kept[pos] = i;
    } else {
      new_idx[i] = -1;
    }
  }
}

// ------- CSR2 in ONE kernel: count + wave-aggregated alloc + fill (order-free rows) -------

__global__ void csr2_build_kernel(const int* __restrict__ kept, const int* __restrict__ rowstart1,
                                  const int* __restrict__ csr1, const int* __restrict__ new_idx,
                                  Ctl* ctl, int* __restrict__ rowstart2, int* __restrict__ len2,
                                  float* __restrict__ dis2, int* __restrict__ csr2)
{
  int kp = blockIdx.x * 256 + threadIdx.x;
  int lane = threadIdx.x & 63;
  int c = 0;
  int i0 = 0, i1 = 0;
  if (kp < K_KEEP) {
    int o = kept[kp];
    i0 = rowstart1[o]; i1 = rowstart1[o + 1];
    int i = i0;
    for (; i + 4 <= i1; i += 4) {
      int s0 = csr1[i], s1 = csr1[i + 1], s2 = csr1[i + 2], s3 = csr1[i + 3];
      c += (new_idx[s0] >= 0) + (new_idx[s1] >= 0) + (new_idx[s2] >= 0) + (new_idx[s3] >= 0);
    }
    for (; i < i1; ++i) c += (new_idx[csr1[i]] >= 0);
  }
  // wave inclusive scan of c
  int pre = c;
  #pragma unroll
  for (int off = 1; off < 64; off <<= 1) {
    int t = __shfl_up(pre, off);
    if (lane >= off) pre += t;
  }
  int wtot = __shfl(pre, 63);
  int wbase = 0;
  if (lane == 0) wbase = (int)atomicAdd(&ctl->pad, (u32)wtot);
  wbase = __shfl(wbase, 0);
  int base = wbase + pre - c;
  if (kp < K_KEEP) {
    rowstart2[kp] = base;
    len2[kp] = c;
    dis2[kp] = rsqrtf(1.0f + (float)c);
    int w = base;
    for (int i = i0; i < i1; ++i) {
      int ns = new_idx[csr1[i]];
      if (ns >= 0) csr2[w++] = ns;
    }
  }
}

// ---------------- launch ----------------

extern "C" void kernel_launch(void* const* d_in, const int* in_sizes, int n_in,
                              void* d_out, int out_size, void* d_ws, size_t ws_size,
                              hipStream_t stream)
{
  const void* x  = d_in[0];
  const int*  ei = (const int*)d_in[1];
  const void* W1 = d_in[3];
  const void* b1 = d_in[4];
  const void* pw = d_in[5];
  const void* W2 = d_in[6];
  const void* b2 = d_in[7];
  const void* W3 = d_in[8];
  const void* b3 = d_in[9];
  const void* W4 = d_in[10];
  const void* b4 = d_in[11];

  const int* src = ei;
  const int* dst = ei + N_EDGES;

  float* F = (float*)d_ws;
  bf16*  A16       = (bf16*)F;               // N x 128 bf16
  bf16*  B16       = (bf16*)(F + 3200000);   // N x 128 bf16
  bf16*  C16       = (bf16*)(F + 6400000);   // K x 128 bf16 (also conv1's G [N x 64])
  u32*   xbf       = (u32*)(F + 9000000);    // N x 32 u32 (x as bf16 pairs, only if fp32 input)
  float* dis1      = F + 10600000;           // 50000
  float* dis2      = F + 10650000;           // 40000
  float* score     = F + 10690000;           // 50000
  u64*   keys      = (u64*)(F + 10740000);   // 50000 u64
  int*   new_idx   = (int*)(F + 10840000);   // 50000
  int*   kept      = (int*)(F + 10890000);   // 40000
  int*   len2      = (int*)(F + 10930000);   // 40000
  int*   rowstart1 = (int*)(F + 10970000);   // 50001
  int*   rowstart2 = (int*)(F + 11020004);   // 40000
  int*   csr1      = (int*)(F + 11060008);   // 800000
  int*   csr2      = (int*)(F + 11860008);   // 800000
  Ctl*   ctl       = (Ctl*)(F + 12660008);   // ~1.1 KB (region has 2.3 KB slack)
  int*   detcnt    = (int*)(F + 12660856);   // 64
  int*   bucket_cur= (int*)(F + 12660920);   // 196
  u32*   bucketbuf = (u32*)(F + 12726908);   // 196*6144
  float* partial   = F + 13931132;           // 64 x 1024

  const int NB1 = (N_NODES + 255) / 256;     // 196
  const int EB2 = (N_EDGES + 2047) / 2048;   // 391
  const int GB1 = (N_NODES + 63) / 64;       // 782
  const int AB1 = N_NODES * 32 / 256;        // 6250
  const int ABK = K_KEEP * 32 / 256;         // 5000
  const int CB2 = (K_KEEP + 255) / 256;      // 157
  const int NBF = 1024;                      // final-gather blocks

  init_kernel<<<NB1, 256, 0, stream>>>((const unsigned short*)x, bucket_cur, detcnt, ctl);

  // CSR graph 1 via bucket sort (+fused dtype/norm, +x->bf16 conversion iff fp32 input)
  bucket_scatter_kernel<<<EB2, 256, 0, stream>>>(src, dst, bucket_cur, bucketbuf, x, xbf,
                                                 detcnt, pw, ctl);
  csr_from_buckets_kernel<<<BKT, 256, 0, stream>>>(bucketbuf, bucket_cur, rowstart1, dis1, csr1);

  // conv1 (gather-first on bf16 x): G = A_norm . x ; h1 = G @ W1 + b1 (+fused score/keys)
  agg_gather64_kernel<<<AB1, 256, 0, stream>>>((const bf16*)x, (const bf16*)xbf, rowstart1, nullptr,
                                               csr1, dis1, nullptr, ctl, C16, N_NODES, 0, 0);
  gemm_in_kernel<<<GB1, 256, 0, stream>>>(C16, W1, b1, pw, B16, ctl, score, keys);

  // top-K select: ONE persistent kernel (6 radix passes + mark)
  radix_topk_kernel<<<NB1, 256, 0, stream>>>(keys, ctl, new_idx, kept, NB1);

  // CSR graph 2 in one kernel (row bases via wave-aggregated atomic; order-free)
  csr2_build_kernel<<<CB2, 256, 0, stream>>>(kept, rowstart1, csr1, new_idx, ctl,
                                             rowstart2, len2, dis2, csr2);

  // conv2: gemm-first (fused hp: relu*score on kept rows): A = hp @ W2 ; h2 = gather(A) + b2
  gemm_128_64_kernel<<<K_KEEP / 64, 256, 0, stream>>>(B16, W2, A16, ctl, K_KEEP, 0, kept, score);
  agg_gather64_kernel<<<ABK, 256, 0, stream>>>(A16, A16, rowstart2, len2, csr2, dis2, b2, ctl, C16, K_KEEP, 0, 1);

  // conv3: gather-first: G = gather(relu(h2)) ; h3 = G @ W3 + b3
  agg_gather64_kernel<<<ABK, 256, 0, stream>>>(C16, C16, rowstart2, len2, csr2, dis2, b3, ctl, A16, K_KEEP, 1, 0);
  gemm_64_128_kernel<<<K_KEEP / 64, 256, 0, stream>>>(A16, W3, b3, B16, ctl, K_KEEP);

  // conv4: gemm-first: A = relu(h3) @ W4 ; partials = gather(A) ; fused final reduce
  gemm_128_64_kernel<<<K_KEEP / 64, 256, 0, stream>>>(B16, W4, A16, ctl, K_KEEP, 1, nullptr, nullptr);
  agg_gather64_final_kernel<<<NBF, 256, 0, stream>>>(A16, rowstart2, len2, csr2, dis2,
                                                     partial, K_KEEP, NBF, b4, ctl, d_out);
}

// Round 5
// 470.005 us; speedup vs baseline: 1.3344x; 1.3344x over previous
//
#include <hip/hip_runtime.h>
#include <hip/hip_bf16.h>
#include <stdint.h>

#define N_NODES 50000
#define N_EDGES 800000
#define K_KEEP  40000
#define BKT     196        // ceil(N_NODES/256) dst-range buckets
#define BCAP    6144       // per-bucket capacity (mean 4081, +32 sigma)

typedef unsigned long long u64;
typedef unsigned int u32;
typedef unsigned short u16;
typedef __hip_bfloat16 bf16;
typedef __hip_bfloat162 bf16x2;
typedef __attribute__((ext_vector_type(8))) short short8;
typedef __attribute__((ext_vector_type(4))) float f32x4;

#define SCOPE_AGENT __HIP_MEMORY_SCOPE_AGENT

struct Ctl {
  u64 prefix;
  u32 kremain;
  u32 cnt;
  float inv_norm;
  u32 isfp32;
  u32 done;         // radix pass arrival counter (reset by picker each pass)
  u32 pad;          // csr2 edge cursor
  u32 gen;          // TopK resolved-early flag
  u32 done2;        // final-gather arrival counter
  u32 hist[256];    // radix histogram (LDS-aggregated flushes only)
};

__device__ __forceinline__ float bf2f(bf16 v) { return __bfloat162float(v); }
__device__ __forceinline__ float loadF(const void* p, size_t i, bool f32) {
  return f32 ? ((const float*)p)[i] : bf2f(((const bf16*)p)[i]);
}
__device__ __forceinline__ short f2bf_bits(float f) {
  bf16 t = __float2bfloat16(f);
  return *(const short*)&t;
}

// ---------------- init (+parallel dtype detect, proven R5-R8) ----------------

__global__ void init_kernel(const unsigned short* __restrict__ x16,
                            int* __restrict__ bucket_cur, int* __restrict__ detcnt, Ctl* ctl) {
  __shared__ u32 dsh[256];
  int i = blockIdx.x * 256 + threadIdx.x;
  if (i < BKT) bucket_cur[i] = i * BCAP;
  if (blockIdx.x == 0) {
    ctl->hist[threadIdx.x] = 0u;
    if (threadIdx.x == 0) {
      ctl->prefix = 0ull; ctl->kremain = K_KEEP; ctl->cnt = 0u;
      ctl->done = 0u; ctl->pad = 0u; ctl->gen = 0u; ctl->done2 = 0u;
    }
  }
  if (blockIdx.x < 64) {
    int base = blockIdx.x * 2048;
    u32 c = 0;
    for (int j = threadIdx.x; j < 2048; j += 256) {
      u32 h = x16[base + j];
      if ((h & 0x7F80u) == 0x7F80u) c++;
    }
    dsh[threadIdx.x] = c;
    __syncthreads();
    for (int s = 128; s > 0; s >>= 1) {
      if (threadIdx.x < s) dsh[threadIdx.x] += dsh[threadIdx.x + s];
      __syncthreads();
    }
    if (threadIdx.x == 0) detcnt[blockIdx.x] = (int)dsh[0];
  }
}

// ------- CSR1 bucket scatter (proven R8) + fused dtype/norm + fp32->bf16 convert -------

__global__ void bucket_scatter_kernel(const int* __restrict__ src, const int* __restrict__ dst,
                                      int* __restrict__ bucket_cur, u32* __restrict__ bucketbuf,
                                      const void* __restrict__ x, u32* __restrict__ xbf,
                                      const int* __restrict__ detcnt, const void* __restrict__ pw,
                                      Ctl* ctl)
{
  __shared__ u32 hist[BKT];
  __shared__ u32 base[BKT];
  __shared__ int f32sh;
  __shared__ float ns[128];
  const int tid = threadIdx.x;
  const int e0 = blockIdx.x * 2048;

  // dtype detect from detcnt (written by init, prior dispatch)
  if (tid < 64) {
    int dc = detcnt[tid];
    for (int off = 32; off; off >>= 1) dc += __shfl_down(dc, off);
    if (tid == 0) f32sh = (dc >= 16) ? 1 : 0;
  }
  for (int t = tid; t < BKT; t += 256) hist[t] = 0;
  __syncthreads();
  const bool f32in = f32sh != 0;

  #pragma unroll
  for (int j = 0; j < 8; ++j) {
    int e = e0 + j * 256 + tid;
    if (e < N_EDGES) atomicAdd(&hist[dst[e] >> 8], 1u);
  }
  __syncthreads();
  for (int t = tid; t < BKT; t += 256) {
    u32 c = hist[t];
    base[t] = c ? (u32)atomicAdd(&bucket_cur[t], (int)c) : 0u;
    hist[t] = 0;
  }
  __syncthreads();
  #pragma unroll
  for (int j = 0; j < 8; ++j) {
    int e = e0 + j * 256 + tid;
    if (e < N_EDGES) {
      int d = dst[e];
      int b = d >> 8;
      u32 pos = base[b] + atomicAdd(&hist[b], 1u);
      bucketbuf[pos] = ((u32)src[e] << 8) | (u32)(d & 255);
    }
  }
  // fused x -> bf16 (pair) conversion; only when input is fp32
  if (f32in) {
    const int p0 = blockIdx.x * 4096;
    const float2* xf = (const float2*)x;
    for (int j = tid; j < 4096; j += 256) {
      int p = p0 + j;
      if (p < N_NODES * 32) {
        float2 v = xf[p];
        u32 w = ((u32)(u16)f2bf_bits(v.y) << 16) | (u32)(u16)f2bf_bits(v.x);
        xbf[p] = w;
      }
    }
  }
  // fused norm: block 0 computes inv_norm + publishes isfp32
  if (blockIdx.x == 0) {
    if (tid < 128) { float v = loadF(pw, tid, f32in); ns[tid] = v * v; }
    __syncthreads();
    for (int s = 64; s > 0; s >>= 1) {
      if (tid < s) ns[tid] += ns[tid + s];
      __syncthreads();
    }
    if (tid == 0) {
      ctl->inv_norm = 1.0f / sqrtf(ns[0]);
      ctl->isfp32 = f32in ? 1u : 0u;
    }
  }
}

// ------- CSR1 from buckets (inline bucket scan; no separate scan kernel) -------

__global__ void csr_from_buckets_kernel(const u32* __restrict__ bucketbuf, const int* __restrict__ bucket_cur,
                                        int* __restrict__ rowstart, float* __restrict__ dis,
                                        int* __restrict__ csr)
{
  __shared__ u32 cnt[256];
  __shared__ u32 loc[256];
  __shared__ u32 cur[256];
  const int b = blockIdx.x;
  const int tid = threadIdx.x;

  // inline scan of all bucket sizes -> off0 for this bucket
  int v = (tid < BKT) ? (bucket_cur[tid] - tid * BCAP) : 0;
  loc[tid] = (u32)v;
  __syncthreads();
  for (int off = 1; off < 256; off <<= 1) {
    u32 t = (tid >= off) ? loc[tid - off] : 0;
    __syncthreads();
    loc[tid] += t;
    __syncthreads();
  }
  const int bc = bucket_cur[b] - b * BCAP;
  const int off0 = (int)loc[b] - bc;
  if (b == BKT - 1 && tid == 0) rowstart[N_NODES] = (int)loc[BKT - 1];
  __syncthreads();

  const u32* buf = bucketbuf + (size_t)b * BCAP;
  cnt[tid] = 0;
  __syncthreads();
  for (int i = tid; i < bc; i += 256) atomicAdd(&cnt[buf[i] & 255u], 1u);
  __syncthreads();
  u32 c = cnt[tid];
  loc[tid] = c;
  __syncthreads();
  for (int off = 1; off < 256; off <<= 1) {
    u32 t = (tid >= off) ? loc[tid - off] : 0;
    __syncthreads();
    loc[tid] += t;
    __syncthreads();
  }
  int node = b * 256 + tid;
  u32 excl = loc[tid] - c;
  if (node < N_NODES) {
    rowstart[node] = off0 + (int)excl;
    dis[node] = rsqrtf(1.0f + (float)c);
  }
  cur[tid] = off0 + excl;
  __syncthreads();
  for (int i = tid; i < bc; i += 256) {
    u32 p = buf[i];
    u32 pos = atomicAdd(&cur[p & 255u], 1u);
    csr[pos] = (int)(p >> 8);
  }
}

// ------------- unified gather: 32 lanes/node, bf16x2 loads; ILP-4 -------------

__global__ void agg_gather64_kernel(const bf16* __restrict__ hW, const bf16* __restrict__ hWalt,
                                    const int* __restrict__ rowstart,
                                    const int* __restrict__ len, const int* __restrict__ csr,
                                    const float* __restrict__ dis,
                                    const void* __restrict__ b, const Ctl* __restrict__ ctl,
                                    bf16* __restrict__ agg, int M, int relusrc, int addbias)
{
  const bool f32 = ctl->isfp32 != 0;
  int gid = blockIdx.x * 256 + threadIdx.x;
  int d = gid >> 5;
  int lane = gid & 31;
  if (d >= M) return;
  const bf16x2* H = (const bf16x2*)(f32 ? hWalt : hW);
  float dd = dis[d];
  bf16x2 v = H[(size_t)d * 32 + lane];
  float ax = bf2f(v.x), ay = bf2f(v.y);
  if (relusrc) { ax = fmaxf(ax, 0.f); ay = fmaxf(ay, 0.f); }
  float sw = dd * dd;
  ax *= sw; ay *= sw;
  if (addbias) { ax += loadF(b, 2 * lane, f32); ay += loadF(b, 2 * lane + 1, f32); }
  int i = rowstart[d];
  int i1 = len ? (i + len[d]) : rowstart[d + 1];
  for (; i + 4 <= i1; i += 4) {
    int s0 = csr[i], s1 = csr[i + 1], s2 = csr[i + 2], s3 = csr[i + 3];
    float w0 = dd * dis[s0], w1 = dd * dis[s1], w2 = dd * dis[s2], w3 = dd * dis[s3];
    bf16x2 v0 = H[(size_t)s0 * 32 + lane];
    bf16x2 v1 = H[(size_t)s1 * 32 + lane];
    bf16x2 v2 = H[(size_t)s2 * 32 + lane];
    bf16x2 v3 = H[(size_t)s3 * 32 + lane];
    float x0 = bf2f(v0.x), y0 = bf2f(v0.y), x1 = bf2f(v1.x), y1 = bf2f(v1.y);
    float x2 = bf2f(v2.x), y2 = bf2f(v2.y), x3 = bf2f(v3.x), y3 = bf2f(v3.y);
    if (relusrc) {
      x0 = fmaxf(x0, 0.f); y0 = fmaxf(y0, 0.f); x1 = fmaxf(x1, 0.f); y1 = fmaxf(y1, 0.f);
      x2 = fmaxf(x2, 0.f); y2 = fmaxf(y2, 0.f); x3 = fmaxf(x3, 0.f); y3 = fmaxf(y3, 0.f);
    }
    ax += w0 * x0 + w1 * x1 + w2 * x2 + w3 * x3;
    ay += w0 * y0 + w1 * y1 + w2 * y2 + w3 * y3;
  }
  for (; i < i1; ++i) {
    int s = csr[i];
    float w = dd * dis[s];
    bf16x2 vv = H[(size_t)s * 32 + lane];
    float xx = bf2f(vv.x), yy = bf2f(vv.y);
    if (relusrc) { xx = fmaxf(xx, 0.f); yy = fmaxf(yy, 0.f); }
    ax += w * xx; ay += w * yy;
  }
  bf16x2 w2;
  w2.x = __float2bfloat16(ax);
  w2.y = __float2bfloat16(ay);
  ((bf16x2*)agg)[(size_t)d * 32 + lane] = w2;
}

// ---------------- MFMA GEMMs (16x16x32 bf16, fp32 acc) ----------------

// conv1: Y[N,128] = G[N,64] @ W1 + b1, fused pooling score/keys
__global__ void gemm_in_kernel(const bf16* __restrict__ G, const void* __restrict__ W,
                               const void* __restrict__ b, const void* __restrict__ pw,
                               bf16* __restrict__ Y, const Ctl* __restrict__ ctl,
                               float* __restrict__ score, u64* __restrict__ keys)
{
  __shared__ short Xs[64 * 72];
  __shared__ short Wt[128 * 72];
  __shared__ float bs[128];
  __shared__ float ps[128];
  const bool f32 = ctl->isfp32 != 0;
  const int tid = threadIdx.x;
  const int row0 = blockIdx.x * 64;

  for (int i = tid; i < 64 * 128; i += 256) {
    int k = i >> 7, n = i & 127;
    Wt[n * 72 + k] = f32 ? f2bf_bits(((const float*)W)[i]) : ((const short*)W)[i];
  }
  const u32* G2 = (const u32*)G;
  for (int p = tid; p < 64 * 32; p += 256) {
    int r = p >> 5, kp = p & 31;
    int gr = row0 + r;
    u32 v = (gr < N_NODES) ? G2[(size_t)gr * 32 + kp] : 0u;
    *(u32*)&Xs[r * 72 + 2 * kp] = v;
  }
  for (int i = tid; i < 128; i += 256) { bs[i] = loadF(b, i, f32); ps[i] = loadF(pw, i, f32); }
  __syncthreads();

  const int lane = tid & 63;
  const int w = tid >> 6;
  const int l16 = lane & 15;
  const int quad = lane >> 4;
  f32x4 acc[8];
  #pragma unroll
  for (int ct = 0; ct < 8; ++ct) acc[ct] = (f32x4){0.f, 0.f, 0.f, 0.f};
  const int arow = w * 16 + l16;
  #pragma unroll
  for (int kc = 0; kc < 2; ++kc) {
    short8 a = *(short8*)&Xs[arow * 72 + kc * 32 + quad * 8];
    #pragma unroll
    for (int ct = 0; ct < 8; ++ct) {
      short8 bb = *(short8*)&Wt[(ct * 16 + l16) * 72 + kc * 32 + quad * 8];
      acc[ct] = __builtin_amdgcn_mfma_f32_16x16x32_bf16(a, bb, acc[ct], 0, 0, 0);
    }
  }
  float inv_norm = ctl->inv_norm;
  #pragma unroll
  for (int r = 0; r < 4; ++r) {
    int gr = row0 + w * 16 + quad * 4 + r;
    float p = 0.f;
    #pragma unroll
    for (int ct = 0; ct < 8; ++ct) {
      int col = ct * 16 + l16;
      float h = acc[ct][r] + bs[col];
      if (gr < N_NODES) Y[(size_t)gr * 128 + col] = __float2bfloat16(h);
      p += fmaxf(h, 0.f) * ps[col];
    }
    p += __shfl_down(p, 8, 16);
    p += __shfl_down(p, 4, 16);
    p += __shfl_down(p, 2, 16);
    p += __shfl_down(p, 1, 16);
    if (l16 == 0 && gr < N_NODES) {
      float sc = tanhf(p * inv_norm);
      score[gr] = sc;
      u32 u = __float_as_uint(sc);
      u = (u & 0x80000000u) ? ~u : (u | 0x80000000u);
      keys[gr] = (((u64)u) << 16) | (u64)(0xFFFFu - (u32)gr);
    }
  }
}

// Y[M,64] = (relu?)X[M,128] @ W[128,64]; M multiple of 64
// kept!=null: X row = kept[row], apply relu*score[kept[row]] (fused TopK hp)
__global__ void gemm_128_64_kernel(const bf16* __restrict__ X, const void* __restrict__ W,
                                   bf16* __restrict__ Y, const Ctl* __restrict__ ctl,
                                   int M, int relu_x,
                                   const int* __restrict__ kept, const float* __restrict__ score)
{
  __shared__ short Xs[64 * 136];
  __shared__ short Wt[64 * 136];
  __shared__ int keptS[64];
  __shared__ float scS[64];
  const bool f32 = ctl->isfp32 != 0;
  const int tid = threadIdx.x;
  const int row0 = blockIdx.x * 64;

  if (kept) {
    for (int i = tid; i < 64; i += 256) {
      int o = kept[row0 + i];
      keptS[i] = o;
      scS[i] = score[o];
    }
  }
  __syncthreads();

  for (int i = tid; i < 128 * 64; i += 256) {
    int k = i >> 6, n = i & 63;
    Wt[n * 136 + k] = f32 ? f2bf_bits(((const float*)W)[i]) : ((const short*)W)[i];
  }
  const u32* X2 = (const u32*)X;
  for (int p = tid; p < 64 * 64; p += 256) {
    int r = p >> 6, kp = p & 63;
    int srow = kept ? keptS[r] : (row0 + r);
    u32 v = X2[(size_t)srow * 64 + kp];
    if (relu_x) {
      if (v & 0x8000u) v &= 0xFFFF0000u;
      if (v & 0x80000000u) v &= 0x0000FFFFu;
    }
    if (kept) {
      bf16x2 h = *(bf16x2*)&v;
      float s = scS[r];
      bf16x2 o;
      o.x = __float2bfloat16(fmaxf(bf2f(h.x), 0.f) * s);
      o.y = __float2bfloat16(fmaxf(bf2f(h.y), 0.f) * s);
      v = *(u32*)&o;
    }
    *(u32*)&Xs[r * 136 + 2 * kp] = v;
  }
  __syncthreads();

  const int lane = tid & 63;
  const int w = tid >> 6;
  const int l16 = lane & 15;
  const int quad = lane >> 4;
  f32x4 acc[4];
  #pragma unroll
  for (int ct = 0; ct < 4; ++ct) acc[ct] = (f32x4){0.f, 0.f, 0.f, 0.f};
  const int arow = w * 16 + l16;
  #pragma unroll
  for (int kc = 0; kc < 4; ++kc) {
    short8 a = *(short8*)&Xs[arow * 136 + kc * 32 + quad * 8];
    #pragma unroll
    for (int ct = 0; ct < 4; ++ct) {
      short8 bb = *(short8*)&Wt[(ct * 16 + l16) * 136 + kc * 32 + quad * 8];
      acc[ct] = __builtin_amdgcn_mfma_f32_16x16x32_bf16(a, bb, acc[ct], 0, 0, 0);
    }
  }
  #pragma unroll
  for (int ct = 0; ct < 4; ++ct)
    #pragma unroll
    for (int r = 0; r < 4; ++r) {
      int gr = row0 + w * 16 + quad * 4 + r;
      Y[(size_t)gr * 64 + ct * 16 + l16] = __float2bfloat16(acc[ct][r]);
    }
}

// conv3: Y[M,128] = X[M,64] @ W[64,128] + b; M multiple of 64
__global__ void gemm_64_128_kernel(const bf16* __restrict__ X, const void* __restrict__ W,
                                   const void* __restrict__ b, bf16* __restrict__ Y,
                                   const Ctl* __restrict__ ctl, int M)
{
  __shared__ short Xs[64 * 72];
  __shared__ short Wt[128 * 72];
  __shared__ float bs[128];
  const bool f32 = ctl->isfp32 != 0;
  const int tid = threadIdx.x;
  const int row0 = blockIdx.x * 64;

  for (int i = tid; i < 64 * 128; i += 256) {
    int k = i >> 7, n = i & 127;
    Wt[n * 72 + k] = f32 ? f2bf_bits(((const float*)W)[i]) : ((const short*)W)[i];
  }
  const u32* X2 = (const u32*)X;
  for (int p = tid; p < 64 * 32; p += 256) {
    int r = p >> 5, kp = p & 31;
    *(u32*)&Xs[r * 72 + 2 * kp] = X2[(size_t)(row0 + r) * 32 + kp];
  }
  for (int i = tid; i < 128; i += 256) bs[i] = loadF(b, i, f32);
  __syncthreads();

  const int lane = tid & 63;
  const int w = tid >> 6;
  const int l16 = lane & 15;
  const int quad = lane >> 4;
  f32x4 acc[8];
  #pragma unroll
  for (int ct = 0; ct < 8; ++ct) acc[ct] = (f32x4){0.f, 0.f, 0.f, 0.f};
  const int arow = w * 16 + l16;
  #pragma unroll
  for (int kc = 0; kc < 2; ++kc) {
    short8 a = *(short8*)&Xs[arow * 72 + kc * 32 + quad * 8];
    #pragma unroll
    for (int ct = 0; ct < 8; ++ct) {
      short8 bb = *(short8*)&Wt[(ct * 16 + l16) * 72 + kc * 32 + quad * 8];
      acc[ct] = __builtin_amdgcn_mfma_f32_16x16x32_bf16(a, bb, acc[ct], 0, 0, 0);
    }
  }
  #pragma unroll
  for (int ct = 0; ct < 8; ++ct)
    #pragma unroll
    for (int r = 0; r < 4; ++r) {
      int gr = row0 + w * 16 + quad * 4 + r;
      int col = ct * 16 + l16;
      Y[(size_t)gr * 128 + col] = __float2bfloat16(acc[ct][r] + bs[col]);
    }
}

// conv4: gather + per-block mean-pool partial + fused final reduce (last block)
__global__ void agg_gather64_final_kernel(const bf16* __restrict__ hW, const int* __restrict__ rowstart,
                                          const int* __restrict__ len, const int* __restrict__ csr,
                                          const float* __restrict__ dis,
                                          float* __restrict__ partial, int M, int nblk,
                                          const void* __restrict__ b, Ctl* ctl,
                                          void* __restrict__ out)
{
  __shared__ float cs[64];
  __shared__ int lastflag;
  const int tid = threadIdx.x;
  if (tid < 64) cs[tid] = 0.f;
  __syncthreads();
  const int lane = tid & 31;
  const bf16x2* H = (const bf16x2*)hW;
  for (int d = (blockIdx.x * 256 + tid) >> 5; d < M; d += nblk * 8) {
    float dd = dis[d];
    bf16x2 v = H[(size_t)d * 32 + lane];
    float sw = dd * dd;
    float ax = bf2f(v.x) * sw, ay = bf2f(v.y) * sw;
    int i = rowstart[d];
    int i1 = i + len[d];
    for (; i + 4 <= i1; i += 4) {
      int s0 = csr[i], s1 = csr[i + 1], s2 = csr[i + 2], s3 = csr[i + 3];
      float w0 = dd * dis[s0], w1 = dd * dis[s1], w2 = dd * dis[s2], w3 = dd * dis[s3];
      bf16x2 v0 = H[(size_t)s0 * 32 + lane];
      bf16x2 v1 = H[(size_t)s1 * 32 + lane];
      bf16x2 v2 = H[(size_t)s2 * 32 + lane];
      bf16x2 v3 = H[(size_t)s3 * 32 + lane];
      ax += w0 * bf2f(v0.x) + w1 * bf2f(v1.x) + w2 * bf2f(v2.x) + w3 * bf2f(v3.x);
      ay += w0 * bf2f(v0.y) + w1 * bf2f(v1.y) + w2 * bf2f(v2.y) + w3 * bf2f(v3.y);
    }
    for (; i < i1; ++i) {
      int s = csr[i];
      float w = dd * dis[s];
      bf16x2 vv = H[(size_t)s * 32 + lane];
      ax += w * bf2f(vv.x);
      ay += w * bf2f(vv.y);
    }
    atomicAdd(&cs[2 * lane], ax);
    atomicAdd(&cs[2 * lane + 1], ay);
  }
  __syncthreads();
  if (tid < 64) partial[(size_t)tid * nblk + blockIdx.x] = cs[tid];
  // fused reduce: last-arriving block sums partials and writes output
  __threadfence();
  __syncthreads();
  if (tid == 0) {
    u32 old = atomicAdd(&ctl->done2, 1u);
    lastflag = (old == (u32)(nblk - 1));
  }
  __syncthreads();
  if (!lastflag) return;
  __threadfence();
  const int c = tid & 63;
  const int part = tid >> 6;           // 0..3
  float s = 0.f;
  for (int j = part; j < nblk; j += 4) s += partial[(size_t)c * nblk + j];
  __shared__ float rs[256];
  rs[tid] = s;
  __syncthreads();
  if (tid < 64) {
    const bool f32 = ctl->isfp32 != 0;
    float val = rs[tid] + rs[tid + 64] + rs[tid + 128] + rs[tid + 192];
    val = val / (float)K_KEEP + loadF(b, tid, f32);
    if (f32) ((float*)out)[tid] = val;
    else     ((bf16*)out)[tid] = __float2bfloat16(val);
  }
}

// ------- TopK select: separate-launch hist+pick (proven R0/R2), parallel pick + early-exit -------

__global__ void histpick_kernel(const u64* __restrict__ keys, Ctl* ctl, int shift, int nblocks) {
  __shared__ u32 lh[256];
  __shared__ u32 sfx[256];
  __shared__ int lastflag;
  __shared__ int selsh;
  const int tid = threadIdx.x;
  if (ctl->gen != 0u) return;          // threshold already resolved by earlier pass
  lh[tid] = 0;
  __syncthreads();
  u64 prefix = ctl->prefix;
  int i = blockIdx.x * 256 + tid;
  if (i < N_NODES) {
    u64 key = keys[i];
    if ((key >> (shift + 8)) == (prefix >> (shift + 8)))
      atomicAdd(&lh[(u32)((key >> shift) & 0xFF)], 1u);
  }
  __syncthreads();
  u32 c = lh[tid];
  if (c) atomicAdd(&ctl->hist[tid], c);
  __syncthreads();
  if (tid == 0) {
    __threadfence();
    u32 old = atomicAdd(&ctl->done, 1u);
    lastflag = (old == (u32)(nblocks - 1));
  }
  __syncthreads();
  if (!lastflag) return;
  // last block: parallel pick via suffix scan
  u32 cc = atomicExch(&ctl->hist[tid], 0u);   // coherent read + zero for next pass
  sfx[tid] = cc;
  __syncthreads();
  for (int off = 1; off < 256; off <<= 1) {
    u32 t = (tid + off < 256) ? sfx[tid + off] : 0u;
    __syncthreads();
    sfx[tid] += t;
    __syncthreads();
  }
  u32 kr = ctl->kremain;
  u32 above = (tid < 255) ? sfx[tid + 1] : 0u;
  if (sfx[tid] >= kr && above < kr) selsh = tid;   // unique (sfx non-increasing)
  __syncthreads();
  if (tid == 0) {
    int sel = selsh;
    u32 ab = (sel < 255) ? sfx[sel + 1] : 0u;
    u32 newkr = kr - ab;
    u32 bucketcnt = sfx[sel] - ab;
    ctl->kremain = newkr;
    ctl->prefix = prefix | (((u64)(u32)sel) << shift);
    if (newkr == bucketcnt) ctl->gen = 1u;  // whole boundary bucket kept -> resolved
    ctl->done = 0u;
  }
}

__global__ void mark_kernel(const u64* __restrict__ keys, Ctl* ctl,
                            int* __restrict__ new_idx, int* __restrict__ kept)
{
  int i = blockIdx.x * 256 + threadIdx.x;
  if (i >= N_NODES) return;
  if (keys[i] >= ctl->prefix) {
    int pos = (int)atomicAdd(&ctl->cnt, 1u);
    new_idx[i] = pos;
    kept[pos] = i;
  } else {
    new_idx[i] = -1;
  }
}

// ------- CSR2 in ONE kernel: count + wave-aggregated alloc + fill (order-free rows) -------

__global__ void csr2_build_kernel(const int* __restrict__ kept, const int* __restrict__ rowstart1,
                                  const int* __restrict__ csr1, const int* __restrict__ new_idx,
                                  Ctl* ctl, int* __restrict__ rowstart2, int* __restrict__ len2,
                                  float* __restrict__ dis2, int* __restrict__ csr2)
{
  int kp = blockIdx.x * 256 + threadIdx.x;
  int lane = threadIdx.x & 63;
  int c = 0;
  int i0 = 0, i1 = 0;
  if (kp < K_KEEP) {
    int o = kept[kp];
    i0 = rowstart1[o]; i1 = rowstart1[o + 1];
    int i = i0;
    for (; i + 4 <= i1; i += 4) {
      int s0 = csr1[i], s1 = csr1[i + 1], s2 = csr1[i + 2], s3 = csr1[i + 3];
      c += (new_idx[s0] >= 0) + (new_idx[s1] >= 0) + (new_idx[s2] >= 0) + (new_idx[s3] >= 0);
    }
    for (; i < i1; ++i) c += (new_idx[csr1[i]] >= 0);
  }
  // wave inclusive scan of c
  int pre = c;
  #pragma unroll
  for (int off = 1; off < 64; off <<= 1) {
    int t = __shfl_up(pre, off);
    if (lane >= off) pre += t;
  }
  int wtot = __shfl(pre, 63);
  int wbase = 0;
  if (lane == 0) wbase = (int)atomicAdd(&ctl->pad, (u32)wtot);
  wbase = __shfl(wbase, 0);
  int base = wbase + pre - c;
  if (kp < K_KEEP) {
    rowstart2[kp] = base;
    len2[kp] = c;
    dis2[kp] = rsqrtf(1.0f + (float)c);
    int w = base;
    for (int i = i0; i < i1; ++i) {
      int ns = new_idx[csr1[i]];
      if (ns >= 0) csr2[w++] = ns;
    }
  }
}

// ---------------- launch ----------------

extern "C" void kernel_launch(void* const* d_in, const int* in_sizes, int n_in,
                              void* d_out, int out_size, void* d_ws, size_t ws_size,
                              hipStream_t stream)
{
  const void* x  = d_in[0];
  const int*  ei = (const int*)d_in[1];
  const void* W1 = d_in[3];
  const void* b1 = d_in[4];
  const void* pw = d_in[5];
  const void* W2 = d_in[6];
  const void* b2 = d_in[7];
  const void* W3 = d_in[8];
  const void* b3 = d_in[9];
  const void* W4 = d_in[10];
  const void* b4 = d_in[11];

  const int* src = ei;
  const int* dst = ei + N_EDGES;

  float* F = (float*)d_ws;
  bf16*  A16       = (bf16*)F;               // N x 128 bf16
  bf16*  B16       = (bf16*)(F + 3200000);   // N x 128 bf16
  bf16*  C16       = (bf16*)(F + 6400000);   // K x 128 bf16 (also conv1's G [N x 64])
  u32*   xbf       = (u32*)(F + 9000000);    // N x 32 u32 (x as bf16 pairs, only if fp32 input)
  float* dis1      = F + 10600000;           // 50000
  float* dis2      = F + 10650000;           // 40000
  float* score     = F + 10690000;           // 50000
  u64*   keys      = (u64*)(F + 10740000);   // 50000 u64
  int*   new_idx   = (int*)(F + 10840000);   // 50000
  int*   kept      = (int*)(F + 10890000);   // 40000
  int*   len2      = (int*)(F + 10930000);   // 40000
  int*   rowstart1 = (int*)(F + 10970000);   // 50001
  int*   rowstart2 = (int*)(F + 11020004);   // 40000
  int*   csr1      = (int*)(F + 11060008);   // 800000
  int*   csr2      = (int*)(F + 11860008);   // 800000
  Ctl*   ctl       = (Ctl*)(F + 12660008);   // ~1.1 KB
  int*   detcnt    = (int*)(F + 12660856);   // 64
  int*   bucket_cur= (int*)(F + 12660920);   // 196
  u32*   bucketbuf = (u32*)(F + 12726908);   // 196*6144
  float* partial   = F + 13931132;           // 64 x 1024

  const int NB1 = (N_NODES + 255) / 256;     // 196
  const int EB2 = (N_EDGES + 2047) / 2048;   // 391
  const int GB1 = (N_NODES + 63) / 64;       // 782
  const int AB1 = N_NODES * 32 / 256;        // 6250
  const int ABK = K_KEEP * 32 / 256;         // 5000
  const int CB2 = (K_KEEP + 255) / 256;      // 157
  const int NBF = 1024;                      // final-gather blocks

  init_kernel<<<NB1, 256, 0, stream>>>((const unsigned short*)x, bucket_cur, detcnt, ctl);

  // CSR graph 1 via bucket sort (+fused dtype/norm, +x->bf16 conversion iff fp32 input)
  bucket_scatter_kernel<<<EB2, 256, 0, stream>>>(src, dst, bucket_cur, bucketbuf, x, xbf,
                                                 detcnt, pw, ctl);
  csr_from_buckets_kernel<<<BKT, 256, 0, stream>>>(bucketbuf, bucket_cur, rowstart1, dis1, csr1);

  // conv1 (gather-first on bf16 x): G = A_norm . x ; h1 = G @ W1 + b1 (+fused score/keys)
  agg_gather64_kernel<<<AB1, 256, 0, stream>>>((const bf16*)x, (const bf16*)xbf, rowstart1, nullptr,
                                               csr1, dis1, nullptr, ctl, C16, N_NODES, 0, 0);
  gemm_in_kernel<<<GB1, 256, 0, stream>>>(C16, W1, b1, pw, B16, ctl, score, keys);

  // top-K select (6 x 8-bit radix, separate launches; early-exit skips tie-break passes)
  for (int p = 0; p < 6; ++p)
    histpick_kernel<<<NB1, 256, 0, stream>>>(keys, ctl, 40 - 8 * p, NB1);
  mark_kernel<<<NB1, 256, 0, stream>>>(keys, ctl, new_idx, kept);

  // CSR graph 2 in one kernel (row bases via wave-aggregated atomic; order-free)
  csr2_build_kernel<<<CB2, 256, 0, stream>>>(kept, rowstart1, csr1, new_idx, ctl,
                                             rowstart2, len2, dis2, csr2);

  // conv2: gemm-first (fused hp: relu*score on kept rows): A = hp @ W2 ; h2 = gather(A) + b2
  gemm_128_64_kernel<<<K_KEEP / 64, 256, 0, stream>>>(B16, W2, A16, ctl, K_KEEP, 0, kept, score);
  agg_gather64_kernel<<<ABK, 256, 0, stream>>>(A16, A16, rowstart2, len2, csr2, dis2, b2, ctl, C16, K_KEEP, 0, 1);

  // conv3: gather-first: G = gather(relu(h2)) ; h3 = G @ W3 + b3
  agg_gather64_kernel<<<ABK, 256, 0, stream>>>(C16, C16, rowstart2, len2, csr2, dis2, b3, ctl, A16, K_KEEP, 1, 0);
  gemm_64_128_kernel<<<K_KEEP / 64, 256, 0, stream>>>(A16, W3, b3, B16, ctl, K_KEEP);

  // conv4: gemm-first: A = relu(h3) @ W4 ; partials = gather(A) ; fused final reduce
  gemm_128_64_kernel<<<K_KEEP / 64, 256, 0, stream>>>(B16, W4, A16, ctl, K_KEEP, 1, nullptr, nullptr);
  agg_gather64_final_kernel<<<NBF, 256, 0, stream>>>(A16, rowstart2, len2, csr2, dis2,
                                                     partial, K_KEEP, NBF, b4, ctl, d_out);
}

// Round 6
// 348.411 us; speedup vs baseline: 1.8001x; 1.3490x over previous
//
#include <hip/hip_runtime.h>
#include <hip/hip_bf16.h>
#include <stdint.h>

#define N_NODES 50000
#define N_EDGES 800000
#define K_KEEP  40000
#define BKT     196        // ceil(N_NODES/256) dst-range buckets
#define BCAP    6144       // per-bucket capacity (mean 4081, +32 sigma)

typedef unsigned long long u64;
typedef unsigned int u32;
typedef unsigned short u16;
typedef __hip_bfloat16 bf16;
typedef __hip_bfloat162 bf16x2;
typedef __attribute__((ext_vector_type(8))) short short8;
typedef __attribute__((ext_vector_type(4))) float f32x4;

struct Ctl {
  u64 prefix;
  u32 kremain;
  u32 cnt;
  float inv_norm;
  u32 isfp32;
  u32 done;         // radix pass arrival counter (reset by picker each pass)
  u32 pad;          // csr2 edge cursor
  u32 gen;          // TopK resolved-early flag
  u32 done2;        // (unused; layout keep)
  u32 hist[256];    // radix histogram (LDS-aggregated flushes only)
};

__device__ __forceinline__ float bf2f(bf16 v) { return __bfloat162float(v); }
__device__ __forceinline__ float loadF(const void* p, size_t i, bool f32) {
  return f32 ? ((const float*)p)[i] : bf2f(((const bf16*)p)[i]);
}
__device__ __forceinline__ short f2bf_bits(float f) {
  bf16 t = __float2bfloat16(f);
  return *(const short*)&t;
}

// ---------------- init (+parallel dtype detect, proven R5-R8) ----------------

__global__ void init_kernel(const unsigned short* __restrict__ x16,
                            int* __restrict__ bucket_cur, int* __restrict__ detcnt, Ctl* ctl) {
  __shared__ u32 dsh[256];
  int i = blockIdx.x * 256 + threadIdx.x;
  if (i < BKT) bucket_cur[i] = i * BCAP;
  if (blockIdx.x == 0) {
    ctl->hist[threadIdx.x] = 0u;
    if (threadIdx.x == 0) {
      ctl->prefix = 0ull; ctl->kremain = K_KEEP; ctl->cnt = 0u;
      ctl->done = 0u; ctl->pad = 0u; ctl->gen = 0u; ctl->done2 = 0u;
    }
  }
  if (blockIdx.x < 64) {
    int base = blockIdx.x * 2048;
    u32 c = 0;
    for (int j = threadIdx.x; j < 2048; j += 256) {
      u32 h = x16[base + j];
      if ((h & 0x7F80u) == 0x7F80u) c++;
    }
    dsh[threadIdx.x] = c;
    __syncthreads();
    for (int s = 128; s > 0; s >>= 1) {
      if (threadIdx.x < s) dsh[threadIdx.x] += dsh[threadIdx.x + s];
      __syncthreads();
    }
    if (threadIdx.x == 0) detcnt[blockIdx.x] = (int)dsh[0];
  }
}

// ------- CSR1 bucket scatter (proven R8) + fused dtype/norm + fp32->bf16 convert -------

__global__ void bucket_scatter_kernel(const int* __restrict__ src, const int* __restrict__ dst,
                                      int* __restrict__ bucket_cur, u32* __restrict__ bucketbuf,
                                      const void* __restrict__ x, u32* __restrict__ xbf,
                                      const int* __restrict__ detcnt, const void* __restrict__ pw,
                                      Ctl* ctl)
{
  __shared__ u32 hist[BKT];
  __shared__ u32 base[BKT];
  __shared__ int f32sh;
  __shared__ float ns[128];
  const int tid = threadIdx.x;
  const int e0 = blockIdx.x * 2048;

  // dtype detect from detcnt (written by init, prior dispatch)
  if (tid < 64) {
    int dc = detcnt[tid];
    for (int off = 32; off; off >>= 1) dc += __shfl_down(dc, off);
    if (tid == 0) f32sh = (dc >= 16) ? 1 : 0;
  }
  for (int t = tid; t < BKT; t += 256) hist[t] = 0;
  __syncthreads();
  const bool f32in = f32sh != 0;

  #pragma unroll
  for (int j = 0; j < 8; ++j) {
    int e = e0 + j * 256 + tid;
    if (e < N_EDGES) atomicAdd(&hist[dst[e] >> 8], 1u);
  }
  __syncthreads();
  for (int t = tid; t < BKT; t += 256) {
    u32 c = hist[t];
    base[t] = c ? (u32)atomicAdd(&bucket_cur[t], (int)c) : 0u;
    hist[t] = 0;
  }
  __syncthreads();
  #pragma unroll
  for (int j = 0; j < 8; ++j) {
    int e = e0 + j * 256 + tid;
    if (e < N_EDGES) {
      int d = dst[e];
      int b = d >> 8;
      u32 pos = base[b] + atomicAdd(&hist[b], 1u);
      bucketbuf[pos] = ((u32)src[e] << 8) | (u32)(d & 255);
    }
  }
  // fused x -> bf16 (pair) conversion; only when input is fp32
  if (f32in) {
    const int p0 = blockIdx.x * 4096;
    const float2* xf = (const float2*)x;
    for (int j = tid; j < 4096; j += 256) {
      int p = p0 + j;
      if (p < N_NODES * 32) {
        float2 v = xf[p];
        u32 w = ((u32)(u16)f2bf_bits(v.y) << 16) | (u32)(u16)f2bf_bits(v.x);
        xbf[p] = w;
      }
    }
  }
  // fused norm: block 0 computes inv_norm + publishes isfp32
  if (blockIdx.x == 0) {
    if (tid < 128) { float v = loadF(pw, tid, f32in); ns[tid] = v * v; }
    __syncthreads();
    for (int s = 64; s > 0; s >>= 1) {
      if (tid < s) ns[tid] += ns[tid + s];
      __syncthreads();
    }
    if (tid == 0) {
      ctl->inv_norm = 1.0f / sqrtf(ns[0]);
      ctl->isfp32 = f32in ? 1u : 0u;
    }
  }
}

// ------- CSR1 from buckets (inline bucket scan; no separate scan kernel) -------

__global__ void csr_from_buckets_kernel(const u32* __restrict__ bucketbuf, const int* __restrict__ bucket_cur,
                                        int* __restrict__ rowstart, float* __restrict__ dis,
                                        int* __restrict__ csr)
{
  __shared__ u32 cnt[256];
  __shared__ u32 loc[256];
  __shared__ u32 cur[256];
  const int b = blockIdx.x;
  const int tid = threadIdx.x;

  // inline scan of all bucket sizes -> off0 for this bucket
  int v = (tid < BKT) ? (bucket_cur[tid] - tid * BCAP) : 0;
  loc[tid] = (u32)v;
  __syncthreads();
  for (int off = 1; off < 256; off <<= 1) {
    u32 t = (tid >= off) ? loc[tid - off] : 0;
    __syncthreads();
    loc[tid] += t;
    __syncthreads();
  }
  const int bc = bucket_cur[b] - b * BCAP;
  const int off0 = (int)loc[b] - bc;
  if (b == BKT - 1 && tid == 0) rowstart[N_NODES] = (int)loc[BKT - 1];
  __syncthreads();

  const u32* buf = bucketbuf + (size_t)b * BCAP;
  cnt[tid] = 0;
  __syncthreads();
  for (int i = tid; i < bc; i += 256) atomicAdd(&cnt[buf[i] & 255u], 1u);
  __syncthreads();
  u32 c = cnt[tid];
  loc[tid] = c;
  __syncthreads();
  for (int off = 1; off < 256; off <<= 1) {
    u32 t = (tid >= off) ? loc[tid - off] : 0;
    __syncthreads();
    loc[tid] += t;
    __syncthreads();
  }
  int node = b * 256 + tid;
  u32 excl = loc[tid] - c;
  if (node < N_NODES) {
    rowstart[node] = off0 + (int)excl;
    dis[node] = rsqrtf(1.0f + (float)c);
  }
  cur[tid] = off0 + excl;
  __syncthreads();
  for (int i = tid; i < bc; i += 256) {
    u32 p = buf[i];
    u32 pos = atomicAdd(&cur[p & 255u], 1u);
    csr[pos] = (int)(p >> 8);
  }
}

// ------------- unified gather: 32 lanes/node, bf16x2 loads; ILP-4 -------------

__global__ void agg_gather64_kernel(const bf16* __restrict__ hW, const bf16* __restrict__ hWalt,
                                    const int* __restrict__ rowstart,
                                    const int* __restrict__ len, const int* __restrict__ csr,
                                    const float* __restrict__ dis,
                                    const void* __restrict__ b, const Ctl* __restrict__ ctl,
                                    bf16* __restrict__ agg, int M, int relusrc, int addbias)
{
  const bool f32 = ctl->isfp32 != 0;
  int gid = blockIdx.x * 256 + threadIdx.x;
  int d = gid >> 5;
  int lane = gid & 31;
  if (d >= M) return;
  const bf16x2* H = (const bf16x2*)(f32 ? hWalt : hW);
  float dd = dis[d];
  bf16x2 v = H[(size_t)d * 32 + lane];
  float ax = bf2f(v.x), ay = bf2f(v.y);
  if (relusrc) { ax = fmaxf(ax, 0.f); ay = fmaxf(ay, 0.f); }
  float sw = dd * dd;
  ax *= sw; ay *= sw;
  if (addbias) { ax += loadF(b, 2 * lane, f32); ay += loadF(b, 2 * lane + 1, f32); }
  int i = rowstart[d];
  int i1 = len ? (i + len[d]) : rowstart[d + 1];
  for (; i + 4 <= i1; i += 4) {
    int s0 = csr[i], s1 = csr[i + 1], s2 = csr[i + 2], s3 = csr[i + 3];
    float w0 = dd * dis[s0], w1 = dd * dis[s1], w2 = dd * dis[s2], w3 = dd * dis[s3];
    bf16x2 v0 = H[(size_t)s0 * 32 + lane];
    bf16x2 v1 = H[(size_t)s1 * 32 + lane];
    bf16x2 v2 = H[(size_t)s2 * 32 + lane];
    bf16x2 v3 = H[(size_t)s3 * 32 + lane];
    float x0 = bf2f(v0.x), y0 = bf2f(v0.y), x1 = bf2f(v1.x), y1 = bf2f(v1.y);
    float x2 = bf2f(v2.x), y2 = bf2f(v2.y), x3 = bf2f(v3.x), y3 = bf2f(v3.y);
    if (relusrc) {
      x0 = fmaxf(x0, 0.f); y0 = fmaxf(y0, 0.f); x1 = fmaxf(x1, 0.f); y1 = fmaxf(y1, 0.f);
      x2 = fmaxf(x2, 0.f); y2 = fmaxf(y2, 0.f); x3 = fmaxf(x3, 0.f); y3 = fmaxf(y3, 0.f);
    }
    ax += w0 * x0 + w1 * x1 + w2 * x2 + w3 * x3;
    ay += w0 * y0 + w1 * y1 + w2 * y2 + w3 * y3;
  }
  for (; i < i1; ++i) {
    int s = csr[i];
    float w = dd * dis[s];
    bf16x2 vv = H[(size_t)s * 32 + lane];
    float xx = bf2f(vv.x), yy = bf2f(vv.y);
    if (relusrc) { xx = fmaxf(xx, 0.f); yy = fmaxf(yy, 0.f); }
    ax += w * xx; ay += w * yy;
  }
  bf16x2 w2;
  w2.x = __float2bfloat16(ax);
  w2.y = __float2bfloat16(ay);
  ((bf16x2*)agg)[(size_t)d * 32 + lane] = w2;
}

// ---------------- MFMA GEMMs (16x16x32 bf16, fp32 acc) ----------------

// conv1: Y[N,128] = G[N,64] @ W1 + b1, fused pooling score/keys
__global__ void gemm_in_kernel(const bf16* __restrict__ G, const void* __restrict__ W,
                               const void* __restrict__ b, const void* __restrict__ pw,
                               bf16* __restrict__ Y, const Ctl* __restrict__ ctl,
                               float* __restrict__ score, u64* __restrict__ keys)
{
  __shared__ short Xs[64 * 72];
  __shared__ short Wt[128 * 72];
  __shared__ float bs[128];
  __shared__ float ps[128];
  const bool f32 = ctl->isfp32 != 0;
  const int tid = threadIdx.x;
  const int row0 = blockIdx.x * 64;

  for (int i = tid; i < 64 * 128; i += 256) {
    int k = i >> 7, n = i & 127;
    Wt[n * 72 + k] = f32 ? f2bf_bits(((const float*)W)[i]) : ((const short*)W)[i];
  }
  const u32* G2 = (const u32*)G;
  for (int p = tid; p < 64 * 32; p += 256) {
    int r = p >> 5, kp = p & 31;
    int gr = row0 + r;
    u32 v = (gr < N_NODES) ? G2[(size_t)gr * 32 + kp] : 0u;
    *(u32*)&Xs[r * 72 + 2 * kp] = v;
  }
  for (int i = tid; i < 128; i += 256) { bs[i] = loadF(b, i, f32); ps[i] = loadF(pw, i, f32); }
  __syncthreads();

  const int lane = tid & 63;
  const int w = tid >> 6;
  const int l16 = lane & 15;
  const int quad = lane >> 4;
  f32x4 acc[8];
  #pragma unroll
  for (int ct = 0; ct < 8; ++ct) acc[ct] = (f32x4){0.f, 0.f, 0.f, 0.f};
  const int arow = w * 16 + l16;
  #pragma unroll
  for (int kc = 0; kc < 2; ++kc) {
    short8 a = *(short8*)&Xs[arow * 72 + kc * 32 + quad * 8];
    #pragma unroll
    for (int ct = 0; ct < 8; ++ct) {
      short8 bb = *(short8*)&Wt[(ct * 16 + l16) * 72 + kc * 32 + quad * 8];
      acc[ct] = __builtin_amdgcn_mfma_f32_16x16x32_bf16(a, bb, acc[ct], 0, 0, 0);
    }
  }
  float inv_norm = ctl->inv_norm;
  #pragma unroll
  for (int r = 0; r < 4; ++r) {
    int gr = row0 + w * 16 + quad * 4 + r;
    float p = 0.f;
    #pragma unroll
    for (int ct = 0; ct < 8; ++ct) {
      int col = ct * 16 + l16;
      float h = acc[ct][r] + bs[col];
      if (gr < N_NODES) Y[(size_t)gr * 128 + col] = __float2bfloat16(h);
      p += fmaxf(h, 0.f) * ps[col];
    }
    p += __shfl_down(p, 8, 16);
    p += __shfl_down(p, 4, 16);
    p += __shfl_down(p, 2, 16);
    p += __shfl_down(p, 1, 16);
    if (l16 == 0 && gr < N_NODES) {
      float sc = tanhf(p * inv_norm);
      score[gr] = sc;
      u32 u = __float_as_uint(sc);
      u = (u & 0x80000000u) ? ~u : (u | 0x80000000u);
      keys[gr] = (((u64)u) << 16) | (u64)(0xFFFFu - (u32)gr);
    }
  }
}

// Y[M,64] = (relu?)X[M,128] @ W[128,64]; M multiple of 64
// kept!=null: X row = kept[row], apply relu*score[kept[row]] (fused TopK hp)
__global__ void gemm_128_64_kernel(const bf16* __restrict__ X, const void* __restrict__ W,
                                   bf16* __restrict__ Y, const Ctl* __restrict__ ctl,
                                   int M, int relu_x,
                                   const int* __restrict__ kept, const float* __restrict__ score)
{
  __shared__ short Xs[64 * 136];
  __shared__ short Wt[64 * 136];
  __shared__ int keptS[64];
  __shared__ float scS[64];
  const bool f32 = ctl->isfp32 != 0;
  const int tid = threadIdx.x;
  const int row0 = blockIdx.x * 64;

  if (kept) {
    for (int i = tid; i < 64; i += 256) {
      int o = kept[row0 + i];
      keptS[i] = o;
      scS[i] = score[o];
    }
  }
  __syncthreads();

  for (int i = tid; i < 128 * 64; i += 256) {
    int k = i >> 6, n = i & 63;
    Wt[n * 136 + k] = f32 ? f2bf_bits(((const float*)W)[i]) : ((const short*)W)[i];
  }
  const u32* X2 = (const u32*)X;
  for (int p = tid; p < 64 * 64; p += 256) {
    int r = p >> 6, kp = p & 63;
    int srow = kept ? keptS[r] : (row0 + r);
    u32 v = X2[(size_t)srow * 64 + kp];
    if (relu_x) {
      if (v & 0x8000u) v &= 0xFFFF0000u;
      if (v & 0x80000000u) v &= 0x0000FFFFu;
    }
    if (kept) {
      bf16x2 h = *(bf16x2*)&v;
      float s = scS[r];
      bf16x2 o;
      o.x = __float2bfloat16(fmaxf(bf2f(h.x), 0.f) * s);
      o.y = __float2bfloat16(fmaxf(bf2f(h.y), 0.f) * s);
      v = *(u32*)&o;
    }
    *(u32*)&Xs[r * 136 + 2 * kp] = v;
  }
  __syncthreads();

  const int lane = tid & 63;
  const int w = tid >> 6;
  const int l16 = lane & 15;
  const int quad = lane >> 4;
  f32x4 acc[4];
  #pragma unroll
  for (int ct = 0; ct < 4; ++ct) acc[ct] = (f32x4){0.f, 0.f, 0.f, 0.f};
  const int arow = w * 16 + l16;
  #pragma unroll
  for (int kc = 0; kc < 4; ++kc) {
    short8 a = *(short8*)&Xs[arow * 136 + kc * 32 + quad * 8];
    #pragma unroll
    for (int ct = 0; ct < 4; ++ct) {
      short8 bb = *(short8*)&Wt[(ct * 16 + l16) * 136 + kc * 32 + quad * 8];
      acc[ct] = __builtin_amdgcn_mfma_f32_16x16x32_bf16(a, bb, acc[ct], 0, 0, 0);
    }
  }
  #pragma unroll
  for (int ct = 0; ct < 4; ++ct)
    #pragma unroll
    for (int r = 0; r < 4; ++r) {
      int gr = row0 + w * 16 + quad * 4 + r;
      Y[(size_t)gr * 64 + ct * 16 + l16] = __float2bfloat16(acc[ct][r]);
    }
}

// conv3: Y[M,128] = X[M,64] @ W[64,128] + b; M multiple of 64
__global__ void gemm_64_128_kernel(const bf16* __restrict__ X, const void* __restrict__ W,
                                   const void* __restrict__ b, bf16* __restrict__ Y,
                                   const Ctl* __restrict__ ctl, int M)
{
  __shared__ short Xs[64 * 72];
  __shared__ short Wt[128 * 72];
  __shared__ float bs[128];
  const bool f32 = ctl->isfp32 != 0;
  const int tid = threadIdx.x;
  const int row0 = blockIdx.x * 64;

  for (int i = tid; i < 64 * 128; i += 256) {
    int k = i >> 7, n = i & 127;
    Wt[n * 72 + k] = f32 ? f2bf_bits(((const float*)W)[i]) : ((const short*)W)[i];
  }
  const u32* X2 = (const u32*)X;
  for (int p = tid; p < 64 * 32; p += 256) {
    int r = p >> 5, kp = p & 31;
    *(u32*)&Xs[r * 72 + 2 * kp] = X2[(size_t)(row0 + r) * 32 + kp];
  }
  for (int i = tid; i < 128; i += 256) bs[i] = loadF(b, i, f32);
  __syncthreads();

  const int lane = tid & 63;
  const int w = tid >> 6;
  const int l16 = lane & 15;
  const int quad = lane >> 4;
  f32x4 acc[8];
  #pragma unroll
  for (int ct = 0; ct < 8; ++ct) acc[ct] = (f32x4){0.f, 0.f, 0.f, 0.f};
  const int arow = w * 16 + l16;
  #pragma unroll
  for (int kc = 0; kc < 2; ++kc) {
    short8 a = *(short8*)&Xs[arow * 72 + kc * 32 + quad * 8];
    #pragma unroll
    for (int ct = 0; ct < 8; ++ct) {
      short8 bb = *(short8*)&Wt[(ct * 16 + l16) * 72 + kc * 32 + quad * 8];
      acc[ct] = __builtin_amdgcn_mfma_f32_16x16x32_bf16(a, bb, acc[ct], 0, 0, 0);
    }
  }
  #pragma unroll
  for (int ct = 0; ct < 8; ++ct)
    #pragma unroll
    for (int r = 0; r < 4; ++r) {
      int gr = row0 + w * 16 + quad * 4 + r;
      int col = ct * 16 + l16;
      Y[(size_t)gr * 128 + col] = __float2bfloat16(acc[ct][r] + bs[col]);
    }
}

// conv4: gather + per-block mean-pool partial (plain stores; NO fence/tail — R5 lesson)
__global__ void agg_gather64_final_kernel(const bf16* __restrict__ hW, const int* __restrict__ rowstart,
                                          const int* __restrict__ len, const int* __restrict__ csr,
                                          const float* __restrict__ dis,
                                          float* __restrict__ partial, int M, int nblk)
{
  __shared__ float cs[64];
  const int tid = threadIdx.x;
  if (tid < 64) cs[tid] = 0.f;
  __syncthreads();
  const int lane = tid & 31;
  const bf16x2* H = (const bf16x2*)hW;
  for (int d = (blockIdx.x * 256 + tid) >> 5; d < M; d += nblk * 8) {
    float dd = dis[d];
    bf16x2 v = H[(size_t)d * 32 + lane];
    float sw = dd * dd;
    float ax = bf2f(v.x) * sw, ay = bf2f(v.y) * sw;
    int i = rowstart[d];
    int i1 = i + len[d];
    for (; i + 4 <= i1; i += 4) {
      int s0 = csr[i], s1 = csr[i + 1], s2 = csr[i + 2], s3 = csr[i + 3];
      float w0 = dd * dis[s0], w1 = dd * dis[s1], w2 = dd * dis[s2], w3 = dd * dis[s3];
      bf16x2 v0 = H[(size_t)s0 * 32 + lane];
      bf16x2 v1 = H[(size_t)s1 * 32 + lane];
      bf16x2 v2 = H[(size_t)s2 * 32 + lane];
      bf16x2 v3 = H[(size_t)s3 * 32 + lane];
      ax += w0 * bf2f(v0.x) + w1 * bf2f(v1.x) + w2 * bf2f(v2.x) + w3 * bf2f(v3.x);
      ay += w0 * bf2f(v0.y) + w1 * bf2f(v1.y) + w2 * bf2f(v2.y) + w3 * bf2f(v3.y);
    }
    for (; i < i1; ++i) {
      int s = csr[i];
      float w = dd * dis[s];
      bf16x2 vv = H[(size_t)s * 32 + lane];
      ax += w * bf2f(vv.x);
      ay += w * bf2f(vv.y);
    }
    atomicAdd(&cs[2 * lane], ax);
    atomicAdd(&cs[2 * lane + 1], ay);
  }
  __syncthreads();
  if (tid < 64) partial[(size_t)tid * nblk + blockIdx.x] = cs[tid];
}

__global__ void reduce_out_kernel(const float* __restrict__ partial, const void* __restrict__ b,
                                  const Ctl* __restrict__ ctl, void* __restrict__ out, int nblk)
{
  __shared__ float sh[256];
  int c = blockIdx.x;
  float s = 0.f;
  for (int j = threadIdx.x; j < nblk; j += 256) s += partial[(size_t)c * nblk + j];
  sh[threadIdx.x] = s;
  __syncthreads();
  for (int st = 128; st > 0; st >>= 1) {
    if (threadIdx.x < st) sh[threadIdx.x] += sh[threadIdx.x + st];
    __syncthreads();
  }
  if (threadIdx.x == 0) {
    const bool f32 = ctl->isfp32 != 0;
    float val = sh[0] / (float)K_KEEP + loadF(b, c, f32);
    if (f32) ((float*)out)[c] = val;
    else     ((bf16*)out)[c] = __float2bfloat16(val);
  }
}

// ------- TopK select: separate-launch hist+pick (proven R0/R2), parallel pick + early-exit -------

__global__ void histpick_kernel(const u64* __restrict__ keys, Ctl* ctl, int shift, int nblocks) {
  __shared__ u32 lh[256];
  __shared__ u32 sfx[256];
  __shared__ int lastflag;
  __shared__ int selsh;
  const int tid = threadIdx.x;
  if (ctl->gen != 0u) return;          // threshold already resolved by earlier pass
  lh[tid] = 0;
  __syncthreads();
  u64 prefix = ctl->prefix;
  int i = blockIdx.x * 256 + tid;
  if (i < N_NODES) {
    u64 key = keys[i];
    if ((key >> (shift + 8)) == (prefix >> (shift + 8)))
      atomicAdd(&lh[(u32)((key >> shift) & 0xFF)], 1u);
  }
  __syncthreads();
  u32 c = lh[tid];
  if (c) atomicAdd(&ctl->hist[tid], c);
  __syncthreads();
  if (tid == 0) {
    __threadfence();
    u32 old = atomicAdd(&ctl->done, 1u);
    lastflag = (old == (u32)(nblocks - 1));
  }
  __syncthreads();
  if (!lastflag) return;
  // last block: parallel pick via suffix scan
  u32 cc = atomicExch(&ctl->hist[tid], 0u);   // coherent read + zero for next pass
  sfx[tid] = cc;
  __syncthreads();
  for (int off = 1; off < 256; off <<= 1) {
    u32 t = (tid + off < 256) ? sfx[tid + off] : 0u;
    __syncthreads();
    sfx[tid] += t;
    __syncthreads();
  }
  u32 kr = ctl->kremain;
  u32 above = (tid < 255) ? sfx[tid + 1] : 0u;
  if (sfx[tid] >= kr && above < kr) selsh = tid;   // unique (sfx non-increasing)
  __syncthreads();
  if (tid == 0) {
    int sel = selsh;
    u32 ab = (sel < 255) ? sfx[sel + 1] : 0u;
    u32 newkr = kr - ab;
    u32 bucketcnt = sfx[sel] - ab;
    ctl->kremain = newkr;
    ctl->prefix = prefix | (((u64)(u32)sel) << shift);
    if (newkr == bucketcnt) ctl->gen = 1u;  // whole boundary bucket kept -> resolved
    ctl->done = 0u;
  }
}

__global__ void mark_kernel(const u64* __restrict__ keys, Ctl* ctl,
                            int* __restrict__ new_idx, int* __restrict__ kept)
{
  int i = blockIdx.x * 256 + threadIdx.x;
  if (i >= N_NODES) return;
  if (keys[i] >= ctl->prefix) {
    int pos = (int)atomicAdd(&ctl->cnt, 1u);
    new_idx[i] = pos;
    kept[pos] = i;
  } else {
    new_idx[i] = -1;
  }
}

// ------- CSR2 in ONE kernel: count + wave-aggregated alloc + fill (order-free rows) -------

__global__ void csr2_build_kernel(const int* __restrict__ kept, const int* __restrict__ rowstart1,
                                  const int* __restrict__ csr1, const int* __restrict__ new_idx,
                                  Ctl* ctl, int* __restrict__ rowstart2, int* __restrict__ len2,
                                  float* __restrict__ dis2, int* __restrict__ csr2)
{
  int kp = blockIdx.x * 256 + threadIdx.x;
  int lane = threadIdx.x & 63;
  int c = 0;
  int i0 = 0, i1 = 0;
  if (kp < K_KEEP) {
    int o = kept[kp];
    i0 = rowstart1[o]; i1 = rowstart1[o + 1];
    int i = i0;
    for (; i + 4 <= i1; i += 4) {
      int s0 = csr1[i], s1 = csr1[i + 1], s2 = csr1[i + 2], s3 = csr1[i + 3];
      c += (new_idx[s0] >= 0) + (new_idx[s1] >= 0) + (new_idx[s2] >= 0) + (new_idx[s3] >= 0);
    }
    for (; i < i1; ++i) c += (new_idx[csr1[i]] >= 0);
  }
  // wave inclusive scan of c
  int pre = c;
  #pragma unroll
  for (int off = 1; off < 64; off <<= 1) {
    int t = __shfl_up(pre, off);
    if (lane >= off) pre += t;
  }
  int wtot = __shfl(pre, 63);
  int wbase = 0;
  if (lane == 0) wbase = (int)atomicAdd(&ctl->pad, (u32)wtot);
  wbase = __shfl(wbase, 0);
  int base = wbase + pre - c;
  if (kp < K_KEEP) {
    rowstart2[kp] = base;
    len2[kp] = c;
    dis2[kp] = rsqrtf(1.0f + (float)c);
    int w = base;
    for (int i = i0; i < i1; ++i) {
      int ns = new_idx[csr1[i]];
      if (ns >= 0) csr2[w++] = ns;
    }
  }
}

// ---------------- launch ----------------

extern "C" void kernel_launch(void* const* d_in, const int* in_sizes, int n_in,
                              void* d_out, int out_size, void* d_ws, size_t ws_size,
                              hipStream_t stream)
{
  const void* x  = d_in[0];
  const int*  ei = (const int*)d_in[1];
  const void* W1 = d_in[3];
  const void* b1 = d_in[4];
  const void* pw = d_in[5];
  const void* W2 = d_in[6];
  const void* b2 = d_in[7];
  const void* W3 = d_in[8];
  const void* b3 = d_in[9];
  const void* W4 = d_in[10];
  const void* b4 = d_in[11];

  const int* src = ei;
  const int* dst = ei + N_EDGES;

  float* F = (float*)d_ws;
  bf16*  A16       = (bf16*)F;               // N x 128 bf16
  bf16*  B16       = (bf16*)(F + 3200000);   // N x 128 bf16
  bf16*  C16       = (bf16*)(F + 6400000);   // K x 128 bf16 (also conv1's G [N x 64])
  u32*   xbf       = (u32*)(F + 9000000);    // N x 32 u32 (x as bf16 pairs, only if fp32 input)
  float* dis1      = F + 10600000;           // 50000
  float* dis2      = F + 10650000;           // 40000
  float* score     = F + 10690000;           // 50000
  u64*   keys      = (u64*)(F + 10740000);   // 50000 u64
  int*   new_idx   = (int*)(F + 10840000);   // 50000
  int*   kept      = (int*)(F + 10890000);   // 40000
  int*   len2      = (int*)(F + 10930000);   // 40000
  int*   rowstart1 = (int*)(F + 10970000);   // 50001
  int*   rowstart2 = (int*)(F + 11020004);   // 40000
  int*   csr1      = (int*)(F + 11060008);   // 800000
  int*   csr2      = (int*)(F + 11860008);   // 800000
  Ctl*   ctl       = (Ctl*)(F + 12660008);   // ~1.1 KB
  int*   detcnt    = (int*)(F + 12660856);   // 64
  int*   bucket_cur= (int*)(F + 12660920);   // 196
  u32*   bucketbuf = (u32*)(F + 12726908);   // 196*6144
  float* partial   = F + 13931132;           // 64 x 1024

  const int NB1 = (N_NODES + 255) / 256;     // 196
  const int EB2 = (N_EDGES + 2047) / 2048;   // 391
  const int GB1 = (N_NODES + 63) / 64;       // 782
  const int AB1 = N_NODES * 32 / 256;        // 6250
  const int ABK = K_KEEP * 32 / 256;         // 5000
  const int CB2 = (K_KEEP + 255) / 256;      // 157
  const int NBF = 1024;                      // final-gather blocks

  init_kernel<<<NB1, 256, 0, stream>>>((const unsigned short*)x, bucket_cur, detcnt, ctl);

  // CSR graph 1 via bucket sort (+fused dtype/norm, +x->bf16 conversion iff fp32 input)
  bucket_scatter_kernel<<<EB2, 256, 0, stream>>>(src, dst, bucket_cur, bucketbuf, x, xbf,
                                                 detcnt, pw, ctl);
  csr_from_buckets_kernel<<<BKT, 256, 0, stream>>>(bucketbuf, bucket_cur, rowstart1, dis1, csr1);

  // conv1 (gather-first on bf16 x): G = A_norm . x ; h1 = G @ W1 + b1 (+fused score/keys)
  agg_gather64_kernel<<<AB1, 256, 0, stream>>>((const bf16*)x, (const bf16*)xbf, rowstart1, nullptr,
                                               csr1, dis1, nullptr, ctl, C16, N_NODES, 0, 0);
  gemm_in_kernel<<<GB1, 256, 0, stream>>>(C16, W1, b1, pw, B16, ctl, score, keys);

  // top-K select (6 x 8-bit radix, separate launches; early-exit skips tie-break passes)
  for (int p = 0; p < 6; ++p)
    histpick_kernel<<<NB1, 256, 0, stream>>>(keys, ctl, 40 - 8 * p, NB1);
  mark_kernel<<<NB1, 256, 0, stream>>>(keys, ctl, new_idx, kept);

  // CSR graph 2 in one kernel (row bases via wave-aggregated atomic; order-free)
  csr2_build_kernel<<<CB2, 256, 0, stream>>>(kept, rowstart1, csr1, new_idx, ctl,
                                             rowstart2, len2, dis2, csr2);

  // conv2: gemm-first (fused hp: relu*score on kept rows): A = hp @ W2 ; h2 = gather(A) + b2
  gemm_128_64_kernel<<<K_KEEP / 64, 256, 0, stream>>>(B16, W2, A16, ctl, K_KEEP, 0, kept, score);
  agg_gather64_kernel<<<ABK, 256, 0, stream>>>(A16, A16, rowstart2, len2, csr2, dis2, b2, ctl, C16, K_KEEP, 0, 1);

  // conv3: gather-first: G = gather(relu(h2)) ; h3 = G @ W3 + b3
  agg_gather64_kernel<<<ABK, 256, 0, stream>>>(C16, C16, rowstart2, len2, csr2, dis2, b3, ctl, A16, K_KEEP, 1, 0);
  gemm_64_128_kernel<<<K_KEEP / 64, 256, 0, stream>>>(A16, W3, b3, B16, ctl, K_KEEP);

  // conv4: gemm-first: A = relu(h3) @ W4 ; partials = gather(A) ; separate tiny reduce
  gemm_128_64_kernel<<<K_KEEP / 64, 256, 0, stream>>>(B16, W4, A16, ctl, K_KEEP, 1, nullptr, nullptr);
  agg_gather64_final_kernel<<<NBF, 256, 0, stream>>>(A16, rowstart2, len2, csr2, dis2,
                                                     partial, K_KEEP, NBF);
  reduce_out_kernel<<<64, 256, 0, stream>>>(partial, b4, ctl, d_out, NBF);
}

// Round 7
// 331.849 us; speedup vs baseline: 1.8899x; 1.0499x over previous
//
#include <hip/hip_runtime.h>
#include <hip/hip_bf16.h>
#include <stdint.h>

#define N_NODES 50000
#define N_EDGES 800000
#define K_KEEP  40000
#define BKT     196        // ceil(N_NODES/256) dst-range buckets
#define BCAP    6144       // per-bucket capacity (mean 4081, +32 sigma)

typedef unsigned long long u64;
typedef unsigned int u32;
typedef unsigned short u16;
typedef __hip_bfloat16 bf16;
typedef __hip_bfloat162 bf16x2;
typedef __attribute__((ext_vector_type(8))) short short8;
typedef __attribute__((ext_vector_type(8))) unsigned short ushort8;
typedef __attribute__((ext_vector_type(4))) float f32x4;

struct Ctl {
  u64 prefix;
  u32 kremain;
  u32 cnt;
  float inv_norm;
  u32 isfp32;
  u32 done;         // radix pass arrival counter (reset by picker each pass)
  u32 pad;          // csr2 edge cursor
  u32 gen;          // TopK resolved-early flag
  u32 done2;        // (unused; layout keep)
  u32 hist[256];    // radix histogram (LDS-aggregated flushes only)
};

__device__ __forceinline__ float bf2f(bf16 v) { return __bfloat162float(v); }
__device__ __forceinline__ float bfbits2f(unsigned short u) {
  return __uint_as_float(((u32)u) << 16);
}
__device__ __forceinline__ float loadF(const void* p, size_t i, bool f32) {
  return f32 ? ((const float*)p)[i] : bf2f(((const bf16*)p)[i]);
}
__device__ __forceinline__ short f2bf_bits(float f) {
  bf16 t = __float2bfloat16(f);
  return *(const short*)&t;
}

// ---------------- init (+parallel dtype detect, proven R5-R8) ----------------

__global__ void init_kernel(const unsigned short* __restrict__ x16,
                            int* __restrict__ bucket_cur, int* __restrict__ detcnt, Ctl* ctl) {
  __shared__ u32 dsh[256];
  int i = blockIdx.x * 256 + threadIdx.x;
  if (i < BKT) bucket_cur[i] = i * BCAP;
  if (blockIdx.x == 0) {
    ctl->hist[threadIdx.x] = 0u;
    if (threadIdx.x == 0) {
      ctl->prefix = 0ull; ctl->kremain = K_KEEP; ctl->cnt = 0u;
      ctl->done = 0u; ctl->pad = 0u; ctl->gen = 0u; ctl->done2 = 0u;
    }
  }
  if (blockIdx.x < 64) {
    int base = blockIdx.x * 2048;
    u32 c = 0;
    for (int j = threadIdx.x; j < 2048; j += 256) {
      u32 h = x16[base + j];
      if ((h & 0x7F80u) == 0x7F80u) c++;
    }
    dsh[threadIdx.x] = c;
    __syncthreads();
    for (int s = 128; s > 0; s >>= 1) {
      if (threadIdx.x < s) dsh[threadIdx.x] += dsh[threadIdx.x + s];
      __syncthreads();
    }
    if (threadIdx.x == 0) detcnt[blockIdx.x] = (int)dsh[0];
  }
}

// ------- CSR1 bucket scatter (proven R8) + fused dtype/norm + fp32->bf16 convert -------

__global__ void bucket_scatter_kernel(const int* __restrict__ src, const int* __restrict__ dst,
                                      int* __restrict__ bucket_cur, u32* __restrict__ bucketbuf,
                                      const void* __restrict__ x, u32* __restrict__ xbf,
                                      const int* __restrict__ detcnt, const void* __restrict__ pw,
                                      Ctl* ctl)
{
  __shared__ u32 hist[BKT];
  __shared__ u32 base[BKT];
  __shared__ int f32sh;
  __shared__ float ns[128];
  const int tid = threadIdx.x;
  const int e0 = blockIdx.x * 2048;

  // dtype detect from detcnt (written by init, prior dispatch)
  if (tid < 64) {
    int dc = detcnt[tid];
    for (int off = 32; off; off >>= 1) dc += __shfl_down(dc, off);
    if (tid == 0) f32sh = (dc >= 16) ? 1 : 0;
  }
  for (int t = tid; t < BKT; t += 256) hist[t] = 0;
  __syncthreads();
  const bool f32in = f32sh != 0;

  #pragma unroll
  for (int j = 0; j < 8; ++j) {
    int e = e0 + j * 256 + tid;
    if (e < N_EDGES) atomicAdd(&hist[dst[e] >> 8], 1u);
  }
  __syncthreads();
  for (int t = tid; t < BKT; t += 256) {
    u32 c = hist[t];
    base[t] = c ? (u32)atomicAdd(&bucket_cur[t], (int)c) : 0u;
    hist[t] = 0;
  }
  __syncthreads();
  #pragma unroll
  for (int j = 0; j < 8; ++j) {
    int e = e0 + j * 256 + tid;
    if (e < N_EDGES) {
      int d = dst[e];
      int b = d >> 8;
      u32 pos = base[b] + atomicAdd(&hist[b], 1u);
      bucketbuf[pos] = ((u32)src[e] << 8) | (u32)(d & 255);
    }
  }
  // fused x -> bf16 (pair) conversion; only when input is fp32
  if (f32in) {
    const int p0 = blockIdx.x * 4096;
    const float2* xf = (const float2*)x;
    for (int j = tid; j < 4096; j += 256) {
      int p = p0 + j;
      if (p < N_NODES * 32) {
        float2 v = xf[p];
        u32 w = ((u32)(u16)f2bf_bits(v.y) << 16) | (u32)(u16)f2bf_bits(v.x);
        xbf[p] = w;
      }
    }
  }
  // fused norm: block 0 computes inv_norm + publishes isfp32
  if (blockIdx.x == 0) {
    if (tid < 128) { float v = loadF(pw, tid, f32in); ns[tid] = v * v; }
    __syncthreads();
    for (int s = 64; s > 0; s >>= 1) {
      if (tid < s) ns[tid] += ns[tid + s];
      __syncthreads();
    }
    if (tid == 0) {
      ctl->inv_norm = 1.0f / sqrtf(ns[0]);
      ctl->isfp32 = f32in ? 1u : 0u;
    }
  }
}

// ------- CSR1 from buckets (inline bucket scan; no separate scan kernel) -------

__global__ void csr_from_buckets_kernel(const u32* __restrict__ bucketbuf, const int* __restrict__ bucket_cur,
                                        int* __restrict__ rowstart, float* __restrict__ dis,
                                        int* __restrict__ csr)
{
  __shared__ u32 cnt[256];
  __shared__ u32 loc[256];
  __shared__ u32 cur[256];
  const int b = blockIdx.x;
  const int tid = threadIdx.x;

  // inline scan of all bucket sizes -> off0 for this bucket
  int v = (tid < BKT) ? (bucket_cur[tid] - tid * BCAP) : 0;
  loc[tid] = (u32)v;
  __syncthreads();
  for (int off = 1; off < 256; off <<= 1) {
    u32 t = (tid >= off) ? loc[tid - off] : 0;
    __syncthreads();
    loc[tid] += t;
    __syncthreads();
  }
  const int bc = bucket_cur[b] - b * BCAP;
  const int off0 = (int)loc[b] - bc;
  if (b == BKT - 1 && tid == 0) rowstart[N_NODES] = (int)loc[BKT - 1];
  __syncthreads();

  const u32* buf = bucketbuf + (size_t)b * BCAP;
  cnt[tid] = 0;
  __syncthreads();
  for (int i = tid; i < bc; i += 256) atomicAdd(&cnt[buf[i] & 255u], 1u);
  __syncthreads();
  u32 c = cnt[tid];
  loc[tid] = c;
  __syncthreads();
  for (int off = 1; off < 256; off <<= 1) {
    u32 t = (tid >= off) ? loc[tid - off] : 0;
    __syncthreads();
    loc[tid] += t;
    __syncthreads();
  }
  int node = b * 256 + tid;
  u32 excl = loc[tid] - c;
  if (node < N_NODES) {
    rowstart[node] = off0 + (int)excl;
    dis[node] = rsqrtf(1.0f + (float)c);
  }
  cur[tid] = off0 + excl;
  __syncthreads();
  for (int i = tid; i < bc; i += 256) {
    u32 p = buf[i];
    u32 pos = atomicAdd(&cur[p & 255u], 1u);
    csr[pos] = (int)(p >> 8);
  }
}

// ------- unified gather: 8 lanes/node, 16B ushort8 loads; ILP-4 (R7 widened) -------

__global__ void agg_gather64_kernel(const bf16* __restrict__ hW, const bf16* __restrict__ hWalt,
                                    const int* __restrict__ rowstart,
                                    const int* __restrict__ len, const int* __restrict__ csr,
                                    const float* __restrict__ dis,
                                    const void* __restrict__ b, const Ctl* __restrict__ ctl,
                                    bf16* __restrict__ agg, int M, int relusrc, int addbias)
{
  const bool f32 = ctl->isfp32 != 0;
  int gid = blockIdx.x * 256 + threadIdx.x;
  int d = gid >> 3;
  int lane = gid & 7;                       // 8 lanes/node, 8 channels each
  if (d >= M) return;
  const ushort8* H = (const ushort8*)(f32 ? hWalt : hW);   // row = 8 x ushort8
  float dd = dis[d];
  float sw = dd * dd;
  float acc[8];
  ushort8 v = H[(size_t)d * 8 + lane];
  #pragma unroll
  for (int c = 0; c < 8; ++c) {
    float t = bfbits2f(v[c]);
    if (relusrc) t = fmaxf(t, 0.f);
    acc[c] = t * sw + (addbias ? loadF(b, 8 * lane + c, f32) : 0.f);
  }
  int i = rowstart[d];
  int i1 = len ? (i + len[d]) : rowstart[d + 1];
  for (; i + 4 <= i1; i += 4) {
    int s0 = csr[i], s1 = csr[i + 1], s2 = csr[i + 2], s3 = csr[i + 3];
    float w0 = dd * dis[s0], w1 = dd * dis[s1], w2 = dd * dis[s2], w3 = dd * dis[s3];
    ushort8 v0 = H[(size_t)s0 * 8 + lane];
    ushort8 v1 = H[(size_t)s1 * 8 + lane];
    ushort8 v2 = H[(size_t)s2 * 8 + lane];
    ushort8 v3 = H[(size_t)s3 * 8 + lane];
    #pragma unroll
    for (int c = 0; c < 8; ++c) {
      float x0 = bfbits2f(v0[c]), x1 = bfbits2f(v1[c]);
      float x2 = bfbits2f(v2[c]), x3 = bfbits2f(v3[c]);
      if (relusrc) {
        x0 = fmaxf(x0, 0.f); x1 = fmaxf(x1, 0.f);
        x2 = fmaxf(x2, 0.f); x3 = fmaxf(x3, 0.f);
      }
      acc[c] += w0 * x0 + w1 * x1 + w2 * x2 + w3 * x3;
    }
  }
  for (; i < i1; ++i) {
    int s = csr[i];
    float w = dd * dis[s];
    ushort8 vv = H[(size_t)s * 8 + lane];
    #pragma unroll
    for (int c = 0; c < 8; ++c) {
      float xx = bfbits2f(vv[c]);
      if (relusrc) xx = fmaxf(xx, 0.f);
      acc[c] += w * xx;
    }
  }
  ushort8 outv;
  #pragma unroll
  for (int c = 0; c < 8; ++c) outv[c] = (unsigned short)f2bf_bits(acc[c]);
  ((ushort8*)agg)[(size_t)d * 8 + lane] = outv;
}

// ---------------- MFMA GEMMs (16x16x32 bf16, fp32 acc) ----------------

// conv1: Y[N,128] = G[N,64] @ W1 + b1, fused pooling score/keys
__global__ void gemm_in_kernel(const bf16* __restrict__ G, const void* __restrict__ W,
                               const void* __restrict__ b, const void* __restrict__ pw,
                               bf16* __restrict__ Y, const Ctl* __restrict__ ctl,
                               float* __restrict__ score, u64* __restrict__ keys)
{
  __shared__ short Xs[64 * 72];
  __shared__ short Wt[128 * 72];
  __shared__ float bs[128];
  __shared__ float ps[128];
  const bool f32 = ctl->isfp32 != 0;
  const int tid = threadIdx.x;
  const int row0 = blockIdx.x * 64;

  for (int i = tid; i < 64 * 128; i += 256) {
    int k = i >> 7, n = i & 127;
    Wt[n * 72 + k] = f32 ? f2bf_bits(((const float*)W)[i]) : ((const short*)W)[i];
  }
  const u32* G2 = (const u32*)G;
  for (int p = tid; p < 64 * 32; p += 256) {
    int r = p >> 5, kp = p & 31;
    int gr = row0 + r;
    u32 v = (gr < N_NODES) ? G2[(size_t)gr * 32 + kp] : 0u;
    *(u32*)&Xs[r * 72 + 2 * kp] = v;
  }
  for (int i = tid; i < 128; i += 256) { bs[i] = loadF(b, i, f32); ps[i] = loadF(pw, i, f32); }
  __syncthreads();

  const int lane = tid & 63;
  const int w = tid >> 6;
  const int l16 = lane & 15;
  const int quad = lane >> 4;
  f32x4 acc[8];
  #pragma unroll
  for (int ct = 0; ct < 8; ++ct) acc[ct] = (f32x4){0.f, 0.f, 0.f, 0.f};
  const int arow = w * 16 + l16;
  #pragma unroll
  for (int kc = 0; kc < 2; ++kc) {
    short8 a = *(short8*)&Xs[arow * 72 + kc * 32 + quad * 8];
    #pragma unroll
    for (int ct = 0; ct < 8; ++ct) {
      short8 bb = *(short8*)&Wt[(ct * 16 + l16) * 72 + kc * 32 + quad * 8];
      acc[ct] = __builtin_amdgcn_mfma_f32_16x16x32_bf16(a, bb, acc[ct], 0, 0, 0);
    }
  }
  float inv_norm = ctl->inv_norm;
  #pragma unroll
  for (int r = 0; r < 4; ++r) {
    int gr = row0 + w * 16 + quad * 4 + r;
    float p = 0.f;
    #pragma unroll
    for (int ct = 0; ct < 8; ++ct) {
      int col = ct * 16 + l16;
      float h = acc[ct][r] + bs[col];
      if (gr < N_NODES) Y[(size_t)gr * 128 + col] = __float2bfloat16(h);
      p += fmaxf(h, 0.f) * ps[col];
    }
    p += __shfl_down(p, 8, 16);
    p += __shfl_down(p, 4, 16);
    p += __shfl_down(p, 2, 16);
    p += __shfl_down(p, 1, 16);
    if (l16 == 0 && gr < N_NODES) {
      float sc = tanhf(p * inv_norm);
      score[gr] = sc;
      u32 u = __float_as_uint(sc);
      u = (u & 0x80000000u) ? ~u : (u | 0x80000000u);
      keys[gr] = (((u64)u) << 16) | (u64)(0xFFFFu - (u32)gr);
    }
  }
}

// Y[M,64] = (relu?)X[M,128] @ W[128,64]; M multiple of 64
// kept!=null: X row = kept[row], apply relu*score[kept[row]] (fused TopK hp)
__global__ void gemm_128_64_kernel(const bf16* __restrict__ X, const void* __restrict__ W,
                                   bf16* __restrict__ Y, const Ctl* __restrict__ ctl,
                                   int M, int relu_x,
                                   const int* __restrict__ kept, const float* __restrict__ score)
{
  __shared__ short Xs[64 * 136];
  __shared__ short Wt[64 * 136];
  __shared__ int keptS[64];
  __shared__ float scS[64];
  const bool f32 = ctl->isfp32 != 0;
  const int tid = threadIdx.x;
  const int row0 = blockIdx.x * 64;

  if (kept) {
    for (int i = tid; i < 64; i += 256) {
      int o = kept[row0 + i];
      keptS[i] = o;
      scS[i] = score[o];
    }
  }
  __syncthreads();

  for (int i = tid; i < 128 * 64; i += 256) {
    int k = i >> 6, n = i & 63;
    Wt[n * 136 + k] = f32 ? f2bf_bits(((const float*)W)[i]) : ((const short*)W)[i];
  }
  const u32* X2 = (const u32*)X;
  for (int p = tid; p < 64 * 64; p += 256) {
    int r = p >> 6, kp = p & 63;
    int srow = kept ? keptS[r] : (row0 + r);
    u32 v = X2[(size_t)srow * 64 + kp];
    if (relu_x) {
      if (v & 0x8000u) v &= 0xFFFF0000u;
      if (v & 0x80000000u) v &= 0x0000FFFFu;
    }
    if (kept) {
      bf16x2 h = *(bf16x2*)&v;
      float s = scS[r];
      bf16x2 o;
      o.x = __float2bfloat16(fmaxf(bf2f(h.x), 0.f) * s);
      o.y = __float2bfloat16(fmaxf(bf2f(h.y), 0.f) * s);
      v = *(u32*)&o;
    }
    *(u32*)&Xs[r * 136 + 2 * kp] = v;
  }
  __syncthreads();

  const int lane = tid & 63;
  const int w = tid >> 6;
  const int l16 = lane & 15;
  const int quad = lane >> 4;
  f32x4 acc[4];
  #pragma unroll
  for (int ct = 0; ct < 4; ++ct) acc[ct] = (f32x4){0.f, 0.f, 0.f, 0.f};
  const int arow = w * 16 + l16;
  #pragma unroll
  for (int kc = 0; kc < 4; ++kc) {
    short8 a = *(short8*)&Xs[arow * 136 + kc * 32 + quad * 8];
    #pragma unroll
    for (int ct = 0; ct < 4; ++ct) {
      short8 bb = *(short8*)&Wt[(ct * 16 + l16) * 136 + kc * 32 + quad * 8];
      acc[ct] = __builtin_amdgcn_mfma_f32_16x16x32_bf16(a, bb, acc[ct], 0, 0, 0);
    }
  }
  #pragma unroll
  for (int ct = 0; ct < 4; ++ct)
    #pragma unroll
    for (int r = 0; r < 4; ++r) {
      int gr = row0 + w * 16 + quad * 4 + r;
      Y[(size_t)gr * 64 + ct * 16 + l16] = __float2bfloat16(acc[ct][r]);
    }
}

// conv3: Y[M,128] = X[M,64] @ W[64,128] + b; M multiple of 64
__global__ void gemm_64_128_kernel(const bf16* __restrict__ X, const void* __restrict__ W,
                                   const void* __restrict__ b, bf16* __restrict__ Y,
                                   const Ctl* __restrict__ ctl, int M)
{
  __shared__ short Xs[64 * 72];
  __shared__ short Wt[128 * 72];
  __shared__ float bs[128];
  const bool f32 = ctl->isfp32 != 0;
  const int tid = threadIdx.x;
  const int row0 = blockIdx.x * 64;

  for (int i = tid; i < 64 * 128; i += 256) {
    int k = i >> 7, n = i & 127;
    Wt[n * 72 + k] = f32 ? f2bf_bits(((const float*)W)[i]) : ((const short*)W)[i];
  }
  const u32* X2 = (const u32*)X;
  for (int p = tid; p < 64 * 32; p += 256) {
    int r = p >> 5, kp = p & 31;
    *(u32*)&Xs[r * 72 + 2 * kp] = X2[(size_t)(row0 + r) * 32 + kp];
  }
  for (int i = tid; i < 128; i += 256) bs[i] = loadF(b, i, f32);
  __syncthreads();

  const int lane = tid & 63;
  const int w = tid >> 6;
  const int l16 = lane & 15;
  const int quad = lane >> 4;
  f32x4 acc[8];
  #pragma unroll
  for (int ct = 0; ct < 8; ++ct) acc[ct] = (f32x4){0.f, 0.f, 0.f, 0.f};
  const int arow = w * 16 + l16;
  #pragma unroll
  for (int kc = 0; kc < 2; ++kc) {
    short8 a = *(short8*)&Xs[arow * 72 + kc * 32 + quad * 8];
    #pragma unroll
    for (int ct = 0; ct < 8; ++ct) {
      short8 bb = *(short8*)&Wt[(ct * 16 + l16) * 72 + kc * 32 + quad * 8];
      acc[ct] = __builtin_amdgcn_mfma_f32_16x16x32_bf16(a, bb, acc[ct], 0, 0, 0);
    }
  }
  #pragma unroll
  for (int ct = 0; ct < 8; ++ct)
    #pragma unroll
    for (int r = 0; r < 4; ++r) {
      int gr = row0 + w * 16 + quad * 4 + r;
      int col = ct * 16 + l16;
      Y[(size_t)gr * 128 + col] = __float2bfloat16(acc[ct][r] + bs[col]);
    }
}

// conv4: gather (8 lanes/node, 16B loads) + register acc + per-block partial
__global__ void agg_gather64_final_kernel(const bf16* __restrict__ hW, const int* __restrict__ rowstart,
                                          const int* __restrict__ len, const int* __restrict__ csr,
                                          const float* __restrict__ dis,
                                          float* __restrict__ partial, int M, int nblk)
{
  __shared__ float cs[64];
  const int tid = threadIdx.x;
  if (tid < 64) cs[tid] = 0.f;
  __syncthreads();
  const int lane = tid & 7;
  const ushort8* H = (const ushort8*)hW;
  float acc[8];
  #pragma unroll
  for (int c = 0; c < 8; ++c) acc[c] = 0.f;
  for (int d = (blockIdx.x * 256 + tid) >> 3; d < M; d += nblk * 32) {
    float dd = dis[d];
    float sw = dd * dd;
    ushort8 v = H[(size_t)d * 8 + lane];
    #pragma unroll
    for (int c = 0; c < 8; ++c) acc[c] += bfbits2f(v[c]) * sw;
    int i = rowstart[d];
    int i1 = i + len[d];
    for (; i + 4 <= i1; i += 4) {
      int s0 = csr[i], s1 = csr[i + 1], s2 = csr[i + 2], s3 = csr[i + 3];
      float w0 = dd * dis[s0], w1 = dd * dis[s1], w2 = dd * dis[s2], w3 = dd * dis[s3];
      ushort8 v0 = H[(size_t)s0 * 8 + lane];
      ushort8 v1 = H[(size_t)s1 * 8 + lane];
      ushort8 v2 = H[(size_t)s2 * 8 + lane];
      ushort8 v3 = H[(size_t)s3 * 8 + lane];
      #pragma unroll
      for (int c = 0; c < 8; ++c) {
        acc[c] += w0 * bfbits2f(v0[c]) + w1 * bfbits2f(v1[c])
                + w2 * bfbits2f(v2[c]) + w3 * bfbits2f(v3[c]);
      }
    }
    for (; i < i1; ++i) {
      int s = csr[i];
      float w = dd * dis[s];
      ushort8 vv = H[(size_t)s * 8 + lane];
      #pragma unroll
      for (int c = 0; c < 8; ++c) acc[c] += w * bfbits2f(vv[c]);
    }
  }
  #pragma unroll
  for (int c = 0; c < 8; ++c) atomicAdd(&cs[8 * lane + c], acc[c]);
  __syncthreads();
  if (tid < 64) partial[(size_t)tid * nblk + blockIdx.x] = cs[tid];
}

__global__ void reduce_out_kernel(const float* __restrict__ partial, const void* __restrict__ b,
                                  const Ctl* __restrict__ ctl, void* __restrict__ out, int nblk)
{
  __shared__ float sh[256];
  int c = blockIdx.x;
  float s = 0.f;
  for (int j = threadIdx.x; j < nblk; j += 256) s += partial[(size_t)c * nblk + j];
  sh[threadIdx.x] = s;
  __syncthreads();
  for (int st = 128; st > 0; st >>= 1) {
    if (threadIdx.x < st) sh[threadIdx.x] += sh[threadIdx.x + st];
    __syncthreads();
  }
  if (threadIdx.x == 0) {
    const bool f32 = ctl->isfp32 != 0;
    float val = sh[0] / (float)K_KEEP + loadF(b, c, f32);
    if (f32) ((float*)out)[c] = val;
    else     ((bf16*)out)[c] = __float2bfloat16(val);
  }
}

// ------- TopK select: separate-launch hist+pick (proven R0/R2), parallel pick + early-exit -------

__global__ void histpick_kernel(const u64* __restrict__ keys, Ctl* ctl, int shift, int nblocks) {
  __shared__ u32 lh[256];
  __shared__ u32 sfx[256];
  __shared__ int lastflag;
  __shared__ int selsh;
  const int tid = threadIdx.x;
  if (ctl->gen != 0u) return;          // threshold already resolved by earlier pass
  lh[tid] = 0;
  __syncthreads();
  u64 prefix = ctl->prefix;
  int i = blockIdx.x * 256 + tid;
  if (i < N_NODES) {
    u64 key = keys[i];
    if ((key >> (shift + 8)) == (prefix >> (shift + 8)))
      atomicAdd(&lh[(u32)((key >> shift) & 0xFF)], 1u);
  }
  __syncthreads();
  u32 c = lh[tid];
  if (c) atomicAdd(&ctl->hist[tid], c);
  __syncthreads();
  if (tid == 0) {
    __threadfence();
    u32 old = atomicAdd(&ctl->done, 1u);
    lastflag = (old == (u32)(nblocks - 1));
  }
  __syncthreads();
  if (!lastflag) return;
  // last block: parallel pick via suffix scan
  u32 cc = atomicExch(&ctl->hist[tid], 0u);   // coherent read + zero for next pass
  sfx[tid] = cc;
  __syncthreads();
  for (int off = 1; off < 256; off <<= 1) {
    u32 t = (tid + off < 256) ? sfx[tid + off] : 0u;
    __syncthreads();
    sfx[tid] += t;
    __syncthreads();
  }
  u32 kr = ctl->kremain;
  u32 above = (tid < 255) ? sfx[tid + 1] : 0u;
  if (sfx[tid] >= kr && above < kr) selsh = tid;   // unique (sfx non-increasing)
  __syncthreads();
  if (tid == 0) {
    int sel = selsh;
    u32 ab = (sel < 255) ? sfx[sel + 1] : 0u;
    u32 newkr = kr - ab;
    u32 bucketcnt = sfx[sel] - ab;
    ctl->kremain = newkr;
    ctl->prefix = prefix | (((u64)(u32)sel) << shift);
    if (newkr == bucketcnt) ctl->gen = 1u;  // whole boundary bucket kept -> resolved
    ctl->done = 0u;
  }
}

__global__ void mark_kernel(const u64* __restrict__ keys, Ctl* ctl,
                            int* __restrict__ new_idx, int* __restrict__ kept)
{
  int i = blockIdx.x * 256 + threadIdx.x;
  if (i >= N_NODES) return;
  if (keys[i] >= ctl->prefix) {
    int pos = (int)atomicAdd(&ctl->cnt, 1u);
    new_idx[i] = pos;
    kept[pos] = i;
  } else {
    new_idx[i] = -1;
  }
}

// ------- CSR2 in ONE kernel: count + wave-aggregated alloc + fill (order-free rows) -------

__global__ void csr2_build_kernel(const int* __restrict__ kept, const int* __restrict__ rowstart1,
                                  const int* __restrict__ csr1, const int* __restrict__ new_idx,
                                  Ctl* ctl, int* __restrict__ rowstart2, int* __restrict__ len2,
                                  float* __restrict__ dis2, int* __restrict__ csr2)
{
  int kp = blockIdx.x * 256 + threadIdx.x;
  int lane = threadIdx.x & 63;
  int c = 0;
  int i0 = 0, i1 = 0;
  if (kp < K_KEEP) {
    int o = kept[kp];
    i0 = rowstart1[o]; i1 = rowstart1[o + 1];
    int i = i0;
    for (; i + 4 <= i1; i += 4) {
      int s0 = csr1[i], s1 = csr1[i + 1], s2 = csr1[i + 2], s3 = csr1[i + 3];
      c += (new_idx[s0] >= 0) + (new_idx[s1] >= 0) + (new_idx[s2] >= 0) + (new_idx[s3] >= 0);
    }
    for (; i < i1; ++i) c += (new_idx[csr1[i]] >= 0);
  }
  // wave inclusive scan of c
  int pre = c;
  #pragma unroll
  for (int off = 1; off < 64; off <<= 1) {
    int t = __shfl_up(pre, off);
    if (lane >= off) pre += t;
  }
  int wtot = __shfl(pre, 63);
  int wbase = 0;
  if (lane == 0) wbase = (int)atomicAdd(&ctl->pad, (u32)wtot);
  wbase = __shfl(wbase, 0);
  int base = wbase + pre - c;
  if (kp < K_KEEP) {
    rowstart2[kp] = base;
    len2[kp] = c;
    dis2[kp] = rsqrtf(1.0f + (float)c);
    int w = base;
    for (int i = i0; i < i1; ++i) {
      int ns = new_idx[csr1[i]];
      if (ns >= 0) csr2[w++] = ns;
    }
  }
}

// ---------------- launch ----------------

extern "C" void kernel_launch(void* const* d_in, const int* in_sizes, int n_in,
                              void* d_out, int out_size, void* d_ws, size_t ws_size,
                              hipStream_t stream)
{
  const void* x  = d_in[0];
  const int*  ei = (const int*)d_in[1];
  const void* W1 = d_in[3];
  const void* b1 = d_in[4];
  const void* pw = d_in[5];
  const void* W2 = d_in[6];
  const void* b2 = d_in[7];
  const void* W3 = d_in[8];
  const void* b3 = d_in[9];
  const void* W4 = d_in[10];
  const void* b4 = d_in[11];

  const int* src = ei;
  const int* dst = ei + N_EDGES;

  float* F = (float*)d_ws;
  bf16*  A16       = (bf16*)F;               // N x 128 bf16
  bf16*  B16       = (bf16*)(F + 3200000);   // N x 128 bf16
  bf16*  C16       = (bf16*)(F + 6400000);   // K x 128 bf16 (also conv1's G [N x 64])
  u32*   xbf       = (u32*)(F + 9000000);    // N x 32 u32 (x as bf16 pairs, only if fp32 input)
  float* dis1      = F + 10600000;           // 50000
  float* dis2      = F + 10650000;           // 40000
  float* score     = F + 10690000;           // 50000
  u64*   keys      = (u64*)(F + 10740000);   // 50000 u64
  int*   new_idx   = (int*)(F + 10840000);   // 50000
  int*   kept      = (int*)(F + 10890000);   // 40000
  int*   len2      = (int*)(F + 10930000);   // 40000
  int*   rowstart1 = (int*)(F + 10970000);   // 50001
  int*   rowstart2 = (int*)(F + 11020004);   // 40000
  int*   csr1      = (int*)(F + 11060008);   // 800000
  int*   csr2      = (int*)(F + 11860008);   // 800000
  Ctl*   ctl       = (Ctl*)(F + 12660008);   // ~1.1 KB
  int*   detcnt    = (int*)(F + 12660856);   // 64
  int*   bucket_cur= (int*)(F + 12660920);   // 196
  u32*   bucketbuf = (u32*)(F + 12726908);   // 196*6144
  float* partial   = F + 13931132;           // 64 x 1024

  const int NB1 = (N_NODES + 255) / 256;     // 196
  const int EB2 = (N_EDGES + 2047) / 2048;   // 391
  const int GB1 = (N_NODES + 63) / 64;       // 782
  const int AB1 = (N_NODES * 8 + 255) / 256; // 1563 (8 lanes/node)
  const int ABK = K_KEEP * 8 / 256;          // 1250
  const int CB2 = (K_KEEP + 255) / 256;      // 157
  const int NBF = 1024;                      // final-gather blocks

  init_kernel<<<NB1, 256, 0, stream>>>((const unsigned short*)x, bucket_cur, detcnt, ctl);

  // CSR graph 1 via bucket sort (+fused dtype/norm, +x->bf16 conversion iff fp32 input)
  bucket_scatter_kernel<<<EB2, 256, 0, stream>>>(src, dst, bucket_cur, bucketbuf, x, xbf,
                                                 detcnt, pw, ctl);
  csr_from_buckets_kernel<<<BKT, 256, 0, stream>>>(bucketbuf, bucket_cur, rowstart1, dis1, csr1);

  // conv1 (gather-first on bf16 x): G = A_norm . x ; h1 = G @ W1 + b1 (+fused score/keys)
  agg_gather64_kernel<<<AB1, 256, 0, stream>>>((const bf16*)x, (const bf16*)xbf, rowstart1, nullptr,
                                               csr1, dis1, nullptr, ctl, C16, N_NODES, 0, 0);
  gemm_in_kernel<<<GB1, 256, 0, stream>>>(C16, W1, b1, pw, B16, ctl, score, keys);

  // top-K select (6 x 8-bit radix, separate launches; early-exit skips tie-break passes)
  for (int p = 0; p < 6; ++p)
    histpick_kernel<<<NB1, 256, 0, stream>>>(keys, ctl, 40 - 8 * p, NB1);
  mark_kernel<<<NB1, 256, 0, stream>>>(keys, ctl, new_idx, kept);

  // CSR graph 2 in one kernel (row bases via wave-aggregated atomic; order-free)
  csr2_build_kernel<<<CB2, 256, 0, stream>>>(kept, rowstart1, csr1, new_idx, ctl,
                                             rowstart2, len2, dis2, csr2);

  // conv2: gemm-first (fused hp: relu*score on kept rows): A = hp @ W2 ; h2 = gather(A) + b2
  gemm_128_64_kernel<<<K_KEEP / 64, 256, 0, stream>>>(B16, W2, A16, ctl, K_KEEP, 0, kept, score);
  agg_gather64_kernel<<<ABK, 256, 0, stream>>>(A16, A16, rowstart2, len2, csr2, dis2, b2, ctl, C16, K_KEEP, 0, 1);

  // conv3: gather-first: G = gather(relu(h2)) ; h3 = G @ W3 + b3
  agg_gather64_kernel<<<ABK, 256, 0, stream>>>(C16, C16, rowstart2, len2, csr2, dis2, b3, ctl, A16, K_KEEP, 1, 0);
  gemm_64_128_kernel<<<K_KEEP / 64, 256, 0, stream>>>(A16, W3, b3, B16, ctl, K_KEEP);

  // conv4: gemm-first: A = relu(h3) @ W4 ; partials = gather(A) ; separate tiny reduce
  gemm_128_64_kernel<<<K_KEEP / 64, 256, 0, stream>>>(B16, W4, A16, ctl, K_KEEP, 1, nullptr, nullptr);
  agg_gather64_final_kernel<<<NBF, 256, 0, stream>>>(A16, rowstart2, len2, csr2, dis2,
                                                     partial, K_KEEP, NBF);
  reduce_out_kernel<<<64, 256, 0, stream>>>(partial, b4, ctl, d_out, NBF);
}

// Round 8
// 326.957 us; speedup vs baseline: 1.9182x; 1.0150x over previous
//
#include <hip/hip_runtime.h>
#include <hip/hip_bf16.h>
#include <stdint.h>

#define N_NODES 50000
#define N_EDGES 800000
#define K_KEEP  40000
#define BKT     196        // ceil(N_NODES/256) dst-range buckets
#define BCAP    6144       // per-bucket capacity (mean 4081, +32 sigma)

typedef unsigned long long u64;
typedef unsigned int u32;
typedef unsigned short u16;
typedef __hip_bfloat16 bf16;
typedef __hip_bfloat162 bf16x2;
typedef __attribute__((ext_vector_type(8))) short short8;
typedef __attribute__((ext_vector_type(8))) unsigned short ushort8;
typedef __attribute__((ext_vector_type(4))) float f32x4;

struct Ctl {
  u64 prefix;
  u32 kremain;
  u32 cnt;
  float inv_norm;
  u32 isfp32;
  u32 done;         // radix pass arrival counter (reset by picker each pass)
  u32 pad;          // csr2 edge cursor
  u32 gen;          // TopK resolved-early flag
  u32 done2;        // (unused; layout keep)
  u32 hist[256];    // radix histogram (LDS-aggregated flushes only)
};

__device__ __forceinline__ float bf2f(bf16 v) { return __bfloat162float(v); }
__device__ __forceinline__ float bfbits2f(unsigned short u) {
  return __uint_as_float(((u32)u) << 16);
}
__device__ __forceinline__ float loadF(const void* p, size_t i, bool f32) {
  return f32 ? ((const float*)p)[i] : bf2f(((const bf16*)p)[i]);
}
__device__ __forceinline__ short f2bf_bits(float f) {
  bf16 t = __float2bfloat16(f);
  return *(const short*)&t;
}

// gather one (row,lane8) unit: 8 channels of node d from H into acc[8]
// (exact R7 agg_gather64 arithmetic; RELU applied to source values if relusrc)
__device__ __forceinline__ void gather_row8(const ushort8* __restrict__ H, int d, int lane,
                                            const int* __restrict__ rowstart,
                                            const int* __restrict__ len,
                                            const int* __restrict__ csr,
                                            const float* __restrict__ dis,
                                            int relusrc, float* acc)
{
  float dd = dis[d];
  float sw = dd * dd;
  ushort8 v = H[(size_t)d * 8 + lane];
  #pragma unroll
  for (int c = 0; c < 8; ++c) {
    float t = bfbits2f(v[c]);
    if (relusrc) t = fmaxf(t, 0.f);
    acc[c] = t * sw;
  }
  int i = rowstart[d];
  int i1 = len ? (i + len[d]) : rowstart[d + 1];
  for (; i + 4 <= i1; i += 4) {
    int s0 = csr[i], s1 = csr[i + 1], s2 = csr[i + 2], s3 = csr[i + 3];
    float w0 = dd * dis[s0], w1 = dd * dis[s1], w2 = dd * dis[s2], w3 = dd * dis[s3];
    ushort8 v0 = H[(size_t)s0 * 8 + lane];
    ushort8 v1 = H[(size_t)s1 * 8 + lane];
    ushort8 v2 = H[(size_t)s2 * 8 + lane];
    ushort8 v3 = H[(size_t)s3 * 8 + lane];
    #pragma unroll
    for (int c = 0; c < 8; ++c) {
      float x0 = bfbits2f(v0[c]), x1 = bfbits2f(v1[c]);
      float x2 = bfbits2f(v2[c]), x3 = bfbits2f(v3[c]);
      if (relusrc) {
        x0 = fmaxf(x0, 0.f); x1 = fmaxf(x1, 0.f);
        x2 = fmaxf(x2, 0.f); x3 = fmaxf(x3, 0.f);
      }
      acc[c] += w0 * x0 + w1 * x1 + w2 * x2 + w3 * x3;
    }
  }
  for (; i < i1; ++i) {
    int s = csr[i];
    float w = dd * dis[s];
    ushort8 vv = H[(size_t)s * 8 + lane];
    #pragma unroll
    for (int c = 0; c < 8; ++c) {
      float xx = bfbits2f(vv[c]);
      if (relusrc) xx = fmaxf(xx, 0.f);
      acc[c] += w * xx;
    }
  }
}

// ---------------- init (+parallel dtype detect, proven R5-R8) ----------------

__global__ void init_kernel(const unsigned short* __restrict__ x16,
                            int* __restrict__ bucket_cur, int* __restrict__ detcnt, Ctl* ctl) {
  __shared__ u32 dsh[256];
  int i = blockIdx.x * 256 + threadIdx.x;
  if (i < BKT) bucket_cur[i] = i * BCAP;
  if (blockIdx.x == 0) {
    ctl->hist[threadIdx.x] = 0u;
    if (threadIdx.x == 0) {
      ctl->prefix = 0ull; ctl->kremain = K_KEEP; ctl->cnt = 0u;
      ctl->done = 0u; ctl->pad = 0u; ctl->gen = 0u; ctl->done2 = 0u;
    }
  }
  if (blockIdx.x < 64) {
    int base = blockIdx.x * 2048;
    u32 c = 0;
    for (int j = threadIdx.x; j < 2048; j += 256) {
      u32 h = x16[base + j];
      if ((h & 0x7F80u) == 0x7F80u) c++;
    }
    dsh[threadIdx.x] = c;
    __syncthreads();
    for (int s = 128; s > 0; s >>= 1) {
      if (threadIdx.x < s) dsh[threadIdx.x] += dsh[threadIdx.x + s];
      __syncthreads();
    }
    if (threadIdx.x == 0) detcnt[blockIdx.x] = (int)dsh[0];
  }
}

// ------- CSR1 bucket scatter (proven R8) + fused dtype/norm + fp32->bf16 convert -------

__global__ void bucket_scatter_kernel(const int* __restrict__ src, const int* __restrict__ dst,
                                      int* __restrict__ bucket_cur, u32* __restrict__ bucketbuf,
                                      const void* __restrict__ x, u32* __restrict__ xbf,
                                      const int* __restrict__ detcnt, const void* __restrict__ pw,
                                      Ctl* ctl)
{
  __shared__ u32 hist[BKT];
  __shared__ u32 base[BKT];
  __shared__ int f32sh;
  __shared__ float ns[128];
  const int tid = threadIdx.x;
  const int e0 = blockIdx.x * 2048;

  // dtype detect from detcnt (written by init, prior dispatch)
  if (tid < 64) {
    int dc = detcnt[tid];
    for (int off = 32; off; off >>= 1) dc += __shfl_down(dc, off);
    if (tid == 0) f32sh = (dc >= 16) ? 1 : 0;
  }
  for (int t = tid; t < BKT; t += 256) hist[t] = 0;
  __syncthreads();
  const bool f32in = f32sh != 0;

  #pragma unroll
  for (int j = 0; j < 8; ++j) {
    int e = e0 + j * 256 + tid;
    if (e < N_EDGES) atomicAdd(&hist[dst[e] >> 8], 1u);
  }
  __syncthreads();
  for (int t = tid; t < BKT; t += 256) {
    u32 c = hist[t];
    base[t] = c ? (u32)atomicAdd(&bucket_cur[t], (int)c) : 0u;
    hist[t] = 0;
  }
  __syncthreads();
  #pragma unroll
  for (int j = 0; j < 8; ++j) {
    int e = e0 + j * 256 + tid;
    if (e < N_EDGES) {
      int d = dst[e];
      int b = d >> 8;
      u32 pos = base[b] + atomicAdd(&hist[b], 1u);
      bucketbuf[pos] = ((u32)src[e] << 8) | (u32)(d & 255);
    }
  }
  // fused x -> bf16 (pair) conversion; only when input is fp32
  if (f32in) {
    const int p0 = blockIdx.x * 4096;
    const float2* xf = (const float2*)x;
    for (int j = tid; j < 4096; j += 256) {
      int p = p0 + j;
      if (p < N_NODES * 32) {
        float2 v = xf[p];
        u32 w = ((u32)(u16)f2bf_bits(v.y) << 16) | (u32)(u16)f2bf_bits(v.x);
        xbf[p] = w;
      }
    }
  }
  // fused norm: block 0 computes inv_norm + publishes isfp32
  if (blockIdx.x == 0) {
    if (tid < 128) { float v = loadF(pw, tid, f32in); ns[tid] = v * v; }
    __syncthreads();
    for (int s = 64; s > 0; s >>= 1) {
      if (tid < s) ns[tid] += ns[tid + s];
      __syncthreads();
    }
    if (tid == 0) {
      ctl->inv_norm = 1.0f / sqrtf(ns[0]);
      ctl->isfp32 = f32in ? 1u : 0u;
    }
  }
}

// ------- CSR1 from buckets (inline bucket scan; no separate scan kernel) -------

__global__ void csr_from_buckets_kernel(const u32* __restrict__ bucketbuf, const int* __restrict__ bucket_cur,
                                        int* __restrict__ rowstart, float* __restrict__ dis,
                                        int* __restrict__ csr)
{
  __shared__ u32 cnt[256];
  __shared__ u32 loc[256];
  __shared__ u32 cur[256];
  const int b = blockIdx.x;
  const int tid = threadIdx.x;

  // inline scan of all bucket sizes -> off0 for this bucket
  int v = (tid < BKT) ? (bucket_cur[tid] - tid * BCAP) : 0;
  loc[tid] = (u32)v;
  __syncthreads();
  for (int off = 1; off < 256; off <<= 1) {
    u32 t = (tid >= off) ? loc[tid - off] : 0;
    __syncthreads();
    loc[tid] += t;
    __syncthreads();
  }
  const int bc = bucket_cur[b] - b * BCAP;
  const int off0 = (int)loc[b] - bc;
  if (b == BKT - 1 && tid == 0) rowstart[N_NODES] = (int)loc[BKT - 1];
  __syncthreads();

  const u32* buf = bucketbuf + (size_t)b * BCAP;
  cnt[tid] = 0;
  __syncthreads();
  for (int i = tid; i < bc; i += 256) atomicAdd(&cnt[buf[i] & 255u], 1u);
  __syncthreads();
  u32 c = cnt[tid];
  loc[tid] = c;
  __syncthreads();
  for (int off = 1; off < 256; off <<= 1) {
    u32 t = (tid >= off) ? loc[tid - off] : 0;
    __syncthreads();
    loc[tid] += t;
    __syncthreads();
  }
  int node = b * 256 + tid;
  u32 excl = loc[tid] - c;
  if (node < N_NODES) {
    rowstart[node] = off0 + (int)excl;
    dis[node] = rsqrtf(1.0f + (float)c);
  }
  cur[tid] = off0 + excl;
  __syncthreads();
  for (int i = tid; i < bc; i += 256) {
    u32 p = buf[i];
    u32 pos = atomicAdd(&cur[p & 255u], 1u);
    csr[pos] = (int)(p >> 8);
  }
}

// ------- unified gather: 8 lanes/node, 16B ushort8 loads; ILP-4 (standalone, conv2) -------

__global__ void agg_gather64_kernel(const bf16* __restrict__ hW, const bf16* __restrict__ hWalt,
                                    const int* __restrict__ rowstart,
                                    const int* __restrict__ len, const int* __restrict__ csr,
                                    const float* __restrict__ dis,
                                    const void* __restrict__ b, const Ctl* __restrict__ ctl,
                                    bf16* __restrict__ agg, int M, int relusrc, int addbias)
{
  const bool f32 = ctl->isfp32 != 0;
  int gid = blockIdx.x * 256 + threadIdx.x;
  int d = gid >> 3;
  int lane = gid & 7;                       // 8 lanes/node, 8 channels each
  if (d >= M) return;
  const ushort8* H = (const ushort8*)(f32 ? hWalt : hW);   // row = 8 x ushort8
  float acc[8];
  gather_row8(H, d, lane, rowstart, len, csr, dis, relusrc, acc);
  if (addbias) {
    #pragma unroll
    for (int c = 0; c < 8; ++c) acc[c] += loadF(b, 8 * lane + c, f32);
  }
  ushort8 outv;
  #pragma unroll
  for (int c = 0; c < 8; ++c) outv[c] = (unsigned short)f2bf_bits(acc[c]);
  ((ushort8*)agg)[(size_t)d * 8 + lane] = outv;
}

// ---------------- MFMA GEMMs (16x16x32 bf16, fp32 acc) ----------------

// conv1 FUSED: gather(x over graph1) -> LDS, then Y[N,128] = G @ W1 + b1 (+score/keys)
__global__ void gemm_in_kernel(const bf16* __restrict__ x, const bf16* __restrict__ xbf,
                               const int* __restrict__ rowstart, const int* __restrict__ csr,
                               const float* __restrict__ dis,
                               const void* __restrict__ W, const void* __restrict__ b,
                               const void* __restrict__ pw,
                               bf16* __restrict__ Y, const Ctl* __restrict__ ctl,
                               float* __restrict__ score, u64* __restrict__ keys)
{
  __shared__ short Xs[64 * 72];
  __shared__ short Wt[128 * 72];
  __shared__ float bs[128];
  __shared__ float ps[128];
  const bool f32 = ctl->isfp32 != 0;
  const int tid = threadIdx.x;
  const int row0 = blockIdx.x * 64;

  for (int i = tid; i < 64 * 128; i += 256) {
    int k = i >> 7, n = i & 127;
    Wt[n * 72 + k] = f32 ? f2bf_bits(((const float*)W)[i]) : ((const short*)W)[i];
  }
  // fused gather: 64 rows x 8 lane-units, 2 units/thread, straight into Xs
  {
    const ushort8* H = (const ushort8*)(f32 ? xbf : x);
    for (int u = tid; u < 512; u += 256) {
      int r = u >> 3, lane = u & 7;
      int d = row0 + r;
      float acc[8];
      if (d < N_NODES) {
        gather_row8(H, d, lane, rowstart, nullptr, csr, dis, 0, acc);
      } else {
        #pragma unroll
        for (int c = 0; c < 8; ++c) acc[c] = 0.f;
      }
      short8 outv;
      #pragma unroll
      for (int c = 0; c < 8; ++c) outv[c] = f2bf_bits(acc[c]);
      *(short8*)&Xs[r * 72 + lane * 8] = outv;
    }
  }
  for (int i = tid; i < 128; i += 256) { bs[i] = loadF(b, i, f32); ps[i] = loadF(pw, i, f32); }
  __syncthreads();

  const int lane = tid & 63;
  const int w = tid >> 6;
  const int l16 = lane & 15;
  const int quad = lane >> 4;
  f32x4 acc[8];
  #pragma unroll
  for (int ct = 0; ct < 8; ++ct) acc[ct] = (f32x4){0.f, 0.f, 0.f, 0.f};
  const int arow = w * 16 + l16;
  #pragma unroll
  for (int kc = 0; kc < 2; ++kc) {
    short8 a = *(short8*)&Xs[arow * 72 + kc * 32 + quad * 8];
    #pragma unroll
    for (int ct = 0; ct < 8; ++ct) {
      short8 bb = *(short8*)&Wt[(ct * 16 + l16) * 72 + kc * 32 + quad * 8];
      acc[ct] = __builtin_amdgcn_mfma_f32_16x16x32_bf16(a, bb, acc[ct], 0, 0, 0);
    }
  }
  float inv_norm = ctl->inv_norm;
  #pragma unroll
  for (int r = 0; r < 4; ++r) {
    int gr = row0 + w * 16 + quad * 4 + r;
    float p = 0.f;
    #pragma unroll
    for (int ct = 0; ct < 8; ++ct) {
      int col = ct * 16 + l16;
      float h = acc[ct][r] + bs[col];
      if (gr < N_NODES) Y[(size_t)gr * 128 + col] = __float2bfloat16(h);
      p += fmaxf(h, 0.f) * ps[col];
    }
    p += __shfl_down(p, 8, 16);
    p += __shfl_down(p, 4, 16);
    p += __shfl_down(p, 2, 16);
    p += __shfl_down(p, 1, 16);
    if (l16 == 0 && gr < N_NODES) {
      float sc = tanhf(p * inv_norm);
      score[gr] = sc;
      u32 u = __float_as_uint(sc);
      u = (u & 0x80000000u) ? ~u : (u | 0x80000000u);
      keys[gr] = (((u64)u) << 16) | (u64)(0xFFFFu - (u32)gr);
    }
  }
}

// Y[M,64] = (relu?)X[M,128] @ W[128,64]; M multiple of 64
// kept!=null: X row = kept[row], apply relu*score[kept[row]] (fused TopK hp)
__global__ void gemm_128_64_kernel(const bf16* __restrict__ X, const void* __restrict__ W,
                                   bf16* __restrict__ Y, const Ctl* __restrict__ ctl,
                                   int M, int relu_x,
                                   const int* __restrict__ kept, const float* __restrict__ score)
{
  __shared__ short Xs[64 * 136];
  __shared__ short Wt[64 * 136];
  __shared__ int keptS[64];
  __shared__ float scS[64];
  const bool f32 = ctl->isfp32 != 0;
  const int tid = threadIdx.x;
  const int row0 = blockIdx.x * 64;

  if (kept) {
    for (int i = tid; i < 64; i += 256) {
      int o = kept[row0 + i];
      keptS[i] = o;
      scS[i] = score[o];
    }
  }
  __syncthreads();

  for (int i = tid; i < 128 * 64; i += 256) {
    int k = i >> 6, n = i & 63;
    Wt[n * 136 + k] = f32 ? f2bf_bits(((const float*)W)[i]) : ((const short*)W)[i];
  }
  const u32* X2 = (const u32*)X;
  for (int p = tid; p < 64 * 64; p += 256) {
    int r = p >> 6, kp = p & 63;
    int srow = kept ? keptS[r] : (row0 + r);
    u32 v = X2[(size_t)srow * 64 + kp];
    if (relu_x) {
      if (v & 0x8000u) v &= 0xFFFF0000u;
      if (v & 0x80000000u) v &= 0x0000FFFFu;
    }
    if (kept) {
      bf16x2 h = *(bf16x2*)&v;
      float s = scS[r];
      bf16x2 o;
      o.x = __float2bfloat16(fmaxf(bf2f(h.x), 0.f) * s);
      o.y = __float2bfloat16(fmaxf(bf2f(h.y), 0.f) * s);
      v = *(u32*)&o;
    }
    *(u32*)&Xs[r * 136 + 2 * kp] = v;
  }
  __syncthreads();

  const int lane = tid & 63;
  const int w = tid >> 6;
  const int l16 = lane & 15;
  const int quad = lane >> 4;
  f32x4 acc[4];
  #pragma unroll
  for (int ct = 0; ct < 4; ++ct) acc[ct] = (f32x4){0.f, 0.f, 0.f, 0.f};
  const int arow = w * 16 + l16;
  #pragma unroll
  for (int kc = 0; kc < 4; ++kc) {
    short8 a = *(short8*)&Xs[arow * 136 + kc * 32 + quad * 8];
    #pragma unroll
    for (int ct = 0; ct < 4; ++ct) {
      short8 bb = *(short8*)&Wt[(ct * 16 + l16) * 136 + kc * 32 + quad * 8];
      acc[ct] = __builtin_amdgcn_mfma_f32_16x16x32_bf16(a, bb, acc[ct], 0, 0, 0);
    }
  }
  #pragma unroll
  for (int ct = 0; ct < 4; ++ct)
    #pragma unroll
    for (int r = 0; r < 4; ++r) {
      int gr = row0 + w * 16 + quad * 4 + r;
      Y[(size_t)gr * 64 + ct * 16 + l16] = __float2bfloat16(acc[ct][r]);
    }
}

// conv3 FUSED: gather(relu(h2) over graph2) -> LDS, then Y[M,128] = G @ W3 + b3
__global__ void gemm_64_128_kernel(const bf16* __restrict__ X,
                                   const int* __restrict__ rowstart, const int* __restrict__ len,
                                   const int* __restrict__ csr, const float* __restrict__ dis,
                                   const void* __restrict__ W, const void* __restrict__ b,
                                   bf16* __restrict__ Y, const Ctl* __restrict__ ctl, int M)
{
  __shared__ short Xs[64 * 72];
  __shared__ short Wt[128 * 72];
  __shared__ float bs[128];
  const bool f32 = ctl->isfp32 != 0;
  const int tid = threadIdx.x;
  const int row0 = blockIdx.x * 64;

  for (int i = tid; i < 64 * 128; i += 256) {
    int k = i >> 7, n = i & 127;
    Wt[n * 72 + k] = f32 ? f2bf_bits(((const float*)W)[i]) : ((const short*)W)[i];
  }
  // fused gather with relu on source (h2), graph2 (len-based rows)
  {
    const ushort8* H = (const ushort8*)X;
    for (int u = tid; u < 512; u += 256) {
      int r = u >> 3, lane = u & 7;
      int d = row0 + r;           // M multiple of 64 -> always < M
      float acc[8];
      gather_row8(H, d, lane, rowstart, len, csr, dis, 1, acc);
      short8 outv;
      #pragma unroll
      for (int c = 0; c < 8; ++c) outv[c] = f2bf_bits(acc[c]);
      *(short8*)&Xs[r * 72 + lane * 8] = outv;
    }
  }
  for (int i = tid; i < 128; i += 256) bs[i] = loadF(b, i, f32);
  __syncthreads();

  const int lane = tid & 63;
  const int w = tid >> 6;
  const int l16 = lane & 15;
  const int quad = lane >> 4;
  f32x4 acc[8];
  #pragma unroll
  for (int ct = 0; ct < 8; ++ct) acc[ct] = (f32x4){0.f, 0.f, 0.f, 0.f};
  const int arow = w * 16 + l16;
  #pragma unroll
  for (int kc = 0; kc < 2; ++kc) {
    short8 a = *(short8*)&Xs[arow * 72 + kc * 32 + quad * 8];
    #pragma unroll
    for (int ct = 0; ct < 8; ++ct) {
      short8 bb = *(short8*)&Wt[(ct * 16 + l16) * 72 + kc * 32 + quad * 8];
      acc[ct] = __builtin_amdgcn_mfma_f32_16x16x32_bf16(a, bb, acc[ct], 0, 0, 0);
    }
  }
  #pragma unroll
  for (int ct = 0; ct < 8; ++ct)
    #pragma unroll
    for (int r = 0; r < 4; ++r) {
      int gr = row0 + w * 16 + quad * 4 + r;
      int col = ct * 16 + l16;
      Y[(size_t)gr * 128 + col] = __float2bfloat16(acc[ct][r] + bs[col]);
    }
}

// conv4: gather (8 lanes/node, 16B loads) + register acc + per-block partial
__global__ void agg_gather64_final_kernel(const bf16* __restrict__ hW, const int* __restrict__ rowstart,
                                          const int* __restrict__ len, const int* __restrict__ csr,
                                          const float* __restrict__ dis,
                                          float* __restrict__ partial, int M, int nblk)
{
  __shared__ float cs[64];
  const int tid = threadIdx.x;
  if (tid < 64) cs[tid] = 0.f;
  __syncthreads();
  const int lane = tid & 7;
  const ushort8* H = (const ushort8*)hW;
  float acc[8];
  #pragma unroll
  for (int c = 0; c < 8; ++c) acc[c] = 0.f;
  for (int d = (blockIdx.x * 256 + tid) >> 3; d < M; d += nblk * 32) {
    float dd = dis[d];
    float sw = dd * dd;
    ushort8 v = H[(size_t)d * 8 + lane];
    #pragma unroll
    for (int c = 0; c < 8; ++c) acc[c] += bfbits2f(v[c]) * sw;
    int i = rowstart[d];
    int i1 = i + len[d];
    for (; i + 4 <= i1; i += 4) {
      int s0 = csr[i], s1 = csr[i + 1], s2 = csr[i + 2], s3 = csr[i + 3];
      float w0 = dd * dis[s0], w1 = dd * dis[s1], w2 = dd * dis[s2], w3 = dd * dis[s3];
      ushort8 v0 = H[(size_t)s0 * 8 + lane];
      ushort8 v1 = H[(size_t)s1 * 8 + lane];
      ushort8 v2 = H[(size_t)s2 * 8 + lane];
      ushort8 v3 = H[(size_t)s3 * 8 + lane];
      #pragma unroll
      for (int c = 0; c < 8; ++c) {
        acc[c] += w0 * bfbits2f(v0[c]) + w1 * bfbits2f(v1[c])
                + w2 * bfbits2f(v2[c]) + w3 * bfbits2f(v3[c]);
      }
    }
    for (; i < i1; ++i) {
      int s = csr[i];
      float w = dd * dis[s];
      ushort8 vv = H[(size_t)s * 8 + lane];
      #pragma unroll
      for (int c = 0; c < 8; ++c) acc[c] += w * bfbits2f(vv[c]);
    }
  }
  #pragma unroll
  for (int c = 0; c < 8; ++c) atomicAdd(&cs[8 * lane + c], acc[c]);
  __syncthreads();
  if (tid < 64) partial[(size_t)tid * nblk + blockIdx.x] = cs[tid];
}

__global__ void reduce_out_kernel(const float* __restrict__ partial, const void* __restrict__ b,
                                  const Ctl* __restrict__ ctl, void* __restrict__ out, int nblk)
{
  __shared__ float sh[256];
  int c = blockIdx.x;
  float s = 0.f;
  for (int j = threadIdx.x; j < nblk; j += 256) s += partial[(size_t)c * nblk + j];
  sh[threadIdx.x] = s;
  __syncthreads();
  for (int st = 128; st > 0; st >>= 1) {
    if (threadIdx.x < st) sh[threadIdx.x] += sh[threadIdx.x + st];
    __syncthreads();
  }
  if (threadIdx.x == 0) {
    const bool f32 = ctl->isfp32 != 0;
    float val = sh[0] / (float)K_KEEP + loadF(b, c, f32);
    if (f32) ((float*)out)[c] = val;
    else     ((bf16*)out)[c] = __float2bfloat16(val);
  }
}

// ------- TopK select: separate-launch hist+pick (proven R0/R2), parallel pick + early-exit -------

__global__ void histpick_kernel(const u64* __restrict__ keys, Ctl* ctl, int shift, int nblocks) {
  __shared__ u32 lh[256];
  __shared__ u32 sfx[256];
  __shared__ int lastflag;
  __shared__ int selsh;
  const int tid = threadIdx.x;
  if (ctl->gen != 0u) return;          // threshold already resolved by earlier pass
  lh[tid] = 0;
  __syncthreads();
  u64 prefix = ctl->prefix;
  int i = blockIdx.x * 256 + tid;
  if (i < N_NODES) {
    u64 key = keys[i];
    if ((key >> (shift + 8)) == (prefix >> (shift + 8)))
      atomicAdd(&lh[(u32)((key >> shift) & 0xFF)], 1u);
  }
  __syncthreads();
  u32 c = lh[tid];
  if (c) atomicAdd(&ctl->hist[tid], c);
  __syncthreads();
  if (tid == 0) {
    __threadfence();
    u32 old = atomicAdd(&ctl->done, 1u);
    lastflag = (old == (u32)(nblocks - 1));
  }
  __syncthreads();
  if (!lastflag) return;
  // last block: parallel pick via suffix scan
  u32 cc = atomicExch(&ctl->hist[tid], 0u);   // coherent read + zero for next pass
  sfx[tid] = cc;
  __syncthreads();
  for (int off = 1; off < 256; off <<= 1) {
    u32 t = (tid + off < 256) ? sfx[tid + off] : 0u;
    __syncthreads();
    sfx[tid] += t;
    __syncthreads();
  }
  u32 kr = ctl->kremain;
  u32 above = (tid < 255) ? sfx[tid + 1] : 0u;
  if (sfx[tid] >= kr && above < kr) selsh = tid;   // unique (sfx non-increasing)
  __syncthreads();
  if (tid == 0) {
    int sel = selsh;
    u32 ab = (sel < 255) ? sfx[sel + 1] : 0u;
    u32 newkr = kr - ab;
    u32 bucketcnt = sfx[sel] - ab;
    ctl->kremain = newkr;
    ctl->prefix = prefix | (((u64)(u32)sel) << shift);
    if (newkr == bucketcnt) ctl->gen = 1u;  // whole boundary bucket kept -> resolved
    ctl->done = 0u;
  }
}

__global__ void mark_kernel(const u64* __restrict__ keys, Ctl* ctl,
                            int* __restrict__ new_idx, int* __restrict__ kept)
{
  int i = blockIdx.x * 256 + threadIdx.x;
  if (i >= N_NODES) return;
  if (keys[i] >= ctl->prefix) {
    int pos = (int)atomicAdd(&ctl->cnt, 1u);
    new_idx[i] = pos;
    kept[pos] = i;
  } else {
    new_idx[i] = -1;
  }
}

// ------- CSR2 in ONE kernel: count + wave-aggregated alloc + fill (order-free rows) -------

__global__ void csr2_build_kernel(const int* __restrict__ kept, const int* __restrict__ rowstart1,
                                  const int* __restrict__ csr1, const int* __restrict__ new_idx,
                                  Ctl* ctl, int* __restrict__ rowstart2, int* __restrict__ len2,
                                  float* __restrict__ dis2, int* __restrict__ csr2)
{
  int kp = blockIdx.x * 256 + threadIdx.x;
  int lane = threadIdx.x & 63;
  int c = 0;
  int i0 = 0, i1 = 0;
  if (kp < K_KEEP) {
    int o = kept[kp];
    i0 = rowstart1[o]; i1 = rowstart1[o + 1];
    int i = i0;
    for (; i + 4 <= i1; i += 4) {
      int s0 = csr1[i], s1 = csr1[i + 1], s2 = csr1[i + 2], s3 = csr1[i + 3];
      c += (new_idx[s0] >= 0) + (new_idx[s1] >= 0) + (new_idx[s2] >= 0) + (new_idx[s3] >= 0);
    }
    for (; i < i1; ++i) c += (new_idx[csr1[i]] >= 0);
  }
  // wave inclusive scan of c
  int pre = c;
  #pragma unroll
  for (int off = 1; off < 64; off <<= 1) {
    int t = __shfl_up(pre, off);
    if (lane >= off) pre += t;
  }
  int wtot = __shfl(pre, 63);
  int wbase = 0;
  if (lane == 0) wbase = (int)atomicAdd(&ctl->pad, (u32)wtot);
  wbase = __shfl(wbase, 0);
  int base = wbase + pre - c;
  if (kp < K_KEEP) {
    rowstart2[kp] = base;
    len2[kp] = c;
    dis2[kp] = rsqrtf(1.0f + (float)c);
    int w = base;
    for (int i = i0; i < i1; ++i) {
      int ns = new_idx[csr1[i]];
      if (ns >= 0) csr2[w++] = ns;
    }
  }
}

// ---------------- launch ----------------

extern "C" void kernel_launch(void* const* d_in, const int* in_sizes, int n_in,
                              void* d_out, int out_size, void* d_ws, size_t ws_size,
                              hipStream_t stream)
{
  const void* x  = d_in[0];
  const int*  ei = (const int*)d_in[1];
  const void* W1 = d_in[3];
  const void* b1 = d_in[4];
  const void* pw = d_in[5];
  const void* W2 = d_in[6];
  const void* b2 = d_in[7];
  const void* W3 = d_in[8];
  const void* b3 = d_in[9];
  const void* W4 = d_in[10];
  const void* b4 = d_in[11];

  const int* src = ei;
  const int* dst = ei + N_EDGES;

  float* F = (float*)d_ws;
  bf16*  A16       = (bf16*)F;               // N x 128 bf16
  bf16*  B16       = (bf16*)(F + 3200000);   // N x 128 bf16
  bf16*  C16       = (bf16*)(F + 6400000);   // K x 128 bf16
  u32*   xbf       = (u32*)(F + 9000000);    // N x 32 u32 (x as bf16 pairs, only if fp32 input)
  float* dis1      = F + 10600000;           // 50000
  float* dis2      = F + 10650000;           // 40000
  float* score     = F + 10690000;           // 50000
  u64*   keys      = (u64*)(F + 10740000);   // 50000 u64
  int*   new_idx   = (int*)(F + 10840000);   // 50000
  int*   kept      = (int*)(F + 10890000);   // 40000
  int*   len2      = (int*)(F + 10930000);   // 40000
  int*   rowstart1 = (int*)(F + 10970000);   // 50001
  int*   rowstart2 = (int*)(F + 11020004);   // 40000
  int*   csr1      = (int*)(F + 11060008);   // 800000
  int*   csr2      = (int*)(F + 11860008);   // 800000
  Ctl*   ctl       = (Ctl*)(F + 12660008);   // ~1.1 KB
  int*   detcnt    = (int*)(F + 12660856);   // 64
  int*   bucket_cur= (int*)(F + 12660920);   // 196
  u32*   bucketbuf = (u32*)(F + 12726908);   // 196*6144
  float* partial   = F + 13931132;           // 64 x 1024

  const int NB1 = (N_NODES + 255) / 256;     // 196
  const int EB2 = (N_EDGES + 2047) / 2048;   // 391
  const int GB1 = (N_NODES + 63) / 64;       // 782
  const int ABK = K_KEEP * 8 / 256;          // 1250
  const int CB2 = (K_KEEP + 255) / 256;      // 157
  const int NBF = 1024;                      // final-gather blocks

  init_kernel<<<NB1, 256, 0, stream>>>((const unsigned short*)x, bucket_cur, detcnt, ctl);

  // CSR graph 1 via bucket sort (+fused dtype/norm, +x->bf16 conversion iff fp32 input)
  bucket_scatter_kernel<<<EB2, 256, 0, stream>>>(src, dst, bucket_cur, bucketbuf, x, xbf,
                                                 detcnt, pw, ctl);
  csr_from_buckets_kernel<<<BKT, 256, 0, stream>>>(bucketbuf, bucket_cur, rowstart1, dis1, csr1);

  // conv1 FUSED: gather(x) -> LDS -> h1 = G @ W1 + b1 (+fused score/keys)
  gemm_in_kernel<<<GB1, 256, 0, stream>>>((const bf16*)x, (const bf16*)xbf, rowstart1, csr1, dis1,
                                          W1, b1, pw, B16, ctl, score, keys);

  // top-K select (6 x 8-bit radix, separate launches; early-exit skips tie-break passes)
  for (int p = 0; p < 6; ++p)
    histpick_kernel<<<NB1, 256, 0, stream>>>(keys, ctl, 40 - 8 * p, NB1);
  mark_kernel<<<NB1, 256, 0, stream>>>(keys, ctl, new_idx, kept);

  // CSR graph 2 in one kernel (row bases via wave-aggregated atomic; order-free)
  csr2_build_kernel<<<CB2, 256, 0, stream>>>(kept, rowstart1, csr1, new_idx, ctl,
                                             rowstart2, len2, dis2, csr2);

  // conv2: gemm-first (fused hp: relu*score on kept rows): A = hp @ W2 ; h2 = gather(A) + b2
  gemm_128_64_kernel<<<K_KEEP / 64, 256, 0, stream>>>(B16, W2, A16, ctl, K_KEEP, 0, kept, score);
  agg_gather64_kernel<<<ABK, 256, 0, stream>>>(A16, A16, rowstart2, len2, csr2, dis2, b2, ctl, C16, K_KEEP, 0, 1);

  // conv3 FUSED: gather(relu(h2)) -> LDS -> h3 = G @ W3 + b3
  gemm_64_128_kernel<<<K_KEEP / 64, 256, 0, stream>>>(C16, rowstart2, len2, csr2, dis2,
                                                      W3, b3, B16, ctl, K_KEEP);

  // conv4: gemm-first: A = relu(h3) @ W4 ; partials = gather(A) ; separate tiny reduce
  gemm_128_64_kernel<<<K_KEEP / 64, 256, 0, stream>>>(B16, W4, A16, ctl, K_KEEP, 1, nullptr, nullptr);
  agg_gather64_final_kernel<<<NBF, 256, 0, stream>>>(A16, rowstart2, len2, csr2, dis2,
                                                     partial, K_KEEP, NBF);
  reduce_out_kernel<<<64, 256, 0, stream>>>(partial, b4, ctl, d_out, NBF);
}

// Round 10
// 319.368 us; speedup vs baseline: 1.9638x; 1.0238x over previous
//
#include <hip/hip_runtime.h>
#include <hip/hip_bf16.h>
#include <stdint.h>

#define N_NODES 50000
#define N_EDGES 800000
#define K_KEEP  40000
#define BKT     196        // ceil(N_NODES/256) dst-range buckets
#define BCAP    6144       // per-bucket capacity (mean 4081, +32 sigma)

typedef unsigned long long u64;
typedef unsigned int u32;
typedef unsigned short u16;
typedef __hip_bfloat16 bf16;
typedef __hip_bfloat162 bf16x2;
typedef __attribute__((ext_vector_type(8))) short short8;
typedef __attribute__((ext_vector_type(8))) unsigned short ushort8;
typedef __attribute__((ext_vector_type(4))) float f32x4;

struct Ctl {
  u64 prefix;
  u32 kremain;
  u32 cnt;
  float inv_norm;
  u32 isfp32;
  u32 done;         // radix pass arrival counter (reset by picker each pass)
  u32 pad;          // csr2 edge cursor
  u32 gen;          // TopK resolved-early flag
  u32 done2;        // (unused; layout keep)
  u32 hist[256];    // radix histogram (LDS-aggregated flushes only)
};

__device__ __forceinline__ float bf2f(bf16 v) { return __bfloat162float(v); }
__device__ __forceinline__ float bfbits2f(unsigned short u) {
  return __uint_as_float(((u32)u) << 16);
}
__device__ __forceinline__ float loadF(const void* p, size_t i, bool f32) {
  return f32 ? ((const float*)p)[i] : bf2f(((const bf16*)p)[i]);
}
__device__ __forceinline__ short f2bf_bits(float f) {
  bf16 t = __float2bfloat16(f);
  return *(const short*)&t;
}

// R9 prescaled gather: rows of H are P = dis[row]*h[row]; this sums P over
// {self} ∪ N(d). Caller multiplies by dis[d] once. No per-edge dis loads.
__device__ __forceinline__ void gather_row8_pre(const ushort8* __restrict__ H, int d, int lane,
                                                const int* __restrict__ rowstart,
                                                const int* __restrict__ len,
                                                const int* __restrict__ csr,
                                                float* acc)
{
  ushort8 v = H[(size_t)d * 8 + lane];
  #pragma unroll
  for (int c = 0; c < 8; ++c) acc[c] = bfbits2f(v[c]);
  int i = rowstart[d];
  int i1 = len ? (i + len[d]) : rowstart[d + 1];
  for (; i + 4 <= i1; i += 4) {
    int s0 = csr[i], s1 = csr[i + 1], s2 = csr[i + 2], s3 = csr[i + 3];
    ushort8 v0 = H[(size_t)s0 * 8 + lane];
    ushort8 v1 = H[(size_t)s1 * 8 + lane];
    ushort8 v2 = H[(size_t)s2 * 8 + lane];
    ushort8 v3 = H[(size_t)s3 * 8 + lane];
    #pragma unroll
    for (int c = 0; c < 8; ++c) {
      acc[c] += (bfbits2f(v0[c]) + bfbits2f(v1[c]))
              + (bfbits2f(v2[c]) + bfbits2f(v3[c]));
    }
  }
  for (; i < i1; ++i) {
    int s = csr[i];
    ushort8 vv = H[(size_t)s * 8 + lane];
    #pragma unroll
    for (int c = 0; c < 8; ++c) acc[c] += bfbits2f(vv[c]);
  }
}

// ---------------- init (+parallel dtype detect, proven R5-R8) ----------------

__global__ void init_kernel(const unsigned short* __restrict__ x16,
                            int* __restrict__ bucket_cur, int* __restrict__ detcnt, Ctl* ctl) {
  __shared__ u32 dsh[256];
  int i = blockIdx.x * 256 + threadIdx.x;
  if (i < BKT) bucket_cur[i] = i * BCAP;
  if (blockIdx.x == 0) {
    ctl->hist[threadIdx.x] = 0u;
    if (threadIdx.x == 0) {
      ctl->prefix = 0ull; ctl->kremain = K_KEEP; ctl->cnt = 0u;
      ctl->done = 0u; ctl->pad = 0u; ctl->gen = 0u; ctl->done2 = 0u;
    }
  }
  if (blockIdx.x < 64) {
    int base = blockIdx.x * 2048;
    u32 c = 0;
    for (int j = threadIdx.x; j < 2048; j += 256) {
      u32 h = x16[base + j];
      if ((h & 0x7F80u) == 0x7F80u) c++;
    }
    dsh[threadIdx.x] = c;
    __syncthreads();
    for (int s = 128; s > 0; s >>= 1) {
      if (threadIdx.x < s) dsh[threadIdx.x] += dsh[threadIdx.x + s];
      __syncthreads();
    }
    if (threadIdx.x == 0) detcnt[blockIdx.x] = (int)dsh[0];
  }
}

// ------- CSR1 bucket scatter (proven R8) + fused dtype/norm -------

__global__ void bucket_scatter_kernel(const int* __restrict__ src, const int* __restrict__ dst,
                                      int* __restrict__ bucket_cur, u32* __restrict__ bucketbuf,
                                      const int* __restrict__ detcnt, const void* __restrict__ pw,
                                      Ctl* ctl)
{
  __shared__ u32 hist[BKT];
  __shared__ u32 base[BKT];
  __shared__ int f32sh;
  __shared__ float ns[128];
  const int tid = threadIdx.x;
  const int e0 = blockIdx.x * 2048;

  // dtype detect from detcnt (written by init, prior dispatch)
  if (tid < 64) {
    int dc = detcnt[tid];
    for (int off = 32; off; off >>= 1) dc += __shfl_down(dc, off);
    if (tid == 0) f32sh = (dc >= 16) ? 1 : 0;
  }
  for (int t = tid; t < BKT; t += 256) hist[t] = 0;
  __syncthreads();
  const bool f32in = f32sh != 0;

  #pragma unroll
  for (int j = 0; j < 8; ++j) {
    int e = e0 + j * 256 + tid;
    if (e < N_EDGES) atomicAdd(&hist[dst[e] >> 8], 1u);
  }
  __syncthreads();
  for (int t = tid; t < BKT; t += 256) {
    u32 c = hist[t];
    base[t] = c ? (u32)atomicAdd(&bucket_cur[t], (int)c) : 0u;
    hist[t] = 0;
  }
  __syncthreads();
  #pragma unroll
  for (int j = 0; j < 8; ++j) {
    int e = e0 + j * 256 + tid;
    if (e < N_EDGES) {
      int d = dst[e];
      int b = d >> 8;
      u32 pos = base[b] + atomicAdd(&hist[b], 1u);
      bucketbuf[pos] = ((u32)src[e] << 8) | (u32)(d & 255);
    }
  }
  // fused norm: block 0 computes inv_norm + publishes isfp32
  if (blockIdx.x == 0) {
    if (tid < 128) { float v = loadF(pw, tid, f32in); ns[tid] = v * v; }
    __syncthreads();
    for (int s = 64; s > 0; s >>= 1) {
      if (tid < s) ns[tid] += ns[tid + s];
      __syncthreads();
    }
    if (tid == 0) {
      ctl->inv_norm = 1.0f / sqrtf(ns[0]);
      ctl->isfp32 = f32in ? 1u : 0u;
    }
  }
}

// ------- CSR1 from buckets (inline bucket scan) + fused x -> xbf = dis1*x (bf16) -------

__global__ void csr_from_buckets_kernel(const u32* __restrict__ bucketbuf, const int* __restrict__ bucket_cur,
                                        int* __restrict__ rowstart, float* __restrict__ dis,
                                        int* __restrict__ csr,
                                        const void* __restrict__ x, ushort8* __restrict__ xbf,
                                        const Ctl* __restrict__ ctl)
{
  __shared__ u32 cnt[256];
  __shared__ u32 loc[256];
  __shared__ u32 cur[256];
  __shared__ float disS[256];
  const int b = blockIdx.x;
  const int tid = threadIdx.x;

  // inline scan of all bucket sizes -> off0 for this bucket
  int v = (tid < BKT) ? (bucket_cur[tid] - tid * BCAP) : 0;
  loc[tid] = (u32)v;
  __syncthreads();
  for (int off = 1; off < 256; off <<= 1) {
    u32 t = (tid >= off) ? loc[tid - off] : 0;
    __syncthreads();
    loc[tid] += t;
    __syncthreads();
  }
  const int bc = bucket_cur[b] - b * BCAP;
  const int off0 = (int)loc[b] - bc;
  if (b == BKT - 1 && tid == 0) rowstart[N_NODES] = (int)loc[BKT - 1];
  __syncthreads();

  const u32* buf = bucketbuf + (size_t)b * BCAP;
  cnt[tid] = 0;
  __syncthreads();
  for (int i = tid; i < bc; i += 256) atomicAdd(&cnt[buf[i] & 255u], 1u);
  __syncthreads();
  u32 c = cnt[tid];
  loc[tid] = c;
  __syncthreads();
  for (int off = 1; off < 256; off <<= 1) {
    u32 t = (tid >= off) ? loc[tid - off] : 0;
    __syncthreads();
    loc[tid] += t;
    __syncthreads();
  }
  int node = b * 256 + tid;
  u32 excl = loc[tid] - c;
  float ddv = rsqrtf(1.0f + (float)c);
  disS[tid] = ddv;
  if (node < N_NODES) {
    rowstart[node] = off0 + (int)excl;
    dis[node] = ddv;
  }
  cur[tid] = off0 + excl;
  __syncthreads();
  for (int i = tid; i < bc; i += 256) {
    u32 p = buf[i];
    u32 pos = atomicAdd(&cur[p & 255u], 1u);
    csr[pos] = (int)(p >> 8);
  }
  // fused prescaled conversion: xbf[node] = bf16(dis1[node] * x[node]), 64 ch
  {
    const bool f32in = ctl->isfp32 != 0;
    if (f32in) {
      const float* xf = (const float*)x;
      for (int u = tid; u < 2048; u += 256) {
        int r = u >> 3, lane = u & 7;
        int d = b * 256 + r;
        if (d < N_NODES) {
          float sc = disS[r];
          ushort8 o;
          #pragma unroll
          for (int c2 = 0; c2 < 8; ++c2)
            o[c2] = (u16)f2bf_bits(xf[(size_t)d * 64 + lane * 8 + c2] * sc);
          xbf[(size_t)d * 8 + lane] = o;
        }
      }
    } else {
      const ushort8* xi = (const ushort8*)x;
      for (int u = tid; u < 2048; u += 256) {
        int r = u >> 3, lane = u & 7;
        int d = b * 256 + r;
        if (d < N_NODES) {
          float sc = disS[r];
          ushort8 vv = xi[(size_t)d * 8 + lane];
          ushort8 o;
          #pragma unroll
          for (int c2 = 0; c2 < 8; ++c2)
            o[c2] = (u16)f2bf_bits(bfbits2f(vv[c2]) * sc);
          xbf[(size_t)d * 8 + lane] = o;
        }
      }
    }
  }
}

// ------- conv2 gather (prescaled): P2 = dis2 * relu( dd*(sum P) + b2 ) -------

__global__ void gather_h2_kernel(const bf16* __restrict__ P, const int* __restrict__ rowstart,
                                 const int* __restrict__ len, const int* __restrict__ csr,
                                 const float* __restrict__ dis,
                                 const void* __restrict__ b, const Ctl* __restrict__ ctl,
                                 bf16* __restrict__ P2, int M)
{
  const bool f32 = ctl->isfp32 != 0;
  int gid = blockIdx.x * 256 + threadIdx.x;
  int d = gid >> 3;
  int lane = gid & 7;
  if (d >= M) return;
  const ushort8* H = (const ushort8*)P;
  float acc[8];
  gather_row8_pre(H, d, lane, rowstart, len, csr, acc);
  float dd = dis[d];
  ushort8 outv;
  #pragma unroll
  for (int c = 0; c < 8; ++c) {
    float h = acc[c] * dd + loadF(b, 8 * lane + c, f32);
    outv[c] = (u16)f2bf_bits(fmaxf(h, 0.f) * dd);
  }
  ((ushort8*)P2)[(size_t)d * 8 + lane] = outv;
}

// ---------------- MFMA GEMMs (16x16x32 bf16, fp32 acc) ----------------

// conv1 FUSED: gather(xbf prescaled, graph1) -> LDS, then Y = G @ W1 + b1 (+score/keys)
__global__ void gemm_in_kernel(const ushort8* __restrict__ xbf,
                               const int* __restrict__ rowstart, const int* __restrict__ csr,
                               const float* __restrict__ dis,
                               const void* __restrict__ W, const void* __restrict__ b,
                               const void* __restrict__ pw,
                               bf16* __restrict__ Y, const Ctl* __restrict__ ctl,
                               float* __restrict__ score, u64* __restrict__ keys)
{
  __shared__ short Xs[64 * 72];
  __shared__ short Wt[128 * 72];
  __shared__ float bs[128];
  __shared__ float ps[128];
  const bool f32 = ctl->isfp32 != 0;
  const int tid = threadIdx.x;
  const int row0 = blockIdx.x * 64;

  for (int i = tid; i < 64 * 128; i += 256) {
    int k = i >> 7, n = i & 127;
    Wt[n * 72 + k] = f32 ? f2bf_bits(((const float*)W)[i]) : ((const short*)W)[i];
  }
  // fused gather: 64 rows x 8 lane-units, 2 units/thread, straight into Xs
  for (int u = tid; u < 512; u += 256) {
    int r = u >> 3, lane = u & 7;
    int d = row0 + r;
    float acc[8];
    short8 outv;
    if (d < N_NODES) {
      gather_row8_pre(xbf, d, lane, rowstart, nullptr, csr, acc);
      float dd = dis[d];
      #pragma unroll
      for (int c = 0; c < 8; ++c) outv[c] = f2bf_bits(acc[c] * dd);
    } else {
      #pragma unroll
      for (int c = 0; c < 8; ++c) outv[c] = 0;
    }
    *(short8*)&Xs[r * 72 + lane * 8] = outv;
  }
  for (int i = tid; i < 128; i += 256) { bs[i] = loadF(b, i, f32); ps[i] = loadF(pw, i, f32); }
  __syncthreads();

  const int lane = tid & 63;
  const int w = tid >> 6;
  const int l16 = lane & 15;
  const int quad = lane >> 4;
  f32x4 acc[8];
  #pragma unroll
  for (int ct = 0; ct < 8; ++ct) acc[ct] = (f32x4){0.f, 0.f, 0.f, 0.f};
  const int arow = w * 16 + l16;
  #pragma unroll
  for (int kc = 0; kc < 2; ++kc) {
    short8 a = *(short8*)&Xs[arow * 72 + kc * 32 + quad * 8];
    #pragma unroll
    for (int ct = 0; ct < 8; ++ct) {
      short8 bb = *(short8*)&Wt[(ct * 16 + l16) * 72 + kc * 32 + quad * 8];
      acc[ct] = __builtin_amdgcn_mfma_f32_16x16x32_bf16(a, bb, acc[ct], 0, 0, 0);
    }
  }
  float inv_norm = ctl->inv_norm;
  #pragma unroll
  for (int r = 0; r < 4; ++r) {
    int gr = row0 + w * 16 + quad * 4 + r;
    float p = 0.f;
    #pragma unroll
    for (int ct = 0; ct < 8; ++ct) {
      int col = ct * 16 + l16;
      float h = acc[ct][r] + bs[col];
      if (gr < N_NODES) Y[(size_t)gr * 128 + col] = __float2bfloat16(h);
      p += fmaxf(h, 0.f) * ps[col];
    }
    p += __shfl_down(p, 8, 16);
    p += __shfl_down(p, 4, 16);
    p += __shfl_down(p, 2, 16);
    p += __shfl_down(p, 1, 16);
    if (l16 == 0 && gr < N_NODES) {
      float sc = tanhf(p * inv_norm);
      score[gr] = sc;
      u32 u = __float_as_uint(sc);
      u = (u & 0x80000000u) ? ~u : (u | 0x80000000u);
      keys[gr] = (((u64)u) << 16) | (u64)(0xFFFFu - (u32)gr);
    }
  }
}

// Y[M,64] = (relu?)X[M,128] @ W[128,64]; M multiple of 64
// kept!=null: X row = kept[row], apply relu*score[kept[row]] (fused TopK hp)
// prescale!=null: Y row *= prescale[row] (dis2, for gather-consumed outputs)
__global__ void gemm_128_64_kernel(const bf16* __restrict__ X, const void* __restrict__ W,
                                   bf16* __restrict__ Y, const Ctl* __restrict__ ctl,
                                   int M, int relu_x,
                                   const int* __restrict__ kept, const float* __restrict__ score,
                                   const float* __restrict__ prescale)
{
  __shared__ short Xs[64 * 136];
  __shared__ short Wt[64 * 136];
  __shared__ int keptS[64];
  __shared__ float scS[64];
  const bool f32 = ctl->isfp32 != 0;
  const int tid = threadIdx.x;
  const int row0 = blockIdx.x * 64;

  if (kept) {
    for (int i = tid; i < 64; i += 256) {
      int o = kept[row0 + i];
      keptS[i] = o;
      scS[i] = score[o];
    }
  }
  __syncthreads();

  for (int i = tid; i < 128 * 64; i += 256) {
    int k = i >> 6, n = i & 63;
    Wt[n * 136 + k] = f32 ? f2bf_bits(((const float*)W)[i]) : ((const short*)W)[i];
  }
  const u32* X2 = (const u32*)X;
  for (int p = tid; p < 64 * 64; p += 256) {
    int r = p >> 6, kp = p & 63;
    int srow = kept ? keptS[r] : (row0 + r);
    u32 v = X2[(size_t)srow * 64 + kp];
    if (relu_x) {
      if (v & 0x8000u) v &= 0xFFFF0000u;
      if (v & 0x80000000u) v &= 0x0000FFFFu;
    }
    if (kept) {
      bf16x2 h = *(bf16x2*)&v;
      float s = scS[r];
      bf16x2 o;
      o.x = __float2bfloat16(fmaxf(bf2f(h.x), 0.f) * s);
      o.y = __float2bfloat16(fmaxf(bf2f(h.y), 0.f) * s);
      v = *(u32*)&o;
    }
    *(u32*)&Xs[r * 136 + 2 * kp] = v;
  }
  __syncthreads();

  const int lane = tid & 63;
  const int w = tid >> 6;
  const int l16 = lane & 15;
  const int quad = lane >> 4;
  f32x4 acc[4];
  #pragma unroll
  for (int ct = 0; ct < 4; ++ct) acc[ct] = (f32x4){0.f, 0.f, 0.f, 0.f};
  const int arow = w * 16 + l16;
  #pragma unroll
  for (int kc = 0; kc < 4; ++kc) {
    short8 a = *(short8*)&Xs[arow * 136 + kc * 32 + quad * 8];
    #pragma unroll
    for (int ct = 0; ct < 4; ++ct) {
      short8 bb = *(short8*)&Wt[(ct * 16 + l16) * 136 + kc * 32 + quad * 8];
      acc[ct] = __builtin_amdgcn_mfma_f32_16x16x32_bf16(a, bb, acc[ct], 0, 0, 0);
    }
  }
  #pragma unroll
  for (int ct = 0; ct < 4; ++ct)
    #pragma unroll
    for (int r = 0; r < 4; ++r) {
      int gr = row0 + w * 16 + quad * 4 + r;
      float val = acc[ct][r];
      if (prescale) val *= prescale[gr];
      Y[(size_t)gr * 64 + ct * 16 + l16] = __float2bfloat16(val);
    }
}

// conv3 FUSED: gather(P2 prescaled, graph2) -> LDS, then Y[M,128] = G @ W3 + b3
__global__ void gemm_64_128_kernel(const bf16* __restrict__ P2,
                                   const int* __restrict__ rowstart, const int* __restrict__ len,
                                   const int* __restrict__ csr, const float* __restrict__ dis,
                                   const void* __restrict__ W, const void* __restrict__ b,
                                   bf16* __restrict__ Y, const Ctl* __restrict__ ctl, int M)
{
  __shared__ short Xs[64 * 72];
  __shared__ short Wt[128 * 72];
  __shared__ float bs[128];
  const bool f32 = ctl->isfp32 != 0;
  const int tid = threadIdx.x;
  const int row0 = blockIdx.x * 64;

  for (int i = tid; i < 64 * 128; i += 256) {
    int k = i >> 7, n = i & 127;
    Wt[n * 72 + k] = f32 ? f2bf_bits(((const float*)W)[i]) : ((const short*)W)[i];
  }
  // fused gather (relu baked into P2 at conv2 write)
  {
    const ushort8* H = (const ushort8*)P2;
    for (int u = tid; u < 512; u += 256) {
      int r = u >> 3, lane = u & 7;
      int d = row0 + r;           // M multiple of 64 -> always < M
      float acc[8];
      gather_row8_pre(H, d, lane, rowstart, len, csr, acc);
      float dd = dis[d];
      short8 outv;
      #pragma unroll
      for (int c = 0; c < 8; ++c) outv[c] = f2bf_bits(acc[c] * dd);
      *(short8*)&Xs[r * 72 + lane * 8] = outv;
    }
  }
  for (int i = tid; i < 128; i += 256) bs[i] = loadF(b, i, f32);
  __syncthreads();

  const int lane = tid & 63;
  const int w = tid >> 6;
  const int l16 = lane & 15;
  const int quad = lane >> 4;
  f32x4 acc[8];
  #pragma unroll
  for (int ct = 0; ct < 8; ++ct) acc[ct] = (f32x4){0.f, 0.f, 0.f, 0.f};
  const int arow = w * 16 + l16;
  #pragma unroll
  for (int kc = 0; kc < 2; ++kc) {
    short8 a = *(short8*)&Xs[arow * 72 + kc * 32 + quad * 8];
    #pragma unroll
    for (int ct = 0; ct < 8; ++ct) {
      short8 bb = *(short8*)&Wt[(ct * 16 + l16) * 72 + kc * 32 + quad * 8];
      acc[ct] = __builtin_amdgcn_mfma_f32_16x16x32_bf16(a, bb, acc[ct], 0, 0, 0);
    }
  }
  #pragma unroll
  for (int ct = 0; ct < 8; ++ct)
    #pragma unroll
    for (int r = 0; r < 4; ++r) {
      int gr = row0 + w * 16 + quad * 4 + r;
      int col = ct * 16 + l16;
      Y[(size_t)gr * 128 + col] = __float2bfloat16(acc[ct][r] + bs[col]);
    }
}

// conv4: gather (prescaled rows) + register acc + per-block partial
__global__ void agg_gather64_final_kernel(const bf16* __restrict__ P, const int* __restrict__ rowstart,
                                          const int* __restrict__ len, const int* __restrict__ csr,
                                          const float* __restrict__ dis,
                                          float* __restrict__ partial, int M, int nblk)
{
  __shared__ float cs[64];
  const int tid = threadIdx.x;
  if (tid < 64) cs[tid] = 0.f;
  __syncthreads();
  const int lane = tid & 7;
  const ushort8* H = (const ushort8*)P;
  float acc[8];
  #pragma unroll
  for (int c = 0; c < 8; ++c) acc[c] = 0.f;
  for (int d = (blockIdx.x * 256 + tid) >> 3; d < M; d += nblk * 32) {
    float rsum[8];
    gather_row8_pre(H, d, lane, rowstart, len, csr, rsum);
    float dd = dis[d];
    #pragma unroll
    for (int c = 0; c < 8; ++c) acc[c] += rsum[c] * dd;
  }
  #pragma unroll
  for (int c = 0; c < 8; ++c) atomicAdd(&cs[8 * lane + c], acc[c]);
  __syncthreads();
  if (tid < 64) partial[(size_t)tid * nblk + blockIdx.x] = cs[tid];
}

__global__ void reduce_out_kernel(const float* __restrict__ partial, const void* __restrict__ b,
                                  const Ctl* __restrict__ ctl, void* __restrict__ out, int nblk)
{
  __shared__ float sh[256];
  int c = blockIdx.x;
  float s = 0.f;
  for (int j = threadIdx.x; j < nblk; j += 256) s += partial[(size_t)c * nblk + j];
  sh[threadIdx.x] = s;
  __syncthreads();
  for (int st = 128; st > 0; st >>= 1) {
    if (threadIdx.x < st) sh[threadIdx.x] += sh[threadIdx.x + st];
    __syncthreads();
  }
  if (threadIdx.x == 0) {
    const bool f32 = ctl->isfp32 != 0;
    float val = sh[0] / (float)K_KEEP + loadF(b, c, f32);
    if (f32) ((float*)out)[c] = val;
    else     ((bf16*)out)[c] = __float2bfloat16(val);
  }
}

// ------- TopK select: separate-launch hist+pick (proven R0/R2), parallel pick + early-exit -------

__global__ void histpick_kernel(const u64* __restrict__ keys, Ctl* ctl, int shift, int nblocks) {
  __shared__ u32 lh[256];
  __shared__ u32 sfx[256];
  __shared__ int lastflag;
  __shared__ int selsh;
  const int tid = threadIdx.x;
  if (ctl->gen != 0u) return;          // threshold already resolved by earlier pass
  lh[tid] = 0;
  __syncthreads();
  u64 prefix = ctl->prefix;
  int i = blockIdx.x * 256 + tid;
  if (i < N_NODES) {
    u64 key = keys[i];
    if ((key >> (shift + 8)) == (prefix >> (shift + 8)))
      atomicAdd(&lh[(u32)((key >> shift) & 0xFF)], 1u);
  }
  __syncthreads();
  u32 c = lh[tid];
  if (c) atomicAdd(&ctl->hist[tid], c);
  __syncthreads();
  if (tid == 0) {
    __threadfence();
    u32 old = atomicAdd(&ctl->done, 1u);
    lastflag = (old == (u32)(nblocks - 1));
  }
  __syncthreads();
  if (!lastflag) return;
  // last block: parallel pick via suffix scan
  u32 cc = atomicExch(&ctl->hist[tid], 0u);   // coherent read + zero for next pass
  sfx[tid] = cc;
  __syncthreads();
  for (int off = 1; off < 256; off <<= 1) {
    u32 t = (tid + off < 256) ? sfx[tid + off] : 0u;
    __syncthreads();
    sfx[tid] += t;
    __syncthreads();
  }
  u32 kr = ctl->kremain;
  u32 above = (tid < 255) ? sfx[tid + 1] : 0u;
  if (sfx[tid] >= kr && above < kr) selsh = tid;   // unique (sfx non-increasing)
  __syncthreads();
  if (tid == 0) {
    int sel = selsh;
    u32 ab = (sel < 255) ? sfx[sel + 1] : 0u;
    u32 newkr = kr - ab;
    u32 bucketcnt = sfx[sel] - ab;
    ctl->kremain = newkr;
    ctl->prefix = prefix | (((u64)(u32)sel) << shift);
    if (newkr == bucketcnt) ctl->gen = 1u;  // whole boundary bucket kept -> resolved
    ctl->done = 0u;
  }
}

__global__ void mark_kernel(const u64* __restrict__ keys, Ctl* ctl,
                            int* __restrict__ new_idx, int* __restrict__ kept)
{
  int i = blockIdx.x * 256 + threadIdx.x;
  if (i >= N_NODES) return;
  if (keys[i] >= ctl->prefix) {
    int pos = (int)atomicAdd(&ctl->cnt, 1u);
    new_idx[i] = pos;
    kept[pos] = i;
  } else {
    new_idx[i] = -1;
  }
}

// ------- CSR2 in ONE kernel: count + wave-aggregated alloc + fill (order-free rows) -------

__global__ void csr2_build_kernel(const int* __restrict__ kept, const int* __restrict__ rowstart1,
                                  const int* __restrict__ csr1, const int* __restrict__ new_idx,
                                  Ctl* ctl, int* __restrict__ rowstart2, int* __restrict__ len2,
                                  float* __restrict__ dis2, int* __restrict__ csr2)
{
  int kp = blockIdx.x * 256 + threadIdx.x;
  int lane = threadIdx.x & 63;
  int c = 0;
  int i0 = 0, i1 = 0;
  if (kp < K_KEEP) {
    int o = kept[kp];
    i0 = rowstart1[o]; i1 = rowstart1[o + 1];
    int i = i0;
    for (; i + 4 <= i1; i += 4) {
      int s0 = csr1[i], s1 = csr1[i + 1], s2 = csr1[i + 2], s3 = csr1[i + 3];
      c += (new_idx[s0] >= 0) + (new_idx[s1] >= 0) + (new_idx[s2] >= 0) + (new_idx[s3] >= 0);
    }
    for (; i < i1; ++i) c += (new_idx[csr1[i]] >= 0);
  }
  // wave inclusive scan of c
  int pre = c;
  #pragma unroll
  for (int off = 1; off < 64; off <<= 1) {
    int t = __shfl_up(pre, off);
    if (lane >= off) pre += t;
  }
  int wtot = __shfl(pre, 63);
  int wbase = 0;
  if (lane == 0) wbase = (int)atomicAdd(&ctl->pad, (u32)wtot);
  wbase = __shfl(wbase, 0);
  int base = wbase + pre - c;
  if (kp < K_KEEP) {
    rowstart2[kp] = base;
    len2[kp] = c;
    dis2[kp] = rsqrtf(1.0f + (float)c);
    int w = base;
    for (int i = i0; i < i1; ++i) {
      int ns = new_idx[csr1[i]];
      if (ns >= 0) csr2[w++] = ns;
    }
  }
}

// ---------------- launch ----------------

extern "C" void kernel_launch(void* const* d_in, const int* in_sizes, int n_in,
                              void* d_out, int out_size, void* d_ws, size_t ws_size,
                              hipStream_t stream)
{
  const void* x  = d_in[0];
  const int*  ei = (const int*)d_in[1];
  const void* W1 = d_in[3];
  const void* b1 = d_in[4];
  const void* pw = d_in[5];
  const void* W2 = d_in[6];
  const void* b2 = d_in[7];
  const void* W3 = d_in[8];
  const void* b3 = d_in[9];
  const void* W4 = d_in[10];
  const void* b4 = d_in[11];

  const int* src = ei;
  const int* dst = ei + N_EDGES;

  float* F = (float*)d_ws;
  bf16*  A16       = (bf16*)F;               // N x 128 bf16
  bf16*  B16       = (bf16*)(F + 3200000);   // N x 128 bf16
  bf16*  C16       = (bf16*)(F + 6400000);   // K x 128 bf16
  u32*   xbf       = (u32*)(F + 9000000);    // N x 32 u32 (xbf = dis1*x as bf16 pairs)
  float* dis1      = F + 10600000;           // 50000
  float* dis2      = F + 10650000;           // 40000
  float* score     = F + 10690000;           // 50000
  u64*   keys      = (u64*)(F + 10740000);   // 50000 u64
  int*   new_idx   = (int*)(F + 10840000);   // 50000
  int*   kept      = (int*)(F + 10890000);   // 40000
  int*   len2      = (int*)(F + 10930000);   // 40000
  int*   rowstart1 = (int*)(F + 10970000);   // 50001
  int*   rowstart2 = (int*)(F + 11020004);   // 40000
  int*   csr1      = (int*)(F + 11060008);   // 800000
  int*   csr2      = (int*)(F + 11860008);   // 800000
  Ctl*   ctl       = (Ctl*)(F + 12660008);   // ~1.1 KB
  int*   detcnt    = (int*)(F + 12660856);   // 64
  int*   bucket_cur= (int*)(F + 12660920);   // 196
  u32*   bucketbuf = (u32*)(F + 12726908);   // 196*6144
  float* partial   = F + 13931132;           // 64 x 1024

  const int NB1 = (N_NODES + 255) / 256;     // 196
  const int EB2 = (N_EDGES + 2047) / 2048;   // 391
  const int GB1 = (N_NODES + 63) / 64;       // 782
  const int ABK = K_KEEP * 8 / 256;          // 1250
  const int CB2 = (K_KEEP + 255) / 256;      // 157
  const int NBF = 1024;                      // final-gather blocks

  init_kernel<<<NB1, 256, 0, stream>>>((const unsigned short*)x, bucket_cur, detcnt, ctl);

  // CSR graph 1 via bucket sort (+fused dtype/norm)
  bucket_scatter_kernel<<<EB2, 256, 0, stream>>>(src, dst, bucket_cur, bucketbuf,
                                                 detcnt, pw, ctl);
  // CSR1 build + fused xbf = dis1*x prescale-convert
  csr_from_buckets_kernel<<<BKT, 256, 0, stream>>>(bucketbuf, bucket_cur, rowstart1, dis1, csr1,
                                                   x, (ushort8*)xbf, ctl);

  // conv1 FUSED: gather(xbf) -> LDS -> h1 = G @ W1 + b1 (+fused score/keys)
  gemm_in_kernel<<<GB1, 256, 0, stream>>>((const ushort8*)xbf, rowstart1, csr1, dis1,
                                          W1, b1, pw, B16, ctl, score, keys);

  // top-K select (6 x 8-bit radix, separate launches; early-exit skips tie-break passes)
  for (int p = 0; p < 6; ++p)
    histpick_kernel<<<NB1, 256, 0, stream>>>(keys, ctl, 40 - 8 * p, NB1);
  mark_kernel<<<NB1, 256, 0, stream>>>(keys, ctl, new_idx, kept);

  // CSR graph 2 in one kernel (row bases via wave-aggregated atomic; order-free)
  csr2_build_kernel<<<CB2, 256, 0, stream>>>(kept, rowstart1, csr1, new_idx, ctl,
                                             rowstart2, len2, dis2, csr2);

  // conv2: A = dis2*(hp @ W2) ; P2 = dis2*relu(dd*sum(A) + b2)
  gemm_128_64_kernel<<<K_KEEP / 64, 256, 0, stream>>>(B16, W2, A16, ctl, K_KEEP, 0, kept, score, dis2);
  gather_h2_kernel<<<ABK, 256, 0, stream>>>(A16, rowstart2, len2, csr2, dis2, b2, ctl, C16, K_KEEP);

  // conv3 FUSED: gather(P2) -> LDS -> h3 = G @ W3 + b3
  gemm_64_128_kernel<<<K_KEEP / 64, 256, 0, stream>>>(C16, rowstart2, len2, csr2, dis2,
                                                      W3, b3, B16, ctl, K_KEEP);

  // conv4: A = dis2*(relu(h3) @ W4) ; partials = gather(A) ; separate tiny reduce
  gemm_128_64_kernel<<<K_KEEP / 64, 256, 0, stream>>>(B16, W4, A16, ctl, K_KEEP, 1, nullptr, nullptr, dis2);
  agg_gather64_final_kernel<<<NBF, 256, 0, stream>>>(A16, rowstart2, len2, csr2, dis2,
                                                     partial, K_KEEP, NBF);
  reduce_out_kernel<<<64, 256, 0, stream>>>(partial, b4, ctl, d_out, NBF);
}

// Round 11
// 313.571 us; speedup vs baseline: 2.0001x; 1.0185x over previous
//
#include <hip/hip_runtime.h>
#include <hip/hip_bf16.h>
#include <stdint.h>

#define N_NODES 50000
#define N_EDGES 800000
#define K_KEEP  40000
#define BKT     196        // ceil(N_NODES/256) dst-range buckets
#define BCAP    6144       // per-bucket capacity (mean 4081, +32 sigma)

typedef unsigned long long u64;
typedef unsigned int u32;
typedef unsigned short u16;
typedef __hip_bfloat16 bf16;
typedef __hip_bfloat162 bf16x2;
typedef __attribute__((ext_vector_type(8))) short short8;
typedef __attribute__((ext_vector_type(8))) unsigned short ushort8;
typedef __attribute__((ext_vector_type(4))) float f32x4;

struct Ctl {
  u64 prefix;
  u32 kremain;
  u32 cnt;
  float inv_norm;
  u32 isfp32;
  u32 done;         // radix pass arrival counter (reset by picker each pass)
  u32 pad;          // csr2 edge cursor
  u32 gen;          // 0 = unresolved; else (resolution pass + 1); pass==gen does marking
  u32 done2;        // (unused; layout keep)
  u32 hist[256];    // radix histogram (LDS-aggregated flushes only)
};

__device__ __forceinline__ float bf2f(bf16 v) { return __bfloat162float(v); }
__device__ __forceinline__ float bfbits2f(unsigned short u) {
  return __uint_as_float(((u32)u) << 16);
}
__device__ __forceinline__ float loadF(const void* p, size_t i, bool f32) {
  return f32 ? ((const float*)p)[i] : bf2f(((const bf16*)p)[i]);
}
__device__ __forceinline__ short f2bf_bits(float f) {
  bf16 t = __float2bfloat16(f);
  return *(const short*)&t;
}

// Prescaled gather (R9) with ILP-8 (R11): rows of H are P = dis[row]*h[row];
// sums P over {self} ∪ N(d). Caller multiplies by dis[d] once.
// Accumulation ORDER identical to the R10 ILP-4 version (two sequential
// 4-groups per 8-iteration) -> bit-exact results, only more loads in flight.
__device__ __forceinline__ void gather_row8_pre(const ushort8* __restrict__ H, int d, int lane,
                                                const int* __restrict__ rowstart,
                                                const int* __restrict__ len,
                                                const int* __restrict__ csr,
                                                float* acc)
{
  ushort8 v = H[(size_t)d * 8 + lane];
  #pragma unroll
  for (int c = 0; c < 8; ++c) acc[c] = bfbits2f(v[c]);
  int i = rowstart[d];
  int i1 = len ? (i + len[d]) : rowstart[d + 1];
  for (; i + 8 <= i1; i += 8) {
    int s0 = csr[i],     s1 = csr[i + 1], s2 = csr[i + 2], s3 = csr[i + 3];
    int s4 = csr[i + 4], s5 = csr[i + 5], s6 = csr[i + 6], s7 = csr[i + 7];
    ushort8 v0 = H[(size_t)s0 * 8 + lane];
    ushort8 v1 = H[(size_t)s1 * 8 + lane];
    ushort8 v2 = H[(size_t)s2 * 8 + lane];
    ushort8 v3 = H[(size_t)s3 * 8 + lane];
    ushort8 v4 = H[(size_t)s4 * 8 + lane];
    ushort8 v5 = H[(size_t)s5 * 8 + lane];
    ushort8 v6 = H[(size_t)s6 * 8 + lane];
    ushort8 v7 = H[(size_t)s7 * 8 + lane];
    #pragma unroll
    for (int c = 0; c < 8; ++c) {
      acc[c] += (bfbits2f(v0[c]) + bfbits2f(v1[c]))
              + (bfbits2f(v2[c]) + bfbits2f(v3[c]));
      acc[c] += (bfbits2f(v4[c]) + bfbits2f(v5[c]))
              + (bfbits2f(v6[c]) + bfbits2f(v7[c]));
    }
  }
  for (; i + 4 <= i1; i += 4) {
    int s0 = csr[i], s1 = csr[i + 1], s2 = csr[i + 2], s3 = csr[i + 3];
    ushort8 v0 = H[(size_t)s0 * 8 + lane];
    ushort8 v1 = H[(size_t)s1 * 8 + lane];
    ushort8 v2 = H[(size_t)s2 * 8 + lane];
    ushort8 v3 = H[(size_t)s3 * 8 + lane];
    #pragma unroll
    for (int c = 0; c < 8; ++c) {
      acc[c] += (bfbits2f(v0[c]) + bfbits2f(v1[c]))
              + (bfbits2f(v2[c]) + bfbits2f(v3[c]));
    }
  }
  for (; i < i1; ++i) {
    int s = csr[i];
    ushort8 vv = H[(size_t)s * 8 + lane];
    #pragma unroll
    for (int c = 0; c < 8; ++c) acc[c] += bfbits2f(vv[c]);
  }
}

// ---------------- init (+parallel dtype detect, proven R5-R8) ----------------

__global__ void init_kernel(const unsigned short* __restrict__ x16,
                            int* __restrict__ bucket_cur, int* __restrict__ detcnt, Ctl* ctl) {
  __shared__ u32 dsh[256];
  int i = blockIdx.x * 256 + threadIdx.x;
  if (i < BKT) bucket_cur[i] = i * BCAP;
  if (blockIdx.x == 0) {
    ctl->hist[threadIdx.x] = 0u;
    if (threadIdx.x == 0) {
      ctl->prefix = 0ull; ctl->kremain = K_KEEP; ctl->cnt = 0u;
      ctl->done = 0u; ctl->pad = 0u; ctl->gen = 0u; ctl->done2 = 0u;
    }
  }
  if (blockIdx.x < 64) {
    int base = blockIdx.x * 2048;
    u32 c = 0;
    for (int j = threadIdx.x; j < 2048; j += 256) {
      u32 h = x16[base + j];
      if ((h & 0x7F80u) == 0x7F80u) c++;
    }
    dsh[threadIdx.x] = c;
    __syncthreads();
    for (int s = 128; s > 0; s >>= 1) {
      if (threadIdx.x < s) dsh[threadIdx.x] += dsh[threadIdx.x + s];
      __syncthreads();
    }
    if (threadIdx.x == 0) detcnt[blockIdx.x] = (int)dsh[0];
  }
}

// ------- CSR1 bucket scatter (register-cached edges, R11) + fused dtype/norm -------

__global__ void bucket_scatter_kernel(const int* __restrict__ src, const int* __restrict__ dst,
                                      int* __restrict__ bucket_cur, u32* __restrict__ bucketbuf,
                                      const int* __restrict__ detcnt, const void* __restrict__ pw,
                                      Ctl* ctl)
{
  __shared__ u32 hist[BKT];
  __shared__ u32 base[BKT];
  __shared__ int f32sh;
  __shared__ float ns[128];
  const int tid = threadIdx.x;
  const int e0 = blockIdx.x * 2048;

  // dtype detect from detcnt (written by init, prior dispatch)
  if (tid < 64) {
    int dc = detcnt[tid];
    for (int off = 32; off; off >>= 1) dc += __shfl_down(dc, off);
    if (tid == 0) f32sh = (dc >= 16) ? 1 : 0;
  }
  for (int t = tid; t < BKT; t += 256) hist[t] = 0;
  __syncthreads();
  const bool f32in = f32sh != 0;

  // load this block's 8 edges/thread ONCE into registers
  int dreg[8], sreg[8];
  #pragma unroll
  for (int j = 0; j < 8; ++j) {
    int e = e0 + j * 256 + tid;
    if (e < N_EDGES) { dreg[j] = dst[e]; sreg[j] = src[e]; }
    else             { dreg[j] = -1;     sreg[j] = 0;      }
  }
  #pragma unroll
  for (int j = 0; j < 8; ++j)
    if (dreg[j] >= 0) atomicAdd(&hist[dreg[j] >> 8], 1u);
  __syncthreads();
  for (int t = tid; t < BKT; t += 256) {
    u32 c = hist[t];
    base[t] = c ? (u32)atomicAdd(&bucket_cur[t], (int)c) : 0u;
    hist[t] = 0;
  }
  __syncthreads();
  #pragma unroll
  for (int j = 0; j < 8; ++j) {
    if (dreg[j] >= 0) {
      int d = dreg[j];
      int b = d >> 8;
      u32 pos = base[b] + atomicAdd(&hist[b], 1u);
      bucketbuf[pos] = ((u32)sreg[j] << 8) | (u32)(d & 255);
    }
  }
  // fused norm: block 0 computes inv_norm + publishes isfp32
  if (blockIdx.x == 0) {
    if (tid < 128) { float v = loadF(pw, tid, f32in); ns[tid] = v * v; }
    __syncthreads();
    for (int s = 64; s > 0; s >>= 1) {
      if (tid < s) ns[tid] += ns[tid + s];
      __syncthreads();
    }
    if (tid == 0) {
      ctl->inv_norm = 1.0f / sqrtf(ns[0]);
      ctl->isfp32 = f32in ? 1u : 0u;
    }
  }
}

// ------- CSR1 from buckets (inline bucket scan) + fused x -> xbf = dis1*x (bf16) -------

__global__ void csr_from_buckets_kernel(const u32* __restrict__ bucketbuf, const int* __restrict__ bucket_cur,
                                        int* __restrict__ rowstart, float* __restrict__ dis,
                                        int* __restrict__ csr,
                                        const void* __restrict__ x, ushort8* __restrict__ xbf,
                                        const Ctl* __restrict__ ctl)
{
  __shared__ u32 cnt[256];
  __shared__ u32 loc[256];
  __shared__ u32 cur[256];
  __shared__ float disS[256];
  const int b = blockIdx.x;
  const int tid = threadIdx.x;

  // inline scan of all bucket sizes -> off0 for this bucket
  int v = (tid < BKT) ? (bucket_cur[tid] - tid * BCAP) : 0;
  loc[tid] = (u32)v;
  __syncthreads();
  for (int off = 1; off < 256; off <<= 1) {
    u32 t = (tid >= off) ? loc[tid - off] : 0;
    __syncthreads();
    loc[tid] += t;
    __syncthreads();
  }
  const int bc = bucket_cur[b] - b * BCAP;
  const int off0 = (int)loc[b] - bc;
  if (b == BKT - 1 && tid == 0) rowstart[N_NODES] = (int)loc[BKT - 1];
  __syncthreads();

  const u32* buf = bucketbuf + (size_t)b * BCAP;
  cnt[tid] = 0;
  __syncthreads();
  for (int i = tid; i < bc; i += 256) atomicAdd(&cnt[buf[i] & 255u], 1u);
  __syncthreads();
  u32 c = cnt[tid];
  loc[tid] = c;
  __syncthreads();
  for (int off = 1; off < 256; off <<= 1) {
    u32 t = (tid >= off) ? loc[tid - off] : 0;
    __syncthreads();
    loc[tid] += t;
    __syncthreads();
  }
  int node = b * 256 + tid;
  u32 excl = loc[tid] - c;
  float ddv = rsqrtf(1.0f + (float)c);
  disS[tid] = ddv;
  if (node < N_NODES) {
    rowstart[node] = off0 + (int)excl;
    dis[node] = ddv;
  }
  cur[tid] = off0 + excl;
  __syncthreads();
  for (int i = tid; i < bc; i += 256) {
    u32 p = buf[i];
    u32 pos = atomicAdd(&cur[p & 255u], 1u);
    csr[pos] = (int)(p >> 8);
  }
  // fused prescaled conversion: xbf[node] = bf16(dis1[node] * x[node]), 64 ch
  {
    const bool f32in = ctl->isfp32 != 0;
    if (f32in) {
      const float* xf = (const float*)x;
      for (int u = tid; u < 2048; u += 256) {
        int r = u >> 3, lane = u & 7;
        int d = b * 256 + r;
        if (d < N_NODES) {
          float sc = disS[r];
          ushort8 o;
          #pragma unroll
          for (int c2 = 0; c2 < 8; ++c2)
            o[c2] = (u16)f2bf_bits(xf[(size_t)d * 64 + lane * 8 + c2] * sc);
          xbf[(size_t)d * 8 + lane] = o;
        }
      }
    } else {
      const ushort8* xi = (const ushort8*)x;
      for (int u = tid; u < 2048; u += 256) {
        int r = u >> 3, lane = u & 7;
        int d = b * 256 + r;
        if (d < N_NODES) {
          float sc = disS[r];
          ushort8 vv = xi[(size_t)d * 8 + lane];
          ushort8 o;
          #pragma unroll
          for (int c2 = 0; c2 < 8; ++c2)
            o[c2] = (u16)f2bf_bits(bfbits2f(vv[c2]) * sc);
          xbf[(size_t)d * 8 + lane] = o;
        }
      }
    }
  }
}

// ------- conv2 gather (prescaled): P2 = dis2 * relu( dd*(sum P) + b2 ) -------

__global__ void gather_h2_kernel(const bf16* __restrict__ P, const int* __restrict__ rowstart,
                                 const int* __restrict__ len, const int* __restrict__ csr,
                                 const float* __restrict__ dis,
                                 const void* __restrict__ b, const Ctl* __restrict__ ctl,
                                 bf16* __restrict__ P2, int M)
{
  const bool f32 = ctl->isfp32 != 0;
  int gid = blockIdx.x * 256 + threadIdx.x;
  int d = gid >> 3;
  int lane = gid & 7;
  if (d >= M) return;
  const ushort8* H = (const ushort8*)P;
  float acc[8];
  gather_row8_pre(H, d, lane, rowstart, len, csr, acc);
  float dd = dis[d];
  ushort8 outv;
  #pragma unroll
  for (int c = 0; c < 8; ++c) {
    float h = acc[c] * dd + loadF(b, 8 * lane + c, f32);
    outv[c] = (u16)f2bf_bits(fmaxf(h, 0.f) * dd);
  }
  ((ushort8*)P2)[(size_t)d * 8 + lane] = outv;
}

// ---------------- MFMA GEMMs (16x16x32 bf16, fp32 acc) ----------------

// conv1 FUSED: gather(xbf prescaled, graph1) -> LDS, then Y = G @ W1 + b1 (+score/keys)
__global__ void gemm_in_kernel(const ushort8* __restrict__ xbf,
                               const int* __restrict__ rowstart, const int* __restrict__ csr,
                               const float* __restrict__ dis,
                               const void* __restrict__ W, const void* __restrict__ b,
                               const void* __restrict__ pw,
                               bf16* __restrict__ Y, const Ctl* __restrict__ ctl,
                               float* __restrict__ score, u64* __restrict__ keys)
{
  __shared__ short Xs[64 * 72];
  __shared__ short Wt[128 * 72];
  __shared__ float bs[128];
  __shared__ float ps[128];
  const bool f32 = ctl->isfp32 != 0;
  const int tid = threadIdx.x;
  const int row0 = blockIdx.x * 64;

  for (int i = tid; i < 64 * 128; i += 256) {
    int k = i >> 7, n = i & 127;
    Wt[n * 72 + k] = f32 ? f2bf_bits(((const float*)W)[i]) : ((const short*)W)[i];
  }
  // fused gather: 64 rows x 8 lane-units, 2 units/thread, straight into Xs
  for (int u = tid; u < 512; u += 256) {
    int r = u >> 3, lane = u & 7;
    int d = row0 + r;
    float acc[8];
    short8 outv;
    if (d < N_NODES) {
      gather_row8_pre(xbf, d, lane, rowstart, nullptr, csr, acc);
      float dd = dis[d];
      #pragma unroll
      for (int c = 0; c < 8; ++c) outv[c] = f2bf_bits(acc[c] * dd);
    } else {
      #pragma unroll
      for (int c = 0; c < 8; ++c) outv[c] = 0;
    }
    *(short8*)&Xs[r * 72 + lane * 8] = outv;
  }
  for (int i = tid; i < 128; i += 256) { bs[i] = loadF(b, i, f32); ps[i] = loadF(pw, i, f32); }
  __syncthreads();

  const int lane = tid & 63;
  const int w = tid >> 6;
  const int l16 = lane & 15;
  const int quad = lane >> 4;
  f32x4 acc[8];
  #pragma unroll
  for (int ct = 0; ct < 8; ++ct) acc[ct] = (f32x4){0.f, 0.f, 0.f, 0.f};
  const int arow = w * 16 + l16;
  #pragma unroll
  for (int kc = 0; kc < 2; ++kc) {
    short8 a = *(short8*)&Xs[arow * 72 + kc * 32 + quad * 8];
    #pragma unroll
    for (int ct = 0; ct < 8; ++ct) {
      short8 bb = *(short8*)&Wt[(ct * 16 + l16) * 72 + kc * 32 + quad * 8];
      acc[ct] = __builtin_amdgcn_mfma_f32_16x16x32_bf16(a, bb, acc[ct], 0, 0, 0);
    }
  }
  float inv_norm = ctl->inv_norm;
  #pragma unroll
  for (int r = 0; r < 4; ++r) {
    int gr = row0 + w * 16 + quad * 4 + r;
    float p = 0.f;
    #pragma unroll
    for (int ct = 0; ct < 8; ++ct) {
      int col = ct * 16 + l16;
      float h = acc[ct][r] + bs[col];
      if (gr < N_NODES) Y[(size_t)gr * 128 + col] = __float2bfloat16(h);
      p += fmaxf(h, 0.f) * ps[col];
    }
    p += __shfl_down(p, 8, 16);
    p += __shfl_down(p, 4, 16);
    p += __shfl_down(p, 2, 16);
    p += __shfl_down(p, 1, 16);
    if (l16 == 0 && gr < N_NODES) {
      float sc = tanhf(p * inv_norm);
      score[gr] = sc;
      u32 u = __float_as_uint(sc);
      u = (u & 0x80000000u) ? ~u : (u | 0x80000000u);
      keys[gr] = (((u64)u) << 16) | (u64)(0xFFFFu - (u32)gr);
    }
  }
}

// Y[M,64] = (relu?)X[M,128] @ W[128,64]; M multiple of 64
// kept!=null: X row = kept[row], apply relu*score[kept[row]] (fused TopK hp)
// prescale!=null: Y row *= prescale[row] (dis2, for gather-consumed outputs)
__global__ void gemm_128_64_kernel(const bf16* __restrict__ X, const void* __restrict__ W,
                                   bf16* __restrict__ Y, const Ctl* __restrict__ ctl,
                                   int M, int relu_x,
                                   const int* __restrict__ kept, const float* __restrict__ score,
                                   const float* __restrict__ prescale)
{
  __shared__ short Xs[64 * 136];
  __shared__ short Wt[64 * 136];
  __shared__ int keptS[64];
  __shared__ float scS[64];
  const bool f32 = ctl->isfp32 != 0;
  const int tid = threadIdx.x;
  const int row0 = blockIdx.x * 64;

  if (kept) {
    for (int i = tid; i < 64; i += 256) {
      int o = kept[row0 + i];
      keptS[i] = o;
      scS[i] = score[o];
    }
  }
  __syncthreads();

  for (int i = tid; i < 128 * 64; i += 256) {
    int k = i >> 6, n = i & 63;
    Wt[n * 136 + k] = f32 ? f2bf_bits(((const float*)W)[i]) : ((const short*)W)[i];
  }
  const u32* X2 = (const u32*)X;
  for (int p = tid; p < 64 * 64; p += 256) {
    int r = p >> 6, kp = p & 63;
    int srow = kept ? keptS[r] : (row0 + r);
    u32 v = X2[(size_t)srow * 64 + kp];
    if (relu_x) {
      if (v & 0x8000u) v &= 0xFFFF0000u;
      if (v & 0x80000000u) v &= 0x0000FFFFu;
    }
    if (kept) {
      bf16x2 h = *(bf16x2*)&v;
      float s = scS[r];
      bf16x2 o;
      o.x = __float2bfloat16(fmaxf(bf2f(h.x), 0.f) * s);
      o.y = __float2bfloat16(fmaxf(bf2f(h.y), 0.f) * s);
      v = *(u32*)&o;
    }
    *(u32*)&Xs[r * 136 + 2 * kp] = v;
  }
  __syncthreads();

  const int lane = tid & 63;
  const int w = tid >> 6;
  const int l16 = lane & 15;
  const int quad = lane >> 4;
  f32x4 acc[4];
  #pragma unroll
  for (int ct = 0; ct < 4; ++ct) acc[ct] = (f32x4){0.f, 0.f, 0.f, 0.f};
  const int arow = w * 16 + l16;
  #pragma unroll
  for (int kc = 0; kc < 4; ++kc) {
    short8 a = *(short8*)&Xs[arow * 136 + kc * 32 + quad * 8];
    #pragma unroll
    for (int ct = 0; ct < 4; ++ct) {
      short8 bb = *(short8*)&Wt[(ct * 16 + l16) * 136 + kc * 32 + quad * 8];
      acc[ct] = __builtin_amdgcn_mfma_f32_16x16x32_bf16(a, bb, acc[ct], 0, 0, 0);
    }
  }
  #pragma unroll
  for (int ct = 0; ct < 4; ++ct)
    #pragma unroll
    for (int r = 0; r < 4; ++r) {
      int gr = row0 + w * 16 + quad * 4 + r;
      float val = acc[ct][r];
      if (prescale) val *= prescale[gr];
      Y[(size_t)gr * 64 + ct * 16 + l16] = __float2bfloat16(val);
    }
}

// conv3 FUSED: gather(P2 prescaled, graph2) -> LDS, then Y[M,128] = G @ W3 + b3
__global__ void gemm_64_128_kernel(const bf16* __restrict__ P2,
                                   const int* __restrict__ rowstart, const int* __restrict__ len,
                                   const int* __restrict__ csr, const float* __restrict__ dis,
                                   const void* __restrict__ W, const void* __restrict__ b,
                                   bf16* __restrict__ Y, const Ctl* __restrict__ ctl, int M)
{
  __shared__ short Xs[64 * 72];
  __shared__ short Wt[128 * 72];
  __shared__ float bs[128];
  const bool f32 = ctl->isfp32 != 0;
  const int tid = threadIdx.x;
  const int row0 = blockIdx.x * 64;

  for (int i = tid; i < 64 * 128; i += 256) {
    int k = i >> 7, n = i & 127;
    Wt[n * 72 + k] = f32 ? f2bf_bits(((const float*)W)[i]) : ((const short*)W)[i];
  }
  // fused gather (relu baked into P2 at conv2 write)
  {
    const ushort8* H = (const ushort8*)P2;
    for (int u = tid; u < 512; u += 256) {
      int r = u >> 3, lane = u & 7;
      int d = row0 + r;           // M multiple of 64 -> always < M
      float acc[8];
      gather_row8_pre(H, d, lane, rowstart, len, csr, acc);
      float dd = dis[d];
      short8 outv;
      #pragma unroll
      for (int c = 0; c < 8; ++c) outv[c] = f2bf_bits(acc[c] * dd);
      *(short8*)&Xs[r * 72 + lane * 8] = outv;
    }
  }
  for (int i = tid; i < 128; i += 256) bs[i] = loadF(b, i, f32);
  __syncthreads();

  const int lane = tid & 63;
  const int w = tid >> 6;
  const int l16 = lane & 15;
  const int quad = lane >> 4;
  f32x4 acc[8];
  #pragma unroll
  for (int ct = 0; ct < 8; ++ct) acc[ct] = (f32x4){0.f, 0.f, 0.f, 0.f};
  const int arow = w * 16 + l16;
  #pragma unroll
  for (int kc = 0; kc < 2; ++kc) {
    short8 a = *(short8*)&Xs[arow * 72 + kc * 32 + quad * 8];
    #pragma unroll
    for (int ct = 0; ct < 8; ++ct) {
      short8 bb = *(short8*)&Wt[(ct * 16 + l16) * 72 + kc * 32 + quad * 8];
      acc[ct] = __builtin_amdgcn_mfma_f32_16x16x32_bf16(a, bb, acc[ct], 0, 0, 0);
    }
  }
  #pragma unroll
  for (int ct = 0; ct < 8; ++ct)
    #pragma unroll
    for (int r = 0; r < 4; ++r) {
      int gr = row0 + w * 16 + quad * 4 + r;
      int col = ct * 16 + l16;
      Y[(size_t)gr * 128 + col] = __float2bfloat16(acc[ct][r] + bs[col]);
    }
}

// conv4: gather (prescaled rows) + register acc + per-block partial
__global__ void agg_gather64_final_kernel(const bf16* __restrict__ P, const int* __restrict__ rowstart,
                                          const int* __restrict__ len, const int* __restrict__ csr,
                                          const float* __restrict__ dis,
                                          float* __restrict__ partial, int M, int nblk)
{
  __shared__ float cs[64];
  const int tid = threadIdx.x;
  if (tid < 64) cs[tid] = 0.f;
  __syncthreads();
  const int lane = tid & 7;
  const ushort8* H = (const ushort8*)P;
  float acc[8];
  #pragma unroll
  for (int c = 0; c < 8; ++c) acc[c] = 0.f;
  for (int d = (blockIdx.x * 256 + tid) >> 3; d < M; d += nblk * 32) {
    float rsum[8];
    gather_row8_pre(H, d, lane, rowstart, len, csr, rsum);
    float dd = dis[d];
    #pragma unroll
    for (int c = 0; c < 8; ++c) acc[c] += rsum[c] * dd;
  }
  #pragma unroll
  for (int c = 0; c < 8; ++c) atomicAdd(&cs[8 * lane + c], acc[c]);
  __syncthreads();
  if (tid < 64) partial[(size_t)tid * nblk + blockIdx.x] = cs[tid];
}

__global__ void reduce_out_kernel(const float* __restrict__ partial, const void* __restrict__ b,
                                  const Ctl* __restrict__ ctl, void* __restrict__ out, int nblk)
{
  __shared__ float sh[256];
  int c = blockIdx.x;
  float s = 0.f;
  for (int j = threadIdx.x; j < nblk; j += 256) s += partial[(size_t)c * nblk + j];
  sh[threadIdx.x] = s;
  __syncthreads();
  for (int st = 128; st > 0; st >>= 1) {
    if (threadIdx.x < st) sh[threadIdx.x] += sh[threadIdx.x + st];
    __syncthreads();
  }
  if (threadIdx.x == 0) {
    const bool f32 = ctl->isfp32 != 0;
    float val = sh[0] / (float)K_KEEP + loadF(b, c, f32);
    if (f32) ((float*)out)[c] = val;
    else     ((bf16*)out)[c] = __float2bfloat16(val);
  }
}

// ------- TopK select: hist+pick with early-exit; first post-resolution pass marks -------

__device__ __forceinline__ void mark_slice(const u64* __restrict__ keys, Ctl* ctl,
                                           int* __restrict__ new_idx, int* __restrict__ kept,
                                           int i)
{
  if (i >= N_NODES) return;
  if (keys[i] >= ctl->prefix) {
    int pos = (int)atomicAdd(&ctl->cnt, 1u);
    new_idx[i] = pos;
    kept[pos] = i;
  } else {
    new_idx[i] = -1;
  }
}

__global__ void histpick_kernel(const u64* __restrict__ keys, Ctl* ctl, int shift, int pass,
                                int nblocks, int* __restrict__ new_idx, int* __restrict__ kept) {
  __shared__ u32 lh[256];
  __shared__ u32 sfx[256];
  __shared__ int lastflag;
  __shared__ int selsh;
  const int tid = threadIdx.x;
  const u32 g = ctl->gen;
  if (g != 0u) {
    // resolved at pass (g-1); pass q==g performs the fused marking, later passes no-op
    if ((u32)pass == g)
      mark_slice(keys, ctl, new_idx, kept, blockIdx.x * 256 + tid);
    return;
  }
  lh[tid] = 0;
  __syncthreads();
  u64 prefix = ctl->prefix;
  int i = blockIdx.x * 256 + tid;
  if (i < N_NODES) {
    u64 key = keys[i];
    if ((key >> (shift + 8)) == (prefix >> (shift + 8)))
      atomicAdd(&lh[(u32)((key >> shift) & 0xFF)], 1u);
  }
  __syncthreads();
  u32 c = lh[tid];
  if (c) atomicAdd(&ctl->hist[tid], c);
  __syncthreads();
  if (tid == 0) {
    __threadfence();
    u32 old = atomicAdd(&ctl->done, 1u);
    lastflag = (old == (u32)(nblocks - 1));
  }
  __syncthreads();
  if (!lastflag) return;
  // last block: parallel pick via suffix scan
  u32 cc = atomicExch(&ctl->hist[tid], 0u);   // coherent read + zero for next pass
  sfx[tid] = cc;
  __syncthreads();
  for (int off = 1; off < 256; off <<= 1) {
    u32 t = (tid + off < 256) ? sfx[tid + off] : 0u;
    __syncthreads();
    sfx[tid] += t;
    __syncthreads();
  }
  u32 kr = ctl->kremain;
  u32 above = (tid < 255) ? sfx[tid + 1] : 0u;
  if (sfx[tid] >= kr && above < kr) selsh = tid;   // unique (sfx non-increasing)
  __syncthreads();
  if (tid == 0) {
    int sel = selsh;
    u32 ab = (sel < 255) ? sfx[sel + 1] : 0u;
    u32 newkr = kr - ab;
    u32 bucketcnt = sfx[sel] - ab;
    ctl->kremain = newkr;
    ctl->prefix = prefix | (((u64)(u32)sel) << shift);
    if (newkr == bucketcnt) ctl->gen = (u32)(pass + 1);  // resolved; pass+1 marks
    ctl->done = 0u;
  }
}

// fallback mark: only runs if not already marked by a fused pass (gen==0 or gen==6)
__global__ void mark_kernel(const u64* __restrict__ keys, Ctl* ctl,
                            int* __restrict__ new_idx, int* __restrict__ kept)
{
  u32 g = ctl->gen;
  if (g >= 1u && g <= 5u) return;   // marked by histpick pass q==g
  mark_slice(keys, ctl, new_idx, kept, blockIdx.x * 256 + (int)threadIdx.x);
}

// ------- CSR2 in ONE kernel: count + wave-aggregated alloc + fill (order-free rows) -------

__global__ void csr2_build_kernel(const int* __restrict__ kept, const int* __restrict__ rowstart1,
                                  const int* __restrict__ csr1, const int* __restrict__ new_idx,
                                  Ctl* ctl, int* __restrict__ rowstart2, int* __restrict__ len2,
                                  float* __restrict__ dis2, int* __restrict__ csr2)
{
  int kp = blockIdx.x * 256 + threadIdx.x;
  int lane = threadIdx.x & 63;
  int c = 0;
  int i0 = 0, i1 = 0;
  if (kp < K_KEEP) {
    int o = kept[kp];
    i0 = rowstart1[o]; i1 = rowstart1[o + 1];
    int i = i0;
    for (; i + 4 <= i1; i += 4) {
      int s0 = csr1[i], s1 = csr1[i + 1], s2 = csr1[i + 2], s3 = csr1[i + 3];
      c += (new_idx[s0] >= 0) + (new_idx[s1] >= 0) + (new_idx[s2] >= 0) + (new_idx[s3] >= 0);
    }
    for (; i < i1; ++i) c += (new_idx[csr1[i]] >= 0);
  }
  // wave inclusive scan of c
  int pre = c;
  #pragma unroll
  for (int off = 1; off < 64; off <<= 1) {
    int t = __shfl_up(pre, off);
    if (lane >= off) pre += t;
  }
  int wtot = __shfl(pre, 63);
  int wbase = 0;
  if (lane == 0) wbase = (int)atomicAdd(&ctl->pad, (u32)wtot);
  wbase = __shfl(wbase, 0);
  int base = wbase + pre - c;
  if (kp < K_KEEP) {
    rowstart2[kp] = base;
    len2[kp] = c;
    dis2[kp] = rsqrtf(1.0f + (float)c);
    int w = base;
    for (int i = i0; i < i1; ++i) {
      int ns = new_idx[csr1[i]];
      if (ns >= 0) csr2[w++] = ns;
    }
  }
}

// ---------------- launch ----------------

extern "C" void kernel_launch(void* const* d_in, const int* in_sizes, int n_in,
                              void* d_out, int out_size, void* d_ws, size_t ws_size,
                              hipStream_t stream)
{
  const void* x  = d_in[0];
  const int*  ei = (const int*)d_in[1];
  const void* W1 = d_in[3];
  const void* b1 = d_in[4];
  const void* pw = d_in[5];
  const void* W2 = d_in[6];
  const void* b2 = d_in[7];
  const void* W3 = d_in[8];
  const void* b3 = d_in[9];
  const void* W4 = d_in[10];
  const void* b4 = d_in[11];

  const int* src = ei;
  const int* dst = ei + N_EDGES;

  float* F = (float*)d_ws;
  bf16*  A16       = (bf16*)F;               // N x 128 bf16
  bf16*  B16       = (bf16*)(F + 3200000);   // N x 128 bf16
  bf16*  C16       = (bf16*)(F + 6400000);   // K x 128 bf16
  u32*   xbf       = (u32*)(F + 9000000);    // N x 32 u32 (xbf = dis1*x as bf16 pairs)
  float* dis1      = F + 10600000;           // 50000
  float* dis2      = F + 10650000;           // 40000
  float* score     = F + 10690000;           // 50000
  u64*   keys      = (u64*)(F + 10740000);   // 50000 u64
  int*   new_idx   = (int*)(F + 10840000);   // 50000
  int*   kept      = (int*)(F + 10890000);   // 40000
  int*   len2      = (int*)(F + 10930000);   // 40000
  int*   rowstart1 = (int*)(F + 10970000);   // 50001
  int*   rowstart2 = (int*)(F + 11020004);   // 40000
  int*   csr1      = (int*)(F + 11060008);   // 800000
  int*   csr2      = (int*)(F + 11860008);   // 800000
  Ctl*   ctl       = (Ctl*)(F + 12660008);   // ~1.1 KB
  int*   detcnt    = (int*)(F + 12660856);   // 64
  int*   bucket_cur= (int*)(F + 12660920);   // 196
  u32*   bucketbuf = (u32*)(F + 12726908);   // 196*6144
  float* partial   = F + 13931132;           // 64 x 1024

  const int NB1 = (N_NODES + 255) / 256;     // 196
  const int EB2 = (N_EDGES + 2047) / 2048;   // 391
  const int GB1 = (N_NODES + 63) / 64;       // 782
  const int ABK = K_KEEP * 8 / 256;          // 1250
  const int CB2 = (K_KEEP + 255) / 256;      // 157
  const int NBF = 1024;                      // final-gather blocks

  init_kernel<<<NB1, 256, 0, stream>>>((const unsigned short*)x, bucket_cur, detcnt, ctl);

  // CSR graph 1 via bucket sort (+fused dtype/norm)
  bucket_scatter_kernel<<<EB2, 256, 0, stream>>>(src, dst, bucket_cur, bucketbuf,
                                                 detcnt, pw, ctl);
  // CSR1 build + fused xbf = dis1*x prescale-convert
  csr_from_buckets_kernel<<<BKT, 256, 0, stream>>>(bucketbuf, bucket_cur, rowstart1, dis1, csr1,
                                                   x, (ushort8*)xbf, ctl);

  // conv1 FUSED: gather(xbf) -> LDS -> h1 = G @ W1 + b1 (+fused score/keys)
  gemm_in_kernel<<<GB1, 256, 0, stream>>>((const ushort8*)xbf, rowstart1, csr1, dis1,
                                          W1, b1, pw, B16, ctl, score, keys);

  // top-K select (6 x 8-bit radix; early-exit; first post-resolution pass marks)
  for (int p = 0; p < 6; ++p)
    histpick_kernel<<<NB1, 256, 0, stream>>>(keys, ctl, 40 - 8 * p, p, NB1, new_idx, kept);
  mark_kernel<<<NB1, 256, 0, stream>>>(keys, ctl, new_idx, kept);

  // CSR graph 2 in one kernel (row bases via wave-aggregated atomic; order-free)
  csr2_build_kernel<<<CB2, 256, 0, stream>>>(kept, rowstart1, csr1, new_idx, ctl,
                                             rowstart2, len2, dis2, csr2);

  // conv2: A = dis2*(hp @ W2) ; P2 = dis2*relu(dd*sum(A) + b2)
  gemm_128_64_kernel<<<K_KEEP / 64, 256, 0, stream>>>(B16, W2, A16, ctl, K_KEEP, 0, kept, score, dis2);
  gather_h2_kernel<<<ABK, 256, 0, stream>>>(A16, rowstart2, len2, csr2, dis2, b2, ctl, C16, K_KEEP);

  // conv3 FUSED: gather(P2) -> LDS -> h3 = G @ W3 + b3
  gemm_64_128_kernel<<<K_KEEP / 64, 256, 0, stream>>>(C16, rowstart2, len2, csr2, dis2,
                                                      W3, b3, B16, ctl, K_KEEP);

  // conv4: A = dis2*(relu(h3) @ W4) ; partials = gather(A) ; separate tiny reduce
  gemm_128_64_kernel<<<K_KEEP / 64, 256, 0, stream>>>(B16, W4, A16, ctl, K_KEEP, 1, nullptr, nullptr, dis2);
  agg_gather64_final_kernel<<<NBF, 256, 0, stream>>>(A16, rowstart2, len2, csr2, dis2,
                                                     partial, K_KEEP, NBF);
  reduce_out_kernel<<<64, 256, 0, stream>>>(partial, b4, ctl, d_out, NBF);
}

// Round 12
// 305.176 us; speedup vs baseline: 2.0551x; 1.0275x over previous
//
#include <hip/hip_runtime.h>
#include <hip/hip_bf16.h>
#include <stdint.h>

#define N_NODES 50000
#define N_EDGES 800000
#define K_KEEP  40000
#define BKT     196        // ceil(N_NODES/256) dst-range buckets
#define BCAP    6144       // per-bucket capacity (mean 4081, +32 sigma)

typedef unsigned long long u64;
typedef unsigned int u32;
typedef unsigned short u16;
typedef __hip_bfloat16 bf16;
typedef __hip_bfloat162 bf16x2;
typedef __attribute__((ext_vector_type(8))) short short8;
typedef __attribute__((ext_vector_type(8))) unsigned short ushort8;
typedef __attribute__((ext_vector_type(4))) float f32x4;

struct Ctl {
  u64 prefix;
  u32 kremain;
  u32 cnt;
  float inv_norm;
  u32 isfp32;
  u32 done;         // radix pass arrival counter (reset by picker each pass)
  u32 pad;          // csr2 edge cursor
  u32 gen;          // 0 = unresolved; else (resolution pass + 1); pass==gen does marking
  u32 done2;        // (unused; layout keep)
  u32 hist[256];    // radix histogram (LDS-aggregated flushes only)
};

__device__ __forceinline__ float bf2f(bf16 v) { return __bfloat162float(v); }
__device__ __forceinline__ float bfbits2f(unsigned short u) {
  return __uint_as_float(((u32)u) << 16);
}
__device__ __forceinline__ float loadF(const void* p, size_t i, bool f32) {
  return f32 ? ((const float*)p)[i] : bf2f(((const bf16*)p)[i]);
}
__device__ __forceinline__ short f2bf_bits(float f) {
  bf16 t = __float2bfloat16(f);
  return *(const short*)&t;
}

// Prescaled gather (R9) with ILP-8 (R11), 8-lanes/node layout (used inside fused GEMMs)
__device__ __forceinline__ void gather_row8_pre(const ushort8* __restrict__ H, int d, int lane,
                                                const int* __restrict__ rowstart,
                                                const int* __restrict__ len,
                                                const int* __restrict__ csr,
                                                float* acc)
{
  ushort8 v = H[(size_t)d * 8 + lane];
  #pragma unroll
  for (int c = 0; c < 8; ++c) acc[c] = bfbits2f(v[c]);
  int i = rowstart[d];
  int i1 = len ? (i + len[d]) : rowstart[d + 1];
  for (; i + 8 <= i1; i += 8) {
    int s0 = csr[i],     s1 = csr[i + 1], s2 = csr[i + 2], s3 = csr[i + 3];
    int s4 = csr[i + 4], s5 = csr[i + 5], s6 = csr[i + 6], s7 = csr[i + 7];
    ushort8 v0 = H[(size_t)s0 * 8 + lane];
    ushort8 v1 = H[(size_t)s1 * 8 + lane];
    ushort8 v2 = H[(size_t)s2 * 8 + lane];
    ushort8 v3 = H[(size_t)s3 * 8 + lane];
    ushort8 v4 = H[(size_t)s4 * 8 + lane];
    ushort8 v5 = H[(size_t)s5 * 8 + lane];
    ushort8 v6 = H[(size_t)s6 * 8 + lane];
    ushort8 v7 = H[(size_t)s7 * 8 + lane];
    #pragma unroll
    for (int c = 0; c < 8; ++c) {
      acc[c] += (bfbits2f(v0[c]) + bfbits2f(v1[c]))
              + (bfbits2f(v2[c]) + bfbits2f(v3[c]));
      acc[c] += (bfbits2f(v4[c]) + bfbits2f(v5[c]))
              + (bfbits2f(v6[c]) + bfbits2f(v7[c]));
    }
  }
  for (; i + 4 <= i1; i += 4) {
    int s0 = csr[i], s1 = csr[i + 1], s2 = csr[i + 2], s3 = csr[i + 3];
    ushort8 v0 = H[(size_t)s0 * 8 + lane];
    ushort8 v1 = H[(size_t)s1 * 8 + lane];
    ushort8 v2 = H[(size_t)s2 * 8 + lane];
    ushort8 v3 = H[(size_t)s3 * 8 + lane];
    #pragma unroll
    for (int c = 0; c < 8; ++c) {
      acc[c] += (bfbits2f(v0[c]) + bfbits2f(v1[c]))
              + (bfbits2f(v2[c]) + bfbits2f(v3[c]));
    }
  }
  for (; i < i1; ++i) {
    int s = csr[i];
    ushort8 vv = H[(size_t)s * 8 + lane];
    #pragma unroll
    for (int c = 0; c < 8; ++c) acc[c] += bfbits2f(vv[c]);
  }
}

// R12 wave-per-node gather core: slot = lane>>3 walks edges stride-8; unit = lane&7
// reads contiguous 128B rows per slot-group. acc = per-lane partial (slot's edge subset,
// + self on slot 0). Caller reduces across slots (butterfly) or accumulates directly.
__device__ __forceinline__ void gather_wave_partial(const ushort8* __restrict__ H, int d,
                                                    int slot, int unit,
                                                    const int* __restrict__ rowstart,
                                                    const int* __restrict__ len,
                                                    const int* __restrict__ csr,
                                                    float* acc)
{
  #pragma unroll
  for (int c = 0; c < 8; ++c) acc[c] = 0.f;
  if (slot == 0) {
    ushort8 v = H[(size_t)d * 8 + unit];
    #pragma unroll
    for (int c = 0; c < 8; ++c) acc[c] = bfbits2f(v[c]);
  }
  int i0 = rowstart[d];
  int i1 = i0 + len[d];
  int i = i0 + slot;
  for (; i + 8 < i1; i += 16) {
    int sa = csr[i], sb = csr[i + 8];
    ushort8 va = H[(size_t)sa * 8 + unit];
    ushort8 vb = H[(size_t)sb * 8 + unit];
    #pragma unroll
    for (int c = 0; c < 8; ++c) acc[c] += bfbits2f(va[c]) + bfbits2f(vb[c]);
  }
  if (i < i1) {
    int s = csr[i];
    ushort8 vv = H[(size_t)s * 8 + unit];
    #pragma unroll
    for (int c = 0; c < 8; ++c) acc[c] += bfbits2f(vv[c]);
  }
}

// ---------------- init (+parallel dtype detect, proven R5-R8) ----------------

__global__ void init_kernel(const unsigned short* __restrict__ x16,
                            int* __restrict__ bucket_cur, int* __restrict__ detcnt, Ctl* ctl) {
  __shared__ u32 dsh[256];
  int i = blockIdx.x * 256 + threadIdx.x;
  if (i < BKT) bucket_cur[i] = i * BCAP;
  if (blockIdx.x == 0) {
    ctl->hist[threadIdx.x] = 0u;
    if (threadIdx.x == 0) {
      ctl->prefix = 0ull; ctl->kremain = K_KEEP; ctl->cnt = 0u;
      ctl->done = 0u; ctl->pad = 0u; ctl->gen = 0u; ctl->done2 = 0u;
    }
  }
  if (blockIdx.x < 64) {
    int base = blockIdx.x * 2048;
    u32 c = 0;
    for (int j = threadIdx.x; j < 2048; j += 256) {
      u32 h = x16[base + j];
      if ((h & 0x7F80u) == 0x7F80u) c++;
    }
    dsh[threadIdx.x] = c;
    __syncthreads();
    for (int s = 128; s > 0; s >>= 1) {
      if (threadIdx.x < s) dsh[threadIdx.x] += dsh[threadIdx.x + s];
      __syncthreads();
    }
    if (threadIdx.x == 0) detcnt[blockIdx.x] = (int)dsh[0];
  }
}

// ------- CSR1 bucket scatter (register-cached edges, R11) + fused dtype/norm -------

__global__ void bucket_scatter_kernel(const int* __restrict__ src, const int* __restrict__ dst,
                                      int* __restrict__ bucket_cur, u32* __restrict__ bucketbuf,
                                      const int* __restrict__ detcnt, const void* __restrict__ pw,
                                      Ctl* ctl)
{
  __shared__ u32 hist[BKT];
  __shared__ u32 base[BKT];
  __shared__ int f32sh;
  __shared__ float ns[128];
  const int tid = threadIdx.x;
  const int e0 = blockIdx.x * 2048;

  // dtype detect from detcnt (written by init, prior dispatch)
  if (tid < 64) {
    int dc = detcnt[tid];
    for (int off = 32; off; off >>= 1) dc += __shfl_down(dc, off);
    if (tid == 0) f32sh = (dc >= 16) ? 1 : 0;
  }
  for (int t = tid; t < BKT; t += 256) hist[t] = 0;
  __syncthreads();
  const bool f32in = f32sh != 0;

  // load this block's 8 edges/thread ONCE into registers
  int dreg[8], sreg[8];
  #pragma unroll
  for (int j = 0; j < 8; ++j) {
    int e = e0 + j * 256 + tid;
    if (e < N_EDGES) { dreg[j] = dst[e]; sreg[j] = src[e]; }
    else             { dreg[j] = -1;     sreg[j] = 0;      }
  }
  #pragma unroll
  for (int j = 0; j < 8; ++j)
    if (dreg[j] >= 0) atomicAdd(&hist[dreg[j] >> 8], 1u);
  __syncthreads();
  for (int t = tid; t < BKT; t += 256) {
    u32 c = hist[t];
    base[t] = c ? (u32)atomicAdd(&bucket_cur[t], (int)c) : 0u;
    hist[t] = 0;
  }
  __syncthreads();
  #pragma unroll
  for (int j = 0; j < 8; ++j) {
    if (dreg[j] >= 0) {
      int d = dreg[j];
      int b = d >> 8;
      u32 pos = base[b] + atomicAdd(&hist[b], 1u);
      bucketbuf[pos] = ((u32)sreg[j] << 8) | (u32)(d & 255);
    }
  }
  // fused norm: block 0 computes inv_norm + publishes isfp32
  if (blockIdx.x == 0) {
    if (tid < 128) { float v = loadF(pw, tid, f32in); ns[tid] = v * v; }
    __syncthreads();
    for (int s = 64; s > 0; s >>= 1) {
      if (tid < s) ns[tid] += ns[tid + s];
      __syncthreads();
    }
    if (tid == 0) {
      ctl->inv_norm = 1.0f / sqrtf(ns[0]);
      ctl->isfp32 = f32in ? 1u : 0u;
    }
  }
}

// ------- CSR1 from buckets (inline bucket scan) + fused x -> xbf = dis1*x (bf16) -------

__global__ void csr_from_buckets_kernel(const u32* __restrict__ bucketbuf, const int* __restrict__ bucket_cur,
                                        int* __restrict__ rowstart, float* __restrict__ dis,
                                        int* __restrict__ csr,
                                        const void* __restrict__ x, ushort8* __restrict__ xbf,
                                        const Ctl* __restrict__ ctl)
{
  __shared__ u32 cnt[256];
  __shared__ u32 loc[256];
  __shared__ u32 cur[256];
  __shared__ float disS[256];
  const int b = blockIdx.x;
  const int tid = threadIdx.x;

  // inline scan of all bucket sizes -> off0 for this bucket
  int v = (tid < BKT) ? (bucket_cur[tid] - tid * BCAP) : 0;
  loc[tid] = (u32)v;
  __syncthreads();
  for (int off = 1; off < 256; off <<= 1) {
    u32 t = (tid >= off) ? loc[tid - off] : 0;
    __syncthreads();
    loc[tid] += t;
    __syncthreads();
  }
  const int bc = bucket_cur[b] - b * BCAP;
  const int off0 = (int)loc[b] - bc;
  if (b == BKT - 1 && tid == 0) rowstart[N_NODES] = (int)loc[BKT - 1];
  __syncthreads();

  const u32* buf = bucketbuf + (size_t)b * BCAP;
  cnt[tid] = 0;
  __syncthreads();
  for (int i = tid; i < bc; i += 256) atomicAdd(&cnt[buf[i] & 255u], 1u);
  __syncthreads();
  u32 c = cnt[tid];
  loc[tid] = c;
  __syncthreads();
  for (int off = 1; off < 256; off <<= 1) {
    u32 t = (tid >= off) ? loc[tid - off] : 0;
    __syncthreads();
    loc[tid] += t;
    __syncthreads();
  }
  int node = b * 256 + tid;
  u32 excl = loc[tid] - c;
  float ddv = rsqrtf(1.0f + (float)c);
  disS[tid] = ddv;
  if (node < N_NODES) {
    rowstart[node] = off0 + (int)excl;
    dis[node] = ddv;
  }
  cur[tid] = off0 + excl;
  __syncthreads();
  for (int i = tid; i < bc; i += 256) {
    u32 p = buf[i];
    u32 pos = atomicAdd(&cur[p & 255u], 1u);
    csr[pos] = (int)(p >> 8);
  }
  // fused prescaled conversion: xbf[node] = bf16(dis1[node] * x[node]), 64 ch
  {
    const bool f32in = ctl->isfp32 != 0;
    if (f32in) {
      const float* xf = (const float*)x;
      for (int u = tid; u < 2048; u += 256) {
        int r = u >> 3, lane = u & 7;
        int d = b * 256 + r;
        if (d < N_NODES) {
          float sc = disS[r];
          ushort8 o;
          #pragma unroll
          for (int c2 = 0; c2 < 8; ++c2)
            o[c2] = (u16)f2bf_bits(xf[(size_t)d * 64 + lane * 8 + c2] * sc);
          xbf[(size_t)d * 8 + lane] = o;
        }
      }
    } else {
      const ushort8* xi = (const ushort8*)x;
      for (int u = tid; u < 2048; u += 256) {
        int r = u >> 3, lane = u & 7;
        int d = b * 256 + r;
        if (d < N_NODES) {
          float sc = disS[r];
          ushort8 vv = xi[(size_t)d * 8 + lane];
          ushort8 o;
          #pragma unroll
          for (int c2 = 0; c2 < 8; ++c2)
            o[c2] = (u16)f2bf_bits(bfbits2f(vv[c2]) * sc);
          xbf[(size_t)d * 8 + lane] = o;
        }
      }
    }
  }
}

// ------- conv2 gather (R12 wave-per-node): P2 = dis2 * relu( dd*(sum P) + b2 ) -------

__global__ void gather_h2_kernel(const bf16* __restrict__ P, const int* __restrict__ rowstart,
                                 const int* __restrict__ len, const int* __restrict__ csr,
                                 const float* __restrict__ dis,
                                 const void* __restrict__ b, const Ctl* __restrict__ ctl,
                                 bf16* __restrict__ P2, int M)
{
  const bool f32 = ctl->isfp32 != 0;
  const int tid = threadIdx.x;
  const int d = blockIdx.x * 4 + (tid >> 6);   // one wave per node; grid = M/4 exactly
  const int lane = tid & 63;
  const int slot = lane >> 3, unit = lane & 7;
  const ushort8* H = (const ushort8*)P;
  float acc[8];
  gather_wave_partial(H, d, slot, unit, rowstart, len, csr, acc);
  // butterfly reduce across slots (same unit): xor 8,16,32
  #pragma unroll
  for (int m = 8; m < 64; m <<= 1)
    #pragma unroll
    for (int c = 0; c < 8; ++c) acc[c] += __shfl_xor(acc[c], m);
  if (slot == 0) {
    float dd = dis[d];
    ushort8 outv;
    #pragma unroll
    for (int c = 0; c < 8; ++c) {
      float h = acc[c] * dd + loadF(b, 8 * unit + c, f32);
      outv[c] = (u16)f2bf_bits(fmaxf(h, 0.f) * dd);
    }
    ((ushort8*)P2)[(size_t)d * 8 + unit] = outv;
  }
}

// ---------------- MFMA GEMMs (16x16x32 bf16, fp32 acc) ----------------

// conv1 FUSED: gather(xbf prescaled, graph1) -> LDS, then Y = G @ W1 + b1 (+score/keys)
__global__ void gemm_in_kernel(const ushort8* __restrict__ xbf,
                               const int* __restrict__ rowstart, const int* __restrict__ csr,
                               const float* __restrict__ dis,
                               const void* __restrict__ W, const void* __restrict__ b,
                               const void* __restrict__ pw,
                               bf16* __restrict__ Y, const Ctl* __restrict__ ctl,
                               float* __restrict__ score, u64* __restrict__ keys)
{
  __shared__ short Xs[64 * 72];
  __shared__ short Wt[128 * 72];
  __shared__ float bs[128];
  __shared__ float ps[128];
  const bool f32 = ctl->isfp32 != 0;
  const int tid = threadIdx.x;
  const int row0 = blockIdx.x * 64;

  if (!f32) {
    const short8* W8 = (const short8*)W;
    for (int i = tid; i < 1024; i += 256) {       // 64x128 shorts = 1024 short8
      int k = i >> 4, nb = i & 15;
      short8 v = W8[i];
      #pragma unroll
      for (int j = 0; j < 8; ++j) Wt[(nb * 8 + j) * 72 + k] = v[j];
    }
  } else {
    for (int i = tid; i < 64 * 128; i += 256) {
      int k = i >> 7, n = i & 127;
      Wt[n * 72 + k] = f2bf_bits(((const float*)W)[i]);
    }
  }
  // fused gather: 64 rows x 8 lane-units, 2 units/thread, straight into Xs
  for (int u = tid; u < 512; u += 256) {
    int r = u >> 3, lane = u & 7;
    int d = row0 + r;
    float acc[8];
    short8 outv;
    if (d < N_NODES) {
      gather_row8_pre(xbf, d, lane, rowstart, nullptr, csr, acc);
      float dd = dis[d];
      #pragma unroll
      for (int c = 0; c < 8; ++c) outv[c] = f2bf_bits(acc[c] * dd);
    } else {
      #pragma unroll
      for (int c = 0; c < 8; ++c) outv[c] = 0;
    }
    *(short8*)&Xs[r * 72 + lane * 8] = outv;
  }
  for (int i = tid; i < 128; i += 256) { bs[i] = loadF(b, i, f32); ps[i] = loadF(pw, i, f32); }
  __syncthreads();

  const int lane = tid & 63;
  const int w = tid >> 6;
  const int l16 = lane & 15;
  const int quad = lane >> 4;
  f32x4 acc[8];
  #pragma unroll
  for (int ct = 0; ct < 8; ++ct) acc[ct] = (f32x4){0.f, 0.f, 0.f, 0.f};
  const int arow = w * 16 + l16;
  #pragma unroll
  for (int kc = 0; kc < 2; ++kc) {
    short8 a = *(short8*)&Xs[arow * 72 + kc * 32 + quad * 8];
    #pragma unroll
    for (int ct = 0; ct < 8; ++ct) {
      short8 bb = *(short8*)&Wt[(ct * 16 + l16) * 72 + kc * 32 + quad * 8];
      acc[ct] = __builtin_amdgcn_mfma_f32_16x16x32_bf16(a, bb, acc[ct], 0, 0, 0);
    }
  }
  float inv_norm = ctl->inv_norm;
  #pragma unroll
  for (int r = 0; r < 4; ++r) {
    int gr = row0 + w * 16 + quad * 4 + r;
    float p = 0.f;
    #pragma unroll
    for (int ct = 0; ct < 8; ++ct) {
      int col = ct * 16 + l16;
      float h = acc[ct][r] + bs[col];
      if (gr < N_NODES) Y[(size_t)gr * 128 + col] = __float2bfloat16(h);
      p += fmaxf(h, 0.f) * ps[col];
    }
    p += __shfl_down(p, 8, 16);
    p += __shfl_down(p, 4, 16);
    p += __shfl_down(p, 2, 16);
    p += __shfl_down(p, 1, 16);
    if (l16 == 0 && gr < N_NODES) {
      float sc = tanhf(p * inv_norm);
      score[gr] = sc;
      u32 u = __float_as_uint(sc);
      u = (u & 0x80000000u) ? ~u : (u | 0x80000000u);
      keys[gr] = (((u64)u) << 16) | (u64)(0xFFFFu - (u32)gr);
    }
  }
}

// Y[M,64] = (relu?)X[M,128] @ W[128,64]; M multiple of 64
// kept!=null: X row = kept[row], apply relu*score[kept[row]] (fused TopK hp)
// prescale!=null: Y row *= prescale[row] (dis2, for gather-consumed outputs)
__global__ void gemm_128_64_kernel(const bf16* __restrict__ X, const void* __restrict__ W,
                                   bf16* __restrict__ Y, const Ctl* __restrict__ ctl,
                                   int M, int relu_x,
                                   const int* __restrict__ kept, const float* __restrict__ score,
                                   const float* __restrict__ prescale)
{
  __shared__ short Xs[64 * 136];
  __shared__ short Wt[64 * 136];
  __shared__ int keptS[64];
  __shared__ float scS[64];
  const bool f32 = ctl->isfp32 != 0;
  const int tid = threadIdx.x;
  const int row0 = blockIdx.x * 64;

  if (kept) {
    for (int i = tid; i < 64; i += 256) {
      int o = kept[row0 + i];
      keptS[i] = o;
      scS[i] = score[o];
    }
  }
  __syncthreads();

  if (!f32) {
    const short8* W8 = (const short8*)W;
    for (int i = tid; i < 1024; i += 256) {       // 128x64 shorts = 1024 short8
      int k = i >> 3, nb = i & 7;
      short8 v = W8[i];
      #pragma unroll
      for (int j = 0; j < 8; ++j) Wt[(nb * 8 + j) * 136 + k] = v[j];
    }
  } else {
    for (int i = tid; i < 128 * 64; i += 256) {
      int k = i >> 6, n = i & 63;
      Wt[n * 136 + k] = f2bf_bits(((const float*)W)[i]);
    }
  }
  const u32* X2 = (const u32*)X;
  for (int p = tid; p < 64 * 64; p += 256) {
    int r = p >> 6, kp = p & 63;
    int srow = kept ? keptS[r] : (row0 + r);
    u32 v = X2[(size_t)srow * 64 + kp];
    if (relu_x) {
      if (v & 0x8000u) v &= 0xFFFF0000u;
      if (v & 0x80000000u) v &= 0x0000FFFFu;
    }
    if (kept) {
      bf16x2 h = *(bf16x2*)&v;
      float s = scS[r];
      bf16x2 o;
      o.x = __float2bfloat16(fmaxf(bf2f(h.x), 0.f) * s);
      o.y = __float2bfloat16(fmaxf(bf2f(h.y), 0.f) * s);
      v = *(u32*)&o;
    }
    *(u32*)&Xs[r * 136 + 2 * kp] = v;
  }
  __syncthreads();

  const int lane = tid & 63;
  const int w = tid >> 6;
  const int l16 = lane & 15;
  const int quad = lane >> 4;
  f32x4 acc[4];
  #pragma unroll
  for (int ct = 0; ct < 4; ++ct) acc[ct] = (f32x4){0.f, 0.f, 0.f, 0.f};
  const int arow = w * 16 + l16;
  #pragma unroll
  for (int kc = 0; kc < 4; ++kc) {
    short8 a = *(short8*)&Xs[arow * 136 + kc * 32 + quad * 8];
    #pragma unroll
    for (int ct = 0; ct < 4; ++ct) {
      short8 bb = *(short8*)&Wt[(ct * 16 + l16) * 136 + kc * 32 + quad * 8];
      acc[ct] = __builtin_amdgcn_mfma_f32_16x16x32_bf16(a, bb, acc[ct], 0, 0, 0);
    }
  }
  #pragma unroll
  for (int ct = 0; ct < 4; ++ct)
    #pragma unroll
    for (int r = 0; r < 4; ++r) {
      int gr = row0 + w * 16 + quad * 4 + r;
      float val = acc[ct][r];
      if (prescale) val *= prescale[gr];
      Y[(size_t)gr * 64 + ct * 16 + l16] = __float2bfloat16(val);
    }
}

// conv3 FUSED: gather(P2 prescaled, graph2) -> LDS, then Y[M,128] = G @ W3 + b3
__global__ void gemm_64_128_kernel(const bf16* __restrict__ P2,
                                   const int* __restrict__ rowstart, const int* __restrict__ len,
                                   const int* __restrict__ csr, const float* __restrict__ dis,
                                   const void* __restrict__ W, const void* __restrict__ b,
                                   bf16* __restrict__ Y, const Ctl* __restrict__ ctl, int M)
{
  __shared__ short Xs[64 * 72];
  __shared__ short Wt[128 * 72];
  __shared__ float bs[128];
  const bool f32 = ctl->isfp32 != 0;
  const int tid = threadIdx.x;
  const int row0 = blockIdx.x * 64;

  if (!f32) {
    const short8* W8 = (const short8*)W;
    for (int i = tid; i < 1024; i += 256) {       // 64x128 shorts = 1024 short8
      int k = i >> 4, nb = i & 15;
      short8 v = W8[i];
      #pragma unroll
      for (int j = 0; j < 8; ++j) Wt[(nb * 8 + j) * 72 + k] = v[j];
    }
  } else {
    for (int i = tid; i < 64 * 128; i += 256) {
      int k = i >> 7, n = i & 127;
      Wt[n * 72 + k] = f2bf_bits(((const float*)W)[i]);
    }
  }
  // fused gather (relu baked into P2 at conv2 write)
  {
    const ushort8* H = (const ushort8*)P2;
    for (int u = tid; u < 512; u += 256) {
      int r = u >> 3, lane = u & 7;
      int d = row0 + r;           // M multiple of 64 -> always < M
      float acc[8];
      gather_row8_pre(H, d, lane, rowstart, len, csr, acc);
      float dd = dis[d];
      short8 outv;
      #pragma unroll
      for (int c = 0; c < 8; ++c) outv[c] = f2bf_bits(acc[c] * dd);
      *(short8*)&Xs[r * 72 + lane * 8] = outv;
    }
  }
  for (int i = tid; i < 128; i += 256) bs[i] = loadF(b, i, f32);
  __syncthreads();

  const int lane = tid & 63;
  const int w = tid >> 6;
  const int l16 = lane & 15;
  const int quad = lane >> 4;
  f32x4 acc[8];
  #pragma unroll
  for (int ct = 0; ct < 8; ++ct) acc[ct] = (f32x4){0.f, 0.f, 0.f, 0.f};
  const int arow = w * 16 + l16;
  #pragma unroll
  for (int kc = 0; kc < 2; ++kc) {
    short8 a = *(short8*)&Xs[arow * 72 + kc * 32 + quad * 8];
    #pragma unroll
    for (int ct = 0; ct < 8; ++ct) {
      short8 bb = *(short8*)&Wt[(ct * 16 + l16) * 72 + kc * 32 + quad * 8];
      acc[ct] = __builtin_amdgcn_mfma_f32_16x16x32_bf16(a, bb, acc[ct], 0, 0, 0);
    }
  }
  #pragma unroll
  for (int ct = 0; ct < 8; ++ct)
    #pragma unroll
    for (int r = 0; r < 4; ++r) {
      int gr = row0 + w * 16 + quad * 4 + r;
      int col = ct * 16 + l16;
      Y[(size_t)gr * 128 + col] = __float2bfloat16(acc[ct][r] + bs[col]);
    }
}

// conv4: R12 wave-per-node gather + register acc + per-block partial
__global__ void agg_gather64_final_kernel(const bf16* __restrict__ P, const int* __restrict__ rowstart,
                                          const int* __restrict__ len, const int* __restrict__ csr,
                                          const float* __restrict__ dis,
                                          float* __restrict__ partial, int M, int nblk)
{
  __shared__ float cs[64];
  const int tid = threadIdx.x;
  if (tid < 64) cs[tid] = 0.f;
  __syncthreads();
  const int lane = tid & 63;
  const int slot = lane >> 3, unit = lane & 7;
  const int wave = tid >> 6;
  const ushort8* H = (const ushort8*)P;
  float acc[8];
  #pragma unroll
  for (int c = 0; c < 8; ++c) acc[c] = 0.f;
  for (int d = blockIdx.x * 4 + wave; d < M; d += nblk * 4) {
    float part[8];
    gather_wave_partial(H, d, slot, unit, rowstart, len, csr, part);
    float dd = dis[d];
    #pragma unroll
    for (int c = 0; c < 8; ++c) acc[c] += part[c] * dd;
  }
  #pragma unroll
  for (int c = 0; c < 8; ++c) atomicAdd(&cs[8 * unit + c], acc[c]);
  __syncthreads();
  if (tid < 64) partial[(size_t)tid * nblk + blockIdx.x] = cs[tid];
}

__global__ void reduce_out_kernel(const float* __restrict__ partial, const void* __restrict__ b,
                                  const Ctl* __restrict__ ctl, void* __restrict__ out, int nblk)
{
  __shared__ float sh[256];
  int c = blockIdx.x;
  float s = 0.f;
  for (int j = threadIdx.x; j < nblk; j += 256) s += partial[(size_t)c * nblk + j];
  sh[threadIdx.x] = s;
  __syncthreads();
  for (int st = 128; st > 0; st >>= 1) {
    if (threadIdx.x < st) sh[threadIdx.x] += sh[threadIdx.x + st];
    __syncthreads();
  }
  if (threadIdx.x == 0) {
    const bool f32 = ctl->isfp32 != 0;
    float val = sh[0] / (float)K_KEEP + loadF(b, c, f32);
    if (f32) ((float*)out)[c] = val;
    else     ((bf16*)out)[c] = __float2bfloat16(val);
  }
}

// ------- TopK select: hist+pick with early-exit; first post-resolution pass marks -------

__device__ __forceinline__ void mark_slice(const u64* __restrict__ keys, Ctl* ctl,
                                           int* __restrict__ new_idx, int* __restrict__ kept,
                                           int i)
{
  if (i >= N_NODES) return;
  if (keys[i] >= ctl->prefix) {
    int pos = (int)atomicAdd(&ctl->cnt, 1u);
    new_idx[i] = pos;
    kept[pos] = i;
  } else {
    new_idx[i] = -1;
  }
}

__global__ void histpick_kernel(const u64* __restrict__ keys, Ctl* ctl, int shift, int pass,
                                int nblocks, int* __restrict__ new_idx, int* __restrict__ kept) {
  __shared__ u32 lh[256];
  __shared__ u32 sfx[256];
  __shared__ int lastflag;
  __shared__ int selsh;
  const int tid = threadIdx.x;
  const u32 g = ctl->gen;
  if (g != 0u) {
    // resolved at pass (g-1); pass q==g performs the fused marking, later passes no-op
    if ((u32)pass == g)
      mark_slice(keys, ctl, new_idx, kept, blockIdx.x * 256 + tid);
    return;
  }
  lh[tid] = 0;
  __syncthreads();
  u64 prefix = ctl->prefix;
  int i = blockIdx.x * 256 + tid;
  if (i < N_NODES) {
    u64 key = keys[i];
    if ((key >> (shift + 8)) == (prefix >> (shift + 8)))
      atomicAdd(&lh[(u32)((key >> shift) & 0xFF)], 1u);
  }
  __syncthreads();
  u32 c = lh[tid];
  if (c) atomicAdd(&ctl->hist[tid], c);
  __syncthreads();
  if (tid == 0) {
    __threadfence();
    u32 old = atomicAdd(&ctl->done, 1u);
    lastflag = (old == (u32)(nblocks - 1));
  }
  __syncthreads();
  if (!lastflag) return;
  // last block: parallel pick via suffix scan
  u32 cc = atomicExch(&ctl->hist[tid], 0u);   // coherent read + zero for next pass
  sfx[tid] = cc;
  __syncthreads();
  for (int off = 1; off < 256; off <<= 1) {
    u32 t = (tid + off < 256) ? sfx[tid + off] : 0u;
    __syncthreads();
    sfx[tid] += t;
    __syncthreads();
  }
  u32 kr = ctl->kremain;
  u32 above = (tid < 255) ? sfx[tid + 1] : 0u;
  if (sfx[tid] >= kr && above < kr) selsh = tid;   // unique (sfx non-increasing)
  __syncthreads();
  if (tid == 0) {
    int sel = selsh;
    u32 ab = (sel < 255) ? sfx[sel + 1] : 0u;
    u32 newkr = kr - ab;
    u32 bucketcnt = sfx[sel] - ab;
    ctl->kremain = newkr;
    ctl->prefix = prefix | (((u64)(u32)sel) << shift);
    if (newkr == bucketcnt) ctl->gen = (u32)(pass + 1);  // resolved; pass+1 marks
    ctl->done = 0u;
  }
}

// fallback mark: only runs if not already marked by a fused pass (gen==0 or gen==6)
__global__ void mark_kernel(const u64* __restrict__ keys, Ctl* ctl,
                            int* __restrict__ new_idx, int* __restrict__ kept)
{
  u32 g = ctl->gen;
  if (g >= 1u && g <= 5u) return;   // marked by histpick pass q==g
  mark_slice(keys, ctl, new_idx, kept, blockIdx.x * 256 + (int)threadIdx.x);
}

// ------- CSR2 in ONE kernel: count + wave-aggregated alloc + fill (order-free rows) -------

__global__ void csr2_build_kernel(const int* __restrict__ kept, const int* __restrict__ rowstart1,
                                  const int* __restrict__ csr1, const int* __restrict__ new_idx,
                                  Ctl* ctl, int* __restrict__ rowstart2, int* __restrict__ len2,
                                  float* __restrict__ dis2, int* __restrict__ csr2)
{
  int kp = blockIdx.x * 256 + threadIdx.x;
  int lane = threadIdx.x & 63;
  int c = 0;
  int i0 = 0, i1 = 0;
  if (kp < K_KEEP) {
    int o = kept[kp];
    i0 = rowstart1[o]; i1 = rowstart1[o + 1];
    int i = i0;
    for (; i + 4 <= i1; i += 4) {
      int s0 = csr1[i], s1 = csr1[i + 1], s2 = csr1[i + 2], s3 = csr1[i + 3];
      c += (new_idx[s0] >= 0) + (new_idx[s1] >= 0) + (new_idx[s2] >= 0) + (new_idx[s3] >= 0);
    }
    for (; i < i1; ++i) c += (new_idx[csr1[i]] >= 0);
  }
  // wave inclusive scan of c
  int pre = c;
  #pragma unroll
  for (int off = 1; off < 64; off <<= 1) {
    int t = __shfl_up(pre, off);
    if (lane >= off) pre += t;
  }
  int wtot = __shfl(pre, 63);
  int wbase = 0;
  if (lane == 0) wbase = (int)atomicAdd(&ctl->pad, (u32)wtot);
  wbase = __shfl(wbase, 0);
  int base = wbase + pre - c;
  if (kp < K_KEEP) {
    rowstart2[kp] = base;
    len2[kp] = c;
    dis2[kp] = rsqrtf(1.0f + (float)c);
    int w = base;
    for (int i = i0; i < i1; ++i) {
      int ns = new_idx[csr1[i]];
      if (ns >= 0) csr2[w++] = ns;
    }
  }
}

// ---------------- launch ----------------

extern "C" void kernel_launch(void* const* d_in, const int* in_sizes, int n_in,
                              void* d_out, int out_size, void* d_ws, size_t ws_size,
                              hipStream_t stream)
{
  const void* x  = d_in[0];
  const int*  ei = (const int*)d_in[1];
  const void* W1 = d_in[3];
  const void* b1 = d_in[4];
  const void* pw = d_in[5];
  const void* W2 = d_in[6];
  const void* b2 = d_in[7];
  const void* W3 = d_in[8];
  const void* b3 = d_in[9];
  const void* W4 = d_in[10];
  const void* b4 = d_in[11];

  const int* src = ei;
  const int* dst = ei + N_EDGES;

  float* F = (float*)d_ws;
  bf16*  A16       = (bf16*)F;               // N x 128 bf16
  bf16*  B16       = (bf16*)(F + 3200000);   // N x 128 bf16
  bf16*  C16       = (bf16*)(F + 6400000);   // K x 128 bf16
  u32*   xbf       = (u32*)(F + 9000000);    // N x 32 u32 (xbf = dis1*x as bf16 pairs)
  float* dis1      = F + 10600000;           // 50000
  float* dis2      = F + 10650000;           // 40000
  float* score     = F + 10690000;           // 50000
  u64*   keys      = (u64*)(F + 10740000);   // 50000 u64
  int*   new_idx   = (int*)(F + 10840000);   // 50000
  int*   kept      = (int*)(F + 10890000);   // 40000
  int*   len2      = (int*)(F + 10930000);   // 40000
  int*   rowstart1 = (int*)(F + 10970000);   // 50001
  int*   rowstart2 = (int*)(F + 11020004);   // 40000
  int*   csr1      = (int*)(F + 11060008);   // 800000
  int*   csr2      = (int*)(F + 11860008);   // 800000
  Ctl*   ctl       = (Ctl*)(F + 12660008);   // ~1.1 KB
  int*   detcnt    = (int*)(F + 12660856);   // 64
  int*   bucket_cur= (int*)(F + 12660920);   // 196
  u32*   bucketbuf = (u32*)(F + 12726908);   // 196*6144
  float* partial   = F + 13931132;           // 64 x 1024

  const int NB1 = (N_NODES + 255) / 256;     // 196
  const int EB2 = (N_EDGES + 2047) / 2048;   // 391
  const int GB1 = (N_NODES + 63) / 64;       // 782
  const int WBK = K_KEEP / 4;                // 10000 (wave-per-node)
  const int CB2 = (K_KEEP + 255) / 256;      // 157
  const int NBF = 1024;                      // final-gather blocks

  init_kernel<<<NB1, 256, 0, stream>>>((const unsigned short*)x, bucket_cur, detcnt, ctl);

  // CSR graph 1 via bucket sort (+fused dtype/norm)
  bucket_scatter_kernel<<<EB2, 256, 0, stream>>>(src, dst, bucket_cur, bucketbuf,
                                                 detcnt, pw, ctl);
  // CSR1 build + fused xbf = dis1*x prescale-convert
  csr_from_buckets_kernel<<<BKT, 256, 0, stream>>>(bucketbuf, bucket_cur, rowstart1, dis1, csr1,
                                                   x, (ushort8*)xbf, ctl);

  // conv1 FUSED: gather(xbf) -> LDS -> h1 = G @ W1 + b1 (+fused score/keys)
  gemm_in_kernel<<<GB1, 256, 0, stream>>>((const ushort8*)xbf, rowstart1, csr1, dis1,
                                          W1, b1, pw, B16, ctl, score, keys);

  // top-K select (6 x 8-bit radix; early-exit; first post-resolution pass marks)
  for (int p = 0; p < 6; ++p)
    histpick_kernel<<<NB1, 256, 0, stream>>>(keys, ctl, 40 - 8 * p, p, NB1, new_idx, kept);
  mark_kernel<<<NB1, 256, 0, stream>>>(keys, ctl, new_idx, kept);

  // CSR graph 2 in one kernel (row bases via wave-aggregated atomic; order-free)
  csr2_build_kernel<<<CB2, 256, 0, stream>>>(kept, rowstart1, csr1, new_idx, ctl,
                                             rowstart2, len2, dis2, csr2);

  // conv2: A = dis2*(hp @ W2) ; P2 = dis2*relu(dd*sum(A) + b2)   [wave-per-node gather]
  gemm_128_64_kernel<<<K_KEEP / 64, 256, 0, stream>>>(B16, W2, A16, ctl, K_KEEP, 0, kept, score, dis2);
  gather_h2_kernel<<<WBK, 256, 0, stream>>>(A16, rowstart2, len2, csr2, dis2, b2, ctl, C16, K_KEEP);

  // conv3 FUSED: gather(P2) -> LDS -> h3 = G @ W3 + b3
  gemm_64_128_kernel<<<K_KEEP / 64, 256, 0, stream>>>(C16, rowstart2, len2, csr2, dis2,
                                                      W3, b3, B16, ctl, K_KEEP);

  // conv4: A = dis2*(relu(h3) @ W4) ; partials = wave-per-node gather ; tiny reduce
  gemm_128_64_kernel<<<K_KEEP / 64, 256, 0, stream>>>(B16, W4, A16, ctl, K_KEEP, 1, nullptr, nullptr, dis2);
  agg_gather64_final_kernel<<<NBF, 256, 0, stream>>>(A16, rowstart2, len2, csr2, dis2,
                                                     partial, K_KEEP, NBF);
  reduce_out_kernel<<<64, 256, 0, stream>>>(partial, b4, ctl, d_out, NBF);
}